// Round 1
// baseline (7883.404 us; speedup 1.0000x reference)
//
#include <hip/hip_runtime.h>
#include <math.h>

#define Bn 16
#define Tn 384
#define Cn 128
#define Dn 512

// ---------------- workspace layout (in floats) ----------------
static constexpr long OFF_AVG    = 0;                       // Cn*Tn ACF sums
static constexpr long OFF_PER    = (long)Cn * Tn;           // Cn*2 ints
static constexpr long OFF_WTREND = OFF_PER + Cn * 2;        // Dn*Tn
static constexpr long OFF_WP     = OFF_WTREND + (long)Dn * Tn;
static constexpr long WP_TOTAL   = 9483264;                 // sum_{p=4..192} 512*p
static constexpr long OFF_COMB   = OFF_WP + WP_TOTAL;       // Bn*Cn*1536
static constexpr long WS_FLOATS  = OFF_COMB + (long)Bn * Cn * 1536; // ~51.5 MB

__host__ __device__ inline long wpoff(int p) { return 512L * ((long)p * (p - 1) / 2 - 6); }

// interp row j of _interp_matrix(newl, oldl): nonzeros at (i0, 1-w), (i1, w)
__device__ inline void irow(int j, int newl, int oldl, int& i0, int& i1, float& w) {
  double src = ((double)j + 0.5) * (double)oldl / (double)newl - 0.5;
  if (src < 0.0) src = 0.0;
  double mx = (double)(oldl - 1);
  if (src > mx) src = mx;
  int a = (int)src;            // src >= 0 so trunc == floor
  if (a > oldl - 1) a = oldl - 1;
  i0 = a;
  i1 = (a + 1 < oldl) ? (a + 1) : (oldl - 1);
  w = (float)(src - (double)a);
}

// ---------------- stage A1: batch-summed linear ACF per channel ----------------
__global__ __launch_bounds__(256) void acf_kernel(const float* __restrict__ x,
                                                  float* __restrict__ avg) {
  __shared__ float xb[Bn * Tn];
  __shared__ float mean[Bn];
  int c = blockIdx.x, tid = threadIdx.x;
  for (int i = tid; i < Bn * Tn; i += 256) {
    int b = i / Tn, t = i % Tn;
    xb[i] = x[((long)b * Tn + t) * Cn + c];
  }
  __syncthreads();
  if (tid < Bn) {
    float s = 0.f;
    for (int t = 0; t < Tn; ++t) s += xb[tid * Tn + t];
    mean[tid] = s / (float)Tn;
  }
  __syncthreads();
  for (int i = tid; i < Bn * Tn; i += 256) xb[i] -= mean[i / Tn];
  __syncthreads();
  for (int tau = tid; tau < Tn; tau += 256) {
    float acc = 0.f;
    for (int b = 0; b < Bn; ++b) {
      const float* xr = xb + b * Tn;
      float s = 0.f;
      for (int t = 0; t + tau < Tn; ++t) s += xr[t] * xr[t + tau];
      acc += s;
    }
    avg[(long)c * Tn + tau] = acc;   // positive scale of mean -> same peaks/topk
  }
}

// ---------------- stage A2: peak detect + top-2 + clip ----------------
__global__ __launch_bounds__(128) void periods_kernel(const float* __restrict__ avg,
                                                      int* __restrict__ per) {
  int c = threadIdx.x;
  if (c >= Cn) return;
  const float* a = avg + (long)c * Tn;
  const float NEG = -1e30f;
  float b1v = NEG, b2v = NEG;
  int b1i = 0, b2i = 0;
  for (int t = 4; t < Tn; ++t) {
    float v = a[t];
    float pv = (t == 4) ? NEG : a[t - 1];       // avg[0..3] masked to -inf
    float nv = (t == Tn - 1) ? NEG : a[t + 1];  // circular nxt at T-1 is avg[0] = -inf
    bool peak = (v > pv) && (v > nv) && (v > 0.f);
    float m = peak ? v : NEG;
    if (m > b1v)      { b2v = b1v; b2i = b1i; b1v = m; b1i = t; }
    else if (m > b2v) { b2v = m; b2i = t; }
  }
  per[c * 2 + 0] = min(max(b1i, 4), 192);
  per[c * 2 + 1] = min(max(b2i, 4), 192);
}

// ---------------- stage C: build w_p for needed p (and w_trend) on device ----------------
// pinv(M.T) = M (M^T M)^-1 (p>n)  or  (M M^T)^-1 M (p<n); Gram inverted by GJ in LDS.
__global__ __launch_bounds__(256) void build_weights_kernel(
    const float* __restrict__ a12, const float* __restrict__ a24,
    const float* __restrict__ a48, const float* __restrict__ a96,
    const int* __restrict__ per, float* __restrict__ wp_table,
    float* __restrict__ wtrend) {
  __shared__ float mat[96 * 97];   // Gram matrix / its inverse, ld=97 (bank-safe)
  __shared__ float tile[64 * 96];  // 64-row anchor intermediate
  __shared__ float fcol[96];
  __shared__ int flag;
  int tid = threadIdx.x;
  int p = (blockIdx.x < 189) ? (4 + (int)blockIdx.x) : 384;
  if (tid == 0) flag = (p == 384) ? 1 : 0;
  __syncthreads();
  if (p != 384) {
    for (int i = tid; i < Cn * 2; i += 256)
      if (per[i] == p) flag = 1;
  }
  __syncthreads();
  if (!flag) return;

  int n; const float* anchor;
  if (p <= 18)      { n = 12; anchor = a12; }   // ties break to earlier anchor (Python min)
  else if (p <= 36) { n = 24; anchor = a24; }
  else if (p <= 72) { n = 48; anchor = a48; }
  else              { n = 96; anchor = a96; }
  float* dst = (p == 384) ? wtrend : (wp_table + wpoff(p));
  if (p == n) {  // exact anchor, no interp, no scale
    for (int i = tid; i < 512 * p; i += 256) dst[i] = anchor[i];
    return;
  }
  float scale = sqrtf((float)p / (float)n);
  int m = (p > n) ? n : p;  // Gram dim

  for (int idx = tid; idx < m * m; idx += 256)
    mat[(idx / m) * 97 + (idx % m)] = 0.f;
  __syncthreads();
  if (p > n) {  // G = M^T M via scatter of 2-sparse rows
    for (int j = tid; j < p; j += 256) {
      int i0, i1; float w;
      irow(j, p, n, i0, i1, w);
      float w0 = 1.f - w;
      atomicAdd(&mat[i0 * 97 + i0], w0 * w0);
      atomicAdd(&mat[i0 * 97 + i1], w0 * w);
      atomicAdd(&mat[i1 * 97 + i0], w0 * w);
      atomicAdd(&mat[i1 * 97 + i1], w * w);
    }
  } else {      // H = M M^T, direct 2-sparse dot
    for (int idx = tid; idx < m * m; idx += 256) {
      int r = idx / m, c2 = idx % m;
      int ri0, ri1, ci0, ci1; float rw, cw;
      irow(r, p, n, ri0, ri1, rw);
      irow(c2, p, n, ci0, ci1, cw);
      float rv0 = 1.f - rw, cv0 = 1.f - cw;
      float s = 0.f;
      if (ri0 == ci0) s += rv0 * cv0;
      if (ri0 == ci1) s += rv0 * cw;
      if (ri1 == ci0) s += rw * cv0;
      if (ri1 == ci1) s += rw * cw;
      mat[r * 97 + c2] = s;
    }
  }
  __syncthreads();
  // in-place Gauss-Jordan inverse (SPD, no pivoting needed)
  for (int k = 0; k < m; ++k) {
    for (int r = tid; r < m; r += 256) fcol[r] = mat[r * 97 + k];
    __syncthreads();
    float ip = 1.f / fcol[k];
    for (int c2 = tid; c2 < m; c2 += 256)
      mat[k * 97 + c2] = (c2 == k) ? ip : mat[k * 97 + c2] * ip;
    __syncthreads();
    for (int idx = tid; idx < m * m; idx += 256) {
      int r = idx / m, c2 = idx % m;
      if (r != k) {
        float f = fcol[r];
        float rkv = mat[k * 97 + c2];
        mat[r * 97 + c2] = (c2 == k) ? (-f * rkv) : (mat[r * 97 + c2] - f * rkv);
      }
    }
    __syncthreads();
  }
  // w_p = scale * anchor @ Mpinv^T, in 64-row tiles
  for (int base = 0; base < 512; base += 64) {
    if (p > n) {
      // Z = anchor_tile @ Ginv (64 x n), then apply interp rows
      for (int idx = tid; idx < 64 * n; idx += 256) {
        int dd = idx / n, k = idx % n;
        const float* ar = anchor + (long)(base + dd) * n;
        float acc = 0.f;
        for (int mm = 0; mm < n; ++mm) acc += ar[mm] * mat[mm * 97 + k];
        tile[dd * 96 + k] = acc;
      }
      __syncthreads();
      for (int idx = tid; idx < 64 * p; idx += 256) {
        int dd = idx / p, j = idx % p;
        int i0, i1; float w;
        irow(j, p, n, i0, i1, w);
        float v = tile[dd * 96 + i0] * (1.f - w) + tile[dd * 96 + i1] * w;
        dst[(long)(base + dd) * p + j] = scale * v;
      }
    } else {
      // Y = anchor_tile interp'd by M rows (64 x p), then @ Hinv
      for (int idx = tid; idx < 64 * p; idx += 256) {
        int dd = idx / p, j2 = idx % p;
        int i0, i1; float w;
        irow(j2, p, n, i0, i1, w);
        const float* ar = anchor + (long)(base + dd) * n;
        tile[dd * 96 + j2] = (1.f - w) * ar[i0] + w * ar[i1];
      }
      __syncthreads();
      for (int idx = tid; idx < 64 * p; idx += 256) {
        int dd = idx / p, j = idx % p;
        float acc = 0.f;
        for (int j2 = 0; j2 < p; ++j2) acc += tile[dd * 96 + j2] * mat[j2 * 97 + j];
        dst[(long)(base + dd) * p + j] = scale * acc;
      }
    }
    __syncthreads();
  }
}

// ---------------- stage B: fused tokenize + single-query attention + LN ----------------
// one block per (b, c, slot); folded projections:
//   score_{h,j} = (Wk_h^T q_h) . t_j + q_h.bk_h ;  o = Wv @ (sum_j prob t_j) + bv
__global__ __launch_bounds__(256) void attn_kernel(
    const float* __restrict__ x, const int* __restrict__ per,
    const float* __restrict__ wp_table, const float* __restrict__ sbias,
    const float* __restrict__ w1_in_w, const float* __restrict__ w1_in_b,
    const float* __restrict__ w1_out_w, const float* __restrict__ w1_out_b,
    const float* __restrict__ w1_ln_g, const float* __restrict__ w1_ln_b,
    const float* __restrict__ w2_in_w, const float* __restrict__ w2_in_b,
    const float* __restrict__ w2_out_w, const float* __restrict__ w2_out_b,
    const float* __restrict__ w2_ln_g, const float* __restrict__ w2_ln_b,
    float* __restrict__ comb) {
  __shared__ float xb[Tn];
  __shared__ float tl[512];      // last token (residual q)
  __shared__ float qy[512];      // q projection, later reused for y
  __shared__ float rr[2048];     // folded key vectors r_h
  __shared__ float tok[4096];    // 8-token tile
  __shared__ float un[2048];     // normalized weighted token sums per head
  __shared__ float ov[512];      // attention output o
  __shared__ float sc[32];
  __shared__ float cc[4], mh[4], lh[4], al[4], wj[32];
  __shared__ float red[8];
  __shared__ float stats[2];

  int tid = threadIdx.x;
  int bid = blockIdx.x;
  int b = bid >> 8;
  int c = (bid >> 1) & 127;
  int slot = bid & 1;
  int p = per[c * 2 + slot];
  int np = Tn / p;
  int Tuse = np * p;
  const float* wp = wp_table + wpoff(p);
  const float* in_w  = slot ? w2_in_w  : w1_in_w;
  const float* in_b  = slot ? w2_in_b  : w1_in_b;
  const float* out_w = slot ? w2_out_w : w1_out_w;
  const float* out_b = slot ? w2_out_b : w1_out_b;
  const float* ln_g  = slot ? w2_ln_g  : w1_ln_g;
  const float* ln_b  = slot ? w2_ln_b  : w1_ln_b;

  for (int t = tid; t < Tuse; t += 256) xb[t] = x[((long)b * Tn + t) * Cn + c];
  __syncthreads();

  {  // last token
    int jb = (np - 1) * p;
    for (int d = tid; d < 512; d += 256) {
      float acc = sbias[d];
      const float* wr = wp + (long)d * p;
      for (int t = 0; t < p; ++t) acc += wr[t] * xb[jb + t];
      tl[d] = acc;
    }
  }
  __syncthreads();
  // q = Wq @ tl + bq
  for (int i = tid; i < 512; i += 256) {
    const float4* wr = (const float4*)(in_w + (long)i * 512);
    float acc = in_b[i];
    for (int e4 = 0; e4 < 128; ++e4) {
      float4 w4 = wr[e4];
      acc += w4.x * tl[e4 * 4 + 0] + w4.y * tl[e4 * 4 + 1] +
             w4.z * tl[e4 * 4 + 2] + w4.w * tl[e4 * 4 + 3];
    }
    qy[i] = acc;
  }
  __syncthreads();
  // r_h = Wk_h^T q_h (coalesced over e)
  for (int h = 0; h < 4; ++h) {
    for (int e = tid; e < 512; e += 256) {
      float acc = 0.f;
      const float* col = in_w + (long)(512 + h * 128) * 512 + e;
      const float* qh = qy + h * 128;
      for (int i = 0; i < 128; ++i) acc += col[(long)i * 512] * qh[i];
      rr[h * 512 + e] = acc;
    }
  }
  if (tid < 4) {
    float acc = 0.f;
    const float* bk = in_b + 512 + tid * 128;
    const float* qh = qy + tid * 128;
    for (int i = 0; i < 128; ++i) acc += bk[i] * qh[i];
    cc[tid] = acc;
    mh[tid] = -1e30f;
    lh[tid] = 0.f;
  }
  __syncthreads();

  float u[8];
#pragma unroll
  for (int k = 0; k < 8; ++k) u[k] = 0.f;
  const float rscale = 0.08838834764831845f;  // 1/sqrt(128)

  for (int j0 = 0; j0 < np; j0 += 8) {
    int cnt = min(8, np - j0);
    // token tile
    for (int idx = tid; idx < cnt * 512; idx += 256) {
      int jj = idx >> 9, d = idx & 511;
      int jb = (j0 + jj) * p;
      float acc = sbias[d];
      const float* wr = wp + (long)d * p;
      for (int t = 0; t < p; ++t) acc += wr[t] * xb[jb + t];
      tok[jj * 512 + d] = acc;
    }
    __syncthreads();
    // scores: (h,jj) pairs x 8 e-chunks, shfl-reduce width 8
    {
      int pair = tid >> 3, chunk = tid & 7;
      int h = pair >> 3, jj = pair & 7;
      float partial = 0.f;
      if (jj < cnt) {
        const float* rh = rr + h * 512 + chunk * 64;
        const float* tv = tok + jj * 512 + chunk * 64;
        for (int e = 0; e < 64; ++e) partial += rh[e] * tv[e];
      }
      partial += __shfl_down(partial, 4, 8);
      partial += __shfl_down(partial, 2, 8);
      partial += __shfl_down(partial, 1, 8);
      if (chunk == 0) sc[pair] = (jj < cnt) ? (partial + cc[h]) * rscale : -1e30f;
    }
    __syncthreads();
    if (tid < 4) {  // online softmax bookkeeping
      int h = tid;
      float mt = -1e30f;
      for (int jj = 0; jj < cnt; ++jj) mt = fmaxf(mt, sc[h * 8 + jj]);
      float mn = fmaxf(mh[h], mt);
      float a = expf(mh[h] - mn);
      float l = lh[h] * a;
      for (int jj = 0; jj < 8; ++jj) {
        float wv = (jj < cnt) ? expf(sc[h * 8 + jj] - mn) : 0.f;
        wj[h * 8 + jj] = wv;
        l += wv;
      }
      lh[h] = l; mh[h] = mn; al[h] = a;
    }
    __syncthreads();
#pragma unroll
    for (int k = 0; k < 8; ++k) {  // u_h += sum_j w_j t_j (rescaled)
      int idx = (k << 8) + tid;
      int h = idx >> 9, e = idx & 511;
      float acc = u[k] * al[h];
      for (int jj = 0; jj < cnt; ++jj) acc += wj[h * 8 + jj] * tok[jj * 512 + e];
      u[k] = acc;
    }
    __syncthreads();
  }
#pragma unroll
  for (int k = 0; k < 8; ++k) {
    int idx = (k << 8) + tid;
    un[idx] = u[k] / lh[idx >> 9];
  }
  __syncthreads();
  // o = Wv @ un_h + bv
  for (int i = tid; i < 512; i += 256) {
    int h = i >> 7;
    const float4* wr = (const float4*)(in_w + (long)(1024 + i) * 512);
    const float* uh = un + h * 512;
    float acc = in_b[1024 + i];
    for (int e4 = 0; e4 < 128; ++e4) {
      float4 w4 = wr[e4];
      acc += w4.x * uh[e4 * 4 + 0] + w4.y * uh[e4 * 4 + 1] +
             w4.z * uh[e4 * 4 + 2] + w4.w * uh[e4 * 4 + 3];
    }
    ov[i] = acc;
  }
  __syncthreads();
  // y = tl + out_w @ o + out_b (into qy)
  for (int i = tid; i < 512; i += 256) {
    const float4* wr = (const float4*)(out_w + (long)i * 512);
    float acc = out_b[i];
    for (int e4 = 0; e4 < 128; ++e4) {
      float4 w4 = wr[e4];
      acc += w4.x * ov[e4 * 4 + 0] + w4.y * ov[e4 * 4 + 1] +
             w4.z * ov[e4 * 4 + 2] + w4.w * ov[e4 * 4 + 3];
    }
    qy[i] = tl[i] + acc;
  }
  __syncthreads();
  // layernorm (biased var, eps 1e-5)
  {
    float a = qy[tid], b2 = qy[tid + 256];
    float s = a + b2, sq = a * a + b2 * b2;
    for (int off = 32; off > 0; off >>= 1) {
      s += __shfl_down(s, off, 64);
      sq += __shfl_down(sq, off, 64);
    }
    int w = tid >> 6;
    if ((tid & 63) == 0) { red[w] = s; red[4 + w] = sq; }
    __syncthreads();
    if (tid == 0) {
      float S = red[0] + red[1] + red[2] + red[3];
      float Q = red[4] + red[5] + red[6] + red[7];
      float mu = S / 512.f;
      float var = Q / 512.f - mu * mu;
      stats[0] = mu;
      stats[1] = rsqrtf(var + 1e-5f);
    }
    __syncthreads();
    float mu = stats[0], rstd = stats[1];
    long base = ((long)(b * Cn + c)) * 1536 + slot * 512;
    for (int i = tid; i < 512; i += 256)
      comb[base + i] = (qy[i] - mu) * rstd * ln_g[i] + ln_b[i];
  }
}

// ---------------- stage D: trend ----------------
__global__ __launch_bounds__(256) void trend_kernel(const float* __restrict__ x,
                                                    const float* __restrict__ wt,
                                                    const float* __restrict__ sbias,
                                                    float* __restrict__ comb) {
  __shared__ float xb[Tn];
  int bid = blockIdx.x, tid = threadIdx.x;
  int b = bid >> 7, c = bid & 127;
  for (int t = tid; t < Tn; t += 256) xb[t] = x[((long)b * Tn + t) * Cn + c];
  __syncthreads();
  long base = ((long)(b * Cn + c)) * 1536 + 1024;
  for (int d = tid; d < 512; d += 256) {
    const float4* wr = (const float4*)(wt + (long)d * Tn);
    float acc = sbias[d];
    for (int t4 = 0; t4 < Tn / 4; ++t4) {
      float4 w4 = wr[t4];
      acc += w4.x * xb[t4 * 4 + 0] + w4.y * xb[t4 * 4 + 1] +
             w4.z * xb[t4 * 4 + 2] + w4.w * xb[t4 * 4 + 3];
    }
    comb[base + d] = acc;
  }
}

// ---------------- stage E: fusion MLP (exact gelu) ----------------
__global__ __launch_bounds__(256) void fusion_kernel(const float* __restrict__ comb,
                                                     const float* __restrict__ fw1,
                                                     const float* __restrict__ fb1,
                                                     const float* __restrict__ fw2,
                                                     const float* __restrict__ fb2,
                                                     float* __restrict__ out) {
  __shared__ float cb[1536];
  __shared__ float hh[512];
  int bid = blockIdx.x, tid = threadIdx.x;
  long cbase = (long)bid * 1536;
  for (int i = tid; i < 1536; i += 256) cb[i] = comb[cbase + i];
  __syncthreads();
  for (int d = tid; d < 512; d += 256) {
    const float4* wr = (const float4*)(fw1 + (long)d * 1536);
    float acc = fb1[d];
    for (int e4 = 0; e4 < 384; ++e4) {
      float4 w4 = wr[e4];
      acc += w4.x * cb[e4 * 4 + 0] + w4.y * cb[e4 * 4 + 1] +
             w4.z * cb[e4 * 4 + 2] + w4.w * cb[e4 * 4 + 3];
    }
    hh[d] = 0.5f * acc * (1.f + erff(acc * 0.7071067811865475f));
  }
  __syncthreads();
  long obase = (long)bid * 512;
  for (int i = tid; i < 512; i += 256) {
    const float4* wr = (const float4*)(fw2 + (long)i * 512);
    float acc = fb2[i];
    for (int e4 = 0; e4 < 128; ++e4) {
      float4 w4 = wr[e4];
      acc += w4.x * hh[e4 * 4 + 0] + w4.y * hh[e4 * 4 + 1] +
             w4.z * hh[e4 * 4 + 2] + w4.w * hh[e4 * 4 + 3];
    }
    out[obase + i] = acc;
  }
}

extern "C" void kernel_launch(void* const* d_in, const int* in_sizes, int n_in,
                              void* d_out, int out_size, void* d_ws, size_t ws_size,
                              hipStream_t stream) {
  const float* x    = (const float*)d_in[0];
  const float* a12  = (const float*)d_in[1];
  const float* a24  = (const float*)d_in[2];
  const float* a48  = (const float*)d_in[3];
  const float* a96  = (const float*)d_in[4];
  const float* sb   = (const float*)d_in[5];
  const float* g1iw = (const float*)d_in[6];
  const float* g1ib = (const float*)d_in[7];
  const float* g1ow = (const float*)d_in[8];
  const float* g1ob = (const float*)d_in[9];
  const float* g1lg = (const float*)d_in[10];
  const float* g1lb = (const float*)d_in[11];
  const float* g2iw = (const float*)d_in[12];
  const float* g2ib = (const float*)d_in[13];
  const float* g2ow = (const float*)d_in[14];
  const float* g2ob = (const float*)d_in[15];
  const float* g2lg = (const float*)d_in[16];
  const float* g2lb = (const float*)d_in[17];
  const float* fw1  = (const float*)d_in[18];
  const float* fb1  = (const float*)d_in[19];
  const float* fw2  = (const float*)d_in[20];
  const float* fb2  = (const float*)d_in[21];

  if (ws_size < (size_t)WS_FLOATS * sizeof(float)) return;  // need ~52 MB scratch

  float* ws     = (float*)d_ws;
  float* avg    = ws + OFF_AVG;
  int*   per    = (int*)(ws + OFF_PER);
  float* wtrend = ws + OFF_WTREND;
  float* wp     = ws + OFF_WP;
  float* comb   = ws + OFF_COMB;
  float* out    = (float*)d_out;

  acf_kernel<<<Cn, 256, 0, stream>>>(x, avg);
  periods_kernel<<<1, 128, 0, stream>>>(avg, per);
  build_weights_kernel<<<190, 256, 0, stream>>>(a12, a24, a48, a96, per, wp, wtrend);
  attn_kernel<<<Bn * Cn * 2, 256, 0, stream>>>(x, per, wp, sb,
      g1iw, g1ib, g1ow, g1ob, g1lg, g1lb,
      g2iw, g2ib, g2ow, g2ob, g2lg, g2lb, comb);
  trend_kernel<<<Bn * Cn, 256, 0, stream>>>(x, wtrend, sb, comb);
  fusion_kernel<<<Bn * Cn, 256, 0, stream>>>(comb, fw1, fb1, fw2, fb2, out);
}

// Round 2
// 2522.823 us; speedup vs baseline: 3.1248x; 3.1248x over previous
//
#include <hip/hip_runtime.h>
#include <math.h>

#define Bn 16
#define Tn 384
#define Cn 128

// ---------------- workspace layout (floats) ----------------
static constexpr long OFF_XT   = 0;         // 128*16*384
static constexpr long OFF_AVG  = 786432;    // 128*384
static constexpr long OFF_PER  = 835584;    // 256 ints
static constexpr long OFF_MP   = 835840;    // 1671300 (Mpinv for p=4..192 and 384)
static constexpr long OFF_WA   = 2507140;   // 552960: per (s,a): [QAt n*512][KAt 512*n][VA 512*n]
static constexpr long OFF_OVA  = 3060100;   // 737280: per (s,a): [ (h*n+k)*512 + i ]
static constexpr long OFF_CON  = 3797380;   // 3072: per slot: qc[512] kb[512] oc[512]
static constexpr long OFF_AT   = 3800452;   // 92160: anchors transposed, concat by a: [k*512+d]
static constexpr long OFF_COMB = 3892612;   // 2048*1536
static constexpr long OFF_H    = 7038340;   // 2048*512
static constexpr long WS_FLOATS = 8086916;  // ~32.4 MB

__host__ __device__ inline int nanch(int p) {
  if (p == 384) return 96;
  return (p <= 18) ? 12 : (p <= 36) ? 24 : (p <= 72) ? 48 : 96;
}
__host__ __device__ inline int apre(int n) {  // prefix of n over anchors {12,24,48,96}
  return (n == 12) ? 0 : (n == 24) ? 12 : (n == 48) ? 36 : 84;
}
__host__ __device__ inline long mpoff(int p) {
  if (p == 384) return 1634436L;
  long T = (long)(p - 1) * p / 2;
  if (p <= 18) return 12 * (T - 6);
  if (p <= 36) return 1980 + 24 * (T - 171);
  if (p <= 72) return 13860 + 48 * (T - 666);
  return 108036 + 96 * (T - 2628);
}

// interp row j of _interp_matrix(newl, oldl): nonzeros at (i0, 1-w), (i1, w)
__device__ inline void irow(int j, int newl, int oldl, int& i0, int& i1, float& w) {
  double src = ((double)j + 0.5) * (double)oldl / (double)newl - 0.5;
  if (src < 0.0) src = 0.0;
  double mx = (double)(oldl - 1);
  if (src > mx) src = mx;
  int a = (int)src;
  if (a > oldl - 1) a = oldl - 1;
  i0 = a;
  i1 = (a + 1 < oldl) ? (a + 1) : (oldl - 1);
  w = (float)(src - (double)a);
}

// ---------------- stage 0: transpose x -> xT[c][b][t] ----------------
__global__ __launch_bounds__(256) void transpose_kernel(const float* __restrict__ x,
                                                        float* __restrict__ xT) {
  __shared__ float tile[32 * 129];
  int bid = blockIdx.x;           // 16 b * 12 t-tiles
  int b = bid / 12, t0 = (bid % 12) * 32;
  int tid = threadIdx.x;
  for (int i = tid; i < 32 * 128; i += 256) {
    int tt = i >> 7, cc = i & 127;
    tile[tt * 129 + cc] = x[((long)b * Tn + t0 + tt) * Cn + cc];
  }
  __syncthreads();
  for (int i = tid; i < 32 * 128; i += 256) {
    int cc = i >> 5, tt = i & 31;
    xT[((long)cc * Bn + b) * Tn + t0 + tt] = tile[tt * 129 + cc];
  }
}

// ---------------- stage A1: batch-summed linear ACF per channel ----------------
__global__ __launch_bounds__(256) void acf_kernel(const float* __restrict__ xT,
                                                  float* __restrict__ avg) {
  __shared__ float xb[Bn * Tn];
  __shared__ float mean[Bn];
  int c = blockIdx.x, tid = threadIdx.x;
  for (int i = tid; i < Bn * Tn; i += 256) xb[i] = xT[(long)c * Bn * Tn + i];
  __syncthreads();
  if (tid < Bn) {
    float s = 0.f;
    for (int t = 0; t < Tn; ++t) s += xb[tid * Tn + t];
    mean[tid] = s / (float)Tn;
  }
  __syncthreads();
  for (int i = tid; i < Bn * Tn; i += 256) xb[i] -= mean[i / Tn];
  __syncthreads();
  for (int tau = tid; tau < Tn; tau += 256) {
    float acc = 0.f;
    for (int b = 0; b < Bn; ++b) {
      const float* xr = xb + b * Tn;
      float s = 0.f;
      for (int t = 0; t + tau < Tn; ++t) s += xr[t] * xr[t + tau];
      acc += s;
    }
    avg[(long)c * Tn + tau] = acc;
  }
}

// ---------------- stage A2: peak detect + top-2 + clip ----------------
__global__ __launch_bounds__(128) void periods_kernel(const float* __restrict__ avg,
                                                      int* __restrict__ per) {
  int c = threadIdx.x;
  if (c >= Cn) return;
  const float* a = avg + (long)c * Tn;
  const float NEG = -1e30f;
  float b1v = NEG, b2v = NEG;
  int b1i = 0, b2i = 0;
  for (int t = 4; t < Tn; ++t) {
    float v = a[t];
    float pv = (t == 4) ? NEG : a[t - 1];
    float nv = (t == Tn - 1) ? NEG : a[t + 1];
    bool peak = (v > pv) && (v > nv) && (v > 0.f);
    float m = peak ? v : NEG;
    if (m > b1v)      { b2v = b1v; b2i = b1i; b1v = m; b1i = t; }
    else if (m > b2v) { b2v = m; b2i = t; }
  }
  per[c * 2 + 0] = min(max(b1i, 4), 192);
  per[c * 2 + 1] = min(max(b2i, 4), 192);
}

// ---------------- stage C: build Mpinv (p x n) for needed p (and p=384) ----------------
__global__ __launch_bounds__(256) void build_mpinv_kernel(const int* __restrict__ per,
                                                          float* __restrict__ mp) {
  __shared__ float mat[96 * 97];
  __shared__ float fcol[96];
  __shared__ int flag;
  int tid = threadIdx.x;
  int p = (blockIdx.x < 189) ? (4 + (int)blockIdx.x) : 384;
  if (tid == 0) flag = (p == 384) ? 1 : 0;
  __syncthreads();
  if (p != 384) {
    for (int i = tid; i < Cn * 2; i += 256)
      if (per[i] == p) flag = 1;
  }
  __syncthreads();
  if (!flag) return;

  int n = nanch(p);
  int m = (p >= n) ? n : p;  // Gram dim
  float* dst = mp + mpoff(p);

  for (int idx = tid; idx < m * m; idx += 256)
    mat[(idx / m) * 97 + (idx % m)] = 0.f;
  __syncthreads();
  if (p >= n) {  // G = M^T M via scatter of 2-sparse rows
    for (int j = tid; j < p; j += 256) {
      int i0, i1; float w;
      irow(j, p, n, i0, i1, w);
      float w0 = 1.f - w;
      atomicAdd(&mat[i0 * 97 + i0], w0 * w0);
      atomicAdd(&mat[i0 * 97 + i1], w0 * w);
      atomicAdd(&mat[i1 * 97 + i0], w0 * w);
      atomicAdd(&mat[i1 * 97 + i1], w * w);
    }
  } else {       // H = M M^T
    for (int idx = tid; idx < m * m; idx += 256) {
      int r = idx / m, c2 = idx % m;
      int ri0, ri1, ci0, ci1; float rw, cw;
      irow(r, p, n, ri0, ri1, rw);
      irow(c2, p, n, ci0, ci1, cw);
      float rv0 = 1.f - rw, cv0 = 1.f - cw;
      float s = 0.f;
      if (ri0 == ci0) s += rv0 * cv0;
      if (ri0 == ci1) s += rv0 * cw;
      if (ri1 == ci0) s += rw * cv0;
      if (ri1 == ci1) s += rw * cw;
      mat[r * 97 + c2] = s;
    }
  }
  __syncthreads();
  // Gauss-Jordan inverse (SPD)
  for (int k = 0; k < m; ++k) {
    for (int r = tid; r < m; r += 256) fcol[r] = mat[r * 97 + k];
    __syncthreads();
    float ip = 1.f / fcol[k];
    for (int c2 = tid; c2 < m; c2 += 256)
      mat[k * 97 + c2] = (c2 == k) ? ip : mat[k * 97 + c2] * ip;
    __syncthreads();
    for (int idx = tid; idx < m * m; idx += 256) {
      int r = idx / m, c2 = idx % m;
      if (r != k) {
        float f = fcol[r];
        float rkv = mat[k * 97 + c2];
        mat[r * 97 + c2] = (c2 == k) ? (-f * rkv) : (mat[r * 97 + c2] - f * rkv);
      }
    }
    __syncthreads();
  }
  if (p >= n) {  // Mpinv = M @ Ginv
    for (int idx = tid; idx < p * n; idx += 256) {
      int t = idx / n, k = idx % n;
      int i0, i1; float w;
      irow(t, p, n, i0, i1, w);
      dst[idx] = (1.f - w) * mat[i0 * 97 + k] + w * mat[i1 * 97 + k];
    }
  } else {       // Mpinv = Hinv @ M
    for (int idx = tid; idx < p * n; idx += 256) {
      int t = idx / n, k = idx % n;
      float acc = 0.f;
      for (int j = 0; j < p; ++j) {
        int i0, i1; float w;
        irow(j, p, n, i0, i1, w);
        float f = mat[t * 97 + j];
        if (i0 == k) acc += f * (1.f - w);
        if (i1 == k) acc += f * w;
      }
      dst[idx] = acc;
    }
  }
}

// ---------------- stage P1: transpose anchors -> At[k*512+d] ----------------
__global__ __launch_bounds__(256) void at_kernel(const float* __restrict__ a12,
                                                 const float* __restrict__ a24,
                                                 const float* __restrict__ a48,
                                                 const float* __restrict__ a96,
                                                 float* __restrict__ at_tab) {
  __shared__ float tile[64 * 97];
  int bid = blockIdx.x;     // 4 anchors * 8 d-chunks
  int a = bid >> 3, d0 = (bid & 7) * 64;
  int n = (a == 0) ? 12 : (a == 1) ? 24 : (a == 2) ? 48 : 96;
  const float* src = (a == 0) ? a12 : (a == 1) ? a24 : (a == 2) ? a48 : a96;
  float* dst = at_tab + (long)apre(n) * 512;
  int tid = threadIdx.x;
  for (int i = tid; i < 64 * n; i += 256) {
    int dd = i / n, k = i - dd * n;
    tile[dd * 97 + k] = src[(long)(d0 + dd) * n + (long)k];
  }
  __syncthreads();
  for (int i = tid; i < n * 64; i += 256) {
    int k = i >> 6, dd = i & 63;
    dst[(long)k * 512 + d0 + dd] = tile[dd * 97 + k];
  }
}

// ---------------- stage P3: bias folds qc/kb/oc per slot ----------------
__global__ __launch_bounds__(256) void consts_kernel(
    const float* __restrict__ i1w, const float* __restrict__ i1b,
    const float* __restrict__ o1w, const float* __restrict__ o1b,
    const float* __restrict__ i2w, const float* __restrict__ i2b,
    const float* __restrict__ o2w, const float* __restrict__ o2b,
    const float* __restrict__ sb, float* __restrict__ cons) {
  __shared__ float sv[512];
  __shared__ float vb[512];
  int s = blockIdx.x, tid = threadIdx.x;
  const float* inw = s ? i2w : i1w;
  const float* inb = s ? i2b : i1b;
  const float* outw = s ? o2w : o1w;
  const float* outb = s ? o2b : o1b;
  float* dst = cons + s * 1536;
  for (int i = tid; i < 512; i += 256) sv[i] = sb[i];
  __syncthreads();
  int lane = tid & 63, w = tid >> 6;
  // rows: 0..511 -> qc, 512..1023 -> kb, 1024..1535 -> vb (LDS)
  for (int r = w; r < 1536; r += 4) {
    const float* row = inw + (long)r * 512;
    float part = 0.f;
    for (int kk = 0; kk < 8; ++kk) part += row[lane + 64 * kk] * sv[lane + 64 * kk];
    for (int off = 32; off > 0; off >>= 1) part += __shfl_down(part, off, 64);
    if (lane == 0) {
      float v = part + inb[r];
      if (r < 512) dst[r] = v;
      else if (r < 1024) dst[512 + (r - 512)] = v;
      else vb[r - 1024] = v;
    }
  }
  __syncthreads();
  for (int r = w; r < 512; r += 4) {
    const float* row = outw + (long)r * 512;
    float part = 0.f;
    for (int kk = 0; kk < 8; ++kk) part += row[lane + 64 * kk] * vb[lane + 64 * kk];
    for (int off = 32; off > 0; off >>= 1) part += __shfl_down(part, off, 64);
    if (lane == 0) dst[1024 + r] = part + outb[r];
  }
}

// ---------------- stage P2: WA = in_w @ anchor (1536 x n) per (s,a) ----------------
// rows 0..511 -> QAt (transposed, n x 512); 512..1023 -> KAt (row-major);
// 1024..1535 -> VA (row-major)
template <int N>
__global__ __launch_bounds__(256) void wa_gemm(const float* __restrict__ iw0,
                                               const float* __restrict__ iw1,
                                               const float* __restrict__ anchor,
                                               float* __restrict__ dst0,
                                               float* __restrict__ dst1) {
  constexpr int NQ = N / 4;
  constexpr int SM1 = 128 * 33 + 32 * (N + 1);
  constexpr int SM2 = N * 129;
  __shared__ float smem[SM1 > SM2 ? SM1 : SM2];
  float* Ws = smem;                 // [128][33]
  float* As = smem + 128 * 33;      // [32][N+1]
  int bid = blockIdx.x;
  int s = bid / 12, rt = bid % 12;
  const float* inw = s ? iw1 : iw0;
  float* dst = s ? dst1 : dst0;
  int r0 = rt * 128;
  int tid = threadIdx.x;
  int il = tid & 63, q = tid >> 6;
  float acc0[NQ], acc1[NQ];
#pragma unroll
  for (int j = 0; j < NQ; ++j) { acc0[j] = 0.f; acc1[j] = 0.f; }
  for (int d0 = 0; d0 < 512; d0 += 32) {
    for (int i = tid; i < 1024; i += 256) {
      int rr = i >> 3, dc = (i & 7) * 4;
      const float4 v = *(const float4*)&inw[(long)(r0 + rr) * 512 + d0 + dc];
      Ws[rr * 33 + dc + 0] = v.x; Ws[rr * 33 + dc + 1] = v.y;
      Ws[rr * 33 + dc + 2] = v.z; Ws[rr * 33 + dc + 3] = v.w;
    }
    for (int i = tid; i < 32 * N; i += 256) {
      int dd = i / N, k = i - dd * N;
      As[dd * (N + 1) + k] = anchor[(long)d0 * N + i];
    }
    __syncthreads();
    for (int dd = 0; dd < 32; ++dd) {
      float w0 = Ws[il * 33 + dd];
      float w1 = Ws[(il + 64) * 33 + dd];
      const float* ap = As + dd * (N + 1) + q * NQ;
#pragma unroll
      for (int j = 0; j < NQ; ++j) {
        float a = ap[j];
        acc0[j] += w0 * a;
        acc1[j] += w1 * a;
      }
    }
    __syncthreads();
  }
  if (r0 < 512) {  // QAt transpose path
    float* Ct = smem;  // [N][129]
#pragma unroll
    for (int j = 0; j < NQ; ++j) {
      int k = q * NQ + j;
      Ct[k * 129 + il] = acc0[j];
      Ct[k * 129 + il + 64] = acc1[j];
    }
    __syncthreads();
    float* qat = dst;
    for (int i = tid; i < N * 128; i += 256) {
      int k = i >> 7, rr = i & 127;
      qat[(long)k * 512 + r0 + rr] = Ct[k * 129 + rr];
    }
  } else if (r0 < 1024) {  // KAt direct
    float* kat = dst + (long)512 * N;
    int rk = r0 - 512 + il;
#pragma unroll
    for (int j = 0; j < NQ; ++j) {
      kat[(long)rk * N + q * NQ + j] = acc0[j];
      kat[(long)(rk + 64) * N + q * NQ + j] = acc1[j];
    }
  } else {  // VA direct
    float* va = dst + (long)1024 * N;
    int rk = r0 - 1024 + il;
#pragma unroll
    for (int j = 0; j < NQ; ++j) {
      va[(long)rk * N + q * NQ + j] = acc0[j];
      va[(long)(rk + 64) * N + q * NQ + j] = acc1[j];
    }
  }
}

// ---------------- stage P4: OVA_h = out_w[:,hblk] @ VA_h, stored transposed ----------------
template <int N>
__global__ __launch_bounds__(256) void ova_gemm(const float* __restrict__ ow0,
                                                const float* __restrict__ ow1,
                                                const float* __restrict__ wa0,
                                                const float* __restrict__ wa1,
                                                float* __restrict__ dst0,
                                                float* __restrict__ dst1) {
  constexpr int NQ = N / 4;
  constexpr int SM1 = 128 * 33 + 32 * (N + 1);
  constexpr int SM2 = N * 129;
  __shared__ float smem[SM1 > SM2 ? SM1 : SM2];
  float* Ws = smem;
  float* As = smem + 128 * 33;
  int bid = blockIdx.x;
  int s = bid >> 4, h = (bid >> 2) & 3, rt = bid & 3;
  const float* outw = s ? ow1 : ow0;
  const float* va = (s ? wa1 : wa0) + (long)1024 * N;  // VA rows (512 x N)
  float* dst = s ? dst1 : dst0;
  int r0 = rt * 128;
  int tid = threadIdx.x;
  int il = tid & 63, q = tid >> 6;
  float acc0[NQ], acc1[NQ];
#pragma unroll
  for (int j = 0; j < NQ; ++j) { acc0[j] = 0.f; acc1[j] = 0.f; }
  for (int d0 = 0; d0 < 128; d0 += 32) {
    for (int i = tid; i < 1024; i += 256) {
      int rr = i >> 3, dc = (i & 7) * 4;
      const float4 v = *(const float4*)&outw[(long)(r0 + rr) * 512 + h * 128 + d0 + dc];
      Ws[rr * 33 + dc + 0] = v.x; Ws[rr * 33 + dc + 1] = v.y;
      Ws[rr * 33 + dc + 2] = v.z; Ws[rr * 33 + dc + 3] = v.w;
    }
    for (int i = tid; i < 32 * N; i += 256) {
      int dd = i / N, k = i - dd * N;
      As[dd * (N + 1) + k] = va[(long)(h * 128 + d0) * N + i];
    }
    __syncthreads();
    for (int dd = 0; dd < 32; ++dd) {
      float w0 = Ws[il * 33 + dd];
      float w1 = Ws[(il + 64) * 33 + dd];
      const float* ap = As + dd * (N + 1) + q * NQ;
#pragma unroll
      for (int j = 0; j < NQ; ++j) {
        float a = ap[j];
        acc0[j] += w0 * a;
        acc1[j] += w1 * a;
      }
    }
    __syncthreads();
  }
  float* Ct = smem;
#pragma unroll
  for (int j = 0; j < NQ; ++j) {
    int k = q * NQ + j;
    Ct[k * 129 + il] = acc0[j];
    Ct[k * 129 + il + 64] = acc1[j];
  }
  __syncthreads();
  for (int i = tid; i < N * 128; i += 256) {
    int k = i >> 7, rr = i & 127;
    dst[(long)(h * N + k) * 512 + r0 + rr] = Ct[k * 129 + rr];
  }
}

// ---------------- stage B: fused anchor-folded attention, G=4 batches/block ----------------
__global__ __launch_bounds__(256) void attn_kernel(
    const float* __restrict__ xT, const int* __restrict__ per,
    const float* __restrict__ mp, const float* __restrict__ wa,
    const float* __restrict__ ova, const float* __restrict__ cons,
    const float* __restrict__ at_tab, const float* __restrict__ sb,
    const float* __restrict__ l1g, const float* __restrict__ l1b,
    const float* __restrict__ l2g, const float* __restrict__ l2b,
    float* __restrict__ comb) {
  __shared__ float xb[4 * 384];
  __shared__ float Z[4 * 1250];
  __shared__ float qy[4 * 512];
  __shared__ float arb[4 * 388];   // ar, later zh
  __shared__ float sc[4 * 388];
  __shared__ float qkc[16];
  __shared__ float red[8];

  int tid = threadIdx.x;
  int bid = blockIdx.x;
  int slot = bid & 1;
  int c = (bid >> 1) & 127;
  int b0 = (bid >> 8) * 4;
  int p = per[c * 2 + slot];
  int n = nanch(p);
  int np = Tn / p;
  int n1 = n + 1;
  float s = sqrtf((float)p / (float)n);
  const float rscale = 0.08838834764831845f;  // 1/sqrt(128)
  int pre = apre(n);
  const float* mpp = mp + mpoff(p);
  const float* qat = wa + (long)slot * 276480 + (long)pre * 1536;
  const float* kat = qat + (long)512 * n;
  const float* ovat = ova + (long)slot * 368640 + (long)pre * 2048;
  const float* atb = at_tab + (long)pre * 512;
  const float* qc = cons + slot * 1536;
  const float* kb = qc + 512;
  const float* oc = qc + 1024;
  const float* lng = slot ? l2g : l1g;
  const float* lnb = slot ? l2b : l1b;

  // Ph0: stage x rows
  for (int g = 0; g < 4; ++g)
    for (int t = tid; t < Tn; t += 256)
      xb[g * 384 + t] = xT[((long)c * Bn + b0 + g) * Tn + t];
  __syncthreads();

  // Ph1: Z = patches @ Mpinv  (np x n per batch)
  int znp = np * n;
  for (int g = 0; g < 4; ++g) {
    const float* xr0 = xb + g * 384;
    for (int idx = tid; idx < znp; idx += 256) {
      int j = idx / n, k = idx - j * n;
      const float* xr = xr0 + j * p;
      float acc = 0.f;
      for (int t = 0; t < p; ++t) acc += mpp[t * n + k] * xr[t];
      Z[g * 1250 + j * n1 + k] = acc;
    }
  }
  __syncthreads();

  int zlb0 = 0 * 1250 + (np - 1) * n1;
  int zlb1 = 1 * 1250 + (np - 1) * n1;
  int zlb2 = 2 * 1250 + (np - 1) * n1;
  int zlb3 = 3 * 1250 + (np - 1) * n1;

  // Ph2: q = s*QAt^T@Z_last + qc (batched over g; 2 rows/thread)
  {
    float a0[4] = {0.f, 0.f, 0.f, 0.f}, a1[4] = {0.f, 0.f, 0.f, 0.f};
    for (int k = 0; k < n; ++k) {
      float w0 = qat[(long)k * 512 + tid];
      float w1 = qat[(long)k * 512 + 256 + tid];
      float z0 = Z[zlb0 + k], z1 = Z[zlb1 + k], z2 = Z[zlb2 + k], z3 = Z[zlb3 + k];
      a0[0] += w0 * z0; a0[1] += w0 * z1; a0[2] += w0 * z2; a0[3] += w0 * z3;
      a1[0] += w1 * z0; a1[1] += w1 * z1; a1[2] += w1 * z2; a1[3] += w1 * z3;
    }
    float qc0 = qc[tid], qc1 = qc[256 + tid];
#pragma unroll
    for (int g = 0; g < 4; ++g) {
      qy[g * 512 + tid] = qc0 + s * a0[g];
      qy[g * 512 + 256 + tid] = qc1 + s * a1[g];
    }
  }
  __syncthreads();

  // Ph2b: qkc[g][h] = q_h . kb_h
  if (tid < 16) {
    int g = tid >> 2, h = tid & 3;
    float acc = 0.f;
    for (int i = 0; i < 128; ++i) acc += qy[g * 512 + h * 128 + i] * kb[h * 128 + i];
    qkc[g * 4 + h] = acc;
  }

  // Ph3: ar[g][h][k] = s * sum_i KAt[(h*128+i)*n+k] * q[g][h*128+i]
  {
    int tot = 16 * n;
    for (int idx = tid; idx < tot; idx += 256) {
      int g = idx / (4 * n);
      int r = idx - g * 4 * n;
      int h = r / n, k = r - h * n;
      float acc = 0.f;
      const float* kp = kat + (long)(h * 128) * n + k;
      const float* qp = qy + g * 512 + h * 128;
      for (int i = 0; i < 128; ++i) acc += kp[(long)i * n] * qp[i];
      arb[g * 388 + h * n + k] = s * acc;
    }
  }
  __syncthreads();

  // Ph4: scores
  {
    int tot = 16 * np;
    for (int idx = tid; idx < tot; idx += 256) {
      int g = idx / (4 * np);
      int r = idx - g * 4 * np;
      int h = r / np, j = r - h * np;
      const float* ap = arb + g * 388 + h * n;
      const float* zp = Z + g * 1250 + j * n1;
      float acc = 0.f;
      for (int k = 0; k < n; ++k) acc += ap[k] * zp[k];
      sc[g * 388 + h * np + j] = (acc + qkc[g * 4 + h]) * rscale;
    }
  }
  __syncthreads();

  // Ph5: softmax per (g,h), normalized probs in place
  if (tid < 16) {
    int g = tid >> 2, h = tid & 3;
    float* sp = sc + g * 388 + h * np;
    float m = -1e30f;
    for (int j = 0; j < np; ++j) m = fmaxf(m, sp[j]);
    float l = 0.f;
    for (int j = 0; j < np; ++j) { float e = expf(sp[j] - m); sp[j] = e; l += e; }
    float il = 1.f / l;
    for (int j = 0; j < np; ++j) sp[j] *= il;
  }
  __syncthreads();

  // Ph6: zh[g][h][k] = sum_j prob * Z[g][j][k]  (into arb)
  {
    int tot = 16 * n;
    for (int idx = tid; idx < tot; idx += 256) {
      int g = idx / (4 * n);
      int r = idx - g * 4 * n;
      int h = r / n, k = r - h * n;
      const float* sp = sc + g * 388 + h * np;
      const float* zp = Z + g * 1250 + k;
      float acc = 0.f;
      for (int j = 0; j < np; ++j) acc += sp[j] * zp[j * n1];
      arb[g * 388 + h * n + k] = acc;
    }
  }
  __syncthreads();

  // Ph7: y = s*(At@Z_last + sum_h OVAt@zh) + sb + oc  (into qy)
  {
    float a0[4] = {0.f, 0.f, 0.f, 0.f}, a1[4] = {0.f, 0.f, 0.f, 0.f};
    for (int k = 0; k < n; ++k) {
      float w0 = atb[(long)k * 512 + tid];
      float w1 = atb[(long)k * 512 + 256 + tid];
      float z0 = Z[zlb0 + k], z1 = Z[zlb1 + k], z2 = Z[zlb2 + k], z3 = Z[zlb3 + k];
      a0[0] += w0 * z0; a0[1] += w0 * z1; a0[2] += w0 * z2; a0[3] += w0 * z3;
      a1[0] += w1 * z0; a1[1] += w1 * z1; a1[2] += w1 * z2; a1[3] += w1 * z3;
    }
    for (int h = 0; h < 4; ++h) {
      const float* op = ovat + (long)(h * n) * 512;
      const float* zh0 = arb + 0 * 388 + h * n;
      const float* zh1 = arb + 1 * 388 + h * n;
      const float* zh2 = arb + 2 * 388 + h * n;
      const float* zh3 = arb + 3 * 388 + h * n;
      for (int k = 0; k < n; ++k) {
        float w0 = op[(long)k * 512 + tid];
        float w1 = op[(long)k * 512 + 256 + tid];
        float z0 = zh0[k], z1 = zh1[k], z2 = zh2[k], z3 = zh3[k];
        a0[0] += w0 * z0; a0[1] += w0 * z1; a0[2] += w0 * z2; a0[3] += w0 * z3;
        a1[0] += w1 * z0; a1[1] += w1 * z1; a1[2] += w1 * z2; a1[3] += w1 * z3;
      }
    }
    float s0 = sb[tid] + oc[tid];
    float s1 = sb[256 + tid] + oc[256 + tid];
    __syncthreads();  // qy reads done long ago; barrier before overwrite for safety
#pragma unroll
    for (int g = 0; g < 4; ++g) {
      qy[g * 512 + tid] = s * a0[g] + s0;
      qy[g * 512 + 256 + tid] = s * a1[g] + s1;
    }
  }
  __syncthreads();

  // Ph8: layernorm per batch row, write comb
  {
    int w = tid >> 6, lane = tid & 63;
    int g = w;
    float sm = 0.f, sq = 0.f;
    for (int kk = 0; kk < 8; ++kk) {
      float v = qy[g * 512 + lane + 64 * kk];
      sm += v; sq += v * v;
    }
    for (int off = 32; off > 0; off >>= 1) {
      sm += __shfl_down(sm, off, 64);
      sq += __shfl_down(sq, off, 64);
    }
    if (lane == 0) { red[g * 2] = sm; red[g * 2 + 1] = sq; }
    __syncthreads();
    float mu = red[g * 2] / 512.f;
    float var = red[g * 2 + 1] / 512.f - mu * mu;
    float rstd = rsqrtf(var + 1e-5f);
    long base = ((long)(b0 + g) * Cn + c) * 1536 + slot * 512;
    for (int kk = 0; kk < 8; ++kk) {
      int i = lane + 64 * kk;
      comb[base + i] = (qy[g * 512 + i] - mu) * rstd * lng[i] + lnb[i];
    }
  }
}

// ---------------- stage D: trend (anchor-folded) ----------------
__global__ __launch_bounds__(256) void trend_kernel(const float* __restrict__ xT,
                                                    const float* __restrict__ mp384,
                                                    const float* __restrict__ at96,
                                                    const float* __restrict__ sb,
                                                    float* __restrict__ comb) {
  __shared__ float xb[Bn * Tn];
  __shared__ float Ztr[Bn * 97];
  int c = blockIdx.x, tid = threadIdx.x;
  for (int i = tid; i < Bn * Tn; i += 256) xb[i] = xT[(long)c * Bn * Tn + i];
  __syncthreads();
  for (int idx = tid; idx < Bn * 96; idx += 256) {
    int b = idx / 96, k = idx - b * 96;
    const float* xr = xb + b * Tn;
    float acc = 0.f;
    for (int t = 0; t < Tn; ++t) acc += mp384[t * 96 + k] * xr[t];
    Ztr[b * 97 + k] = acc;
  }
  __syncthreads();
  float acc0[Bn], acc1[Bn];
#pragma unroll
  for (int b = 0; b < Bn; ++b) { acc0[b] = 0.f; acc1[b] = 0.f; }
  for (int k = 0; k < 96; ++k) {
    float w0 = at96[(long)k * 512 + tid];
    float w1 = at96[(long)k * 512 + 256 + tid];
#pragma unroll
    for (int b = 0; b < Bn; ++b) {
      float z = Ztr[b * 97 + k];
      acc0[b] += w0 * z;
      acc1[b] += w1 * z;
    }
  }
  float s0 = sb[tid], s1 = sb[256 + tid];
#pragma unroll
  for (int b = 0; b < Bn; ++b) {
    long base = ((long)b * Cn + c) * 1536 + 1024;
    comb[base + tid] = 2.f * acc0[b] + s0;          // sqrt(384/96)=2
    comb[base + 256 + tid] = 2.f * acc1[b] + s1;
  }
}

// ---------------- stage E: tiled GEMM  C = act(A @ W^T + bias) ----------------
template <bool GELU>
__global__ __launch_bounds__(256) void fused_gemm(const float* __restrict__ A,
                                                  const float* __restrict__ W,
                                                  const float* __restrict__ bias,
                                                  float* __restrict__ C,
                                                  int N, int K) {
  __shared__ float As[32 * 68];
  __shared__ float Ws[32 * 68];
  int nb = N >> 6;
  int m0 = (blockIdx.x / nb) * 64, n0 = (blockIdx.x % nb) * 64;
  int tid = threadIdx.x;
  int tm = tid & 15, tn = tid >> 4;
  float acc[4][4];
#pragma unroll
  for (int i = 0; i < 4; ++i)
#pragma unroll
    for (int j = 0; j < 4; ++j) acc[i][j] = 0.f;
  int row = tid >> 3, kc = (tid & 7) * 4;
  for (int k0 = 0; k0 < K; k0 += 32) {
    {
      float4 v = *(const float4*)&A[(long)(m0 + row) * K + k0 + kc];
      As[(kc + 0) * 68 + row] = v.x; As[(kc + 1) * 68 + row] = v.y;
      As[(kc + 2) * 68 + row] = v.z; As[(kc + 3) * 68 + row] = v.w;
      v = *(const float4*)&A[(long)(m0 + row + 32) * K + k0 + kc];
      As[(kc + 0) * 68 + row + 32] = v.x; As[(kc + 1) * 68 + row + 32] = v.y;
      As[(kc + 2) * 68 + row + 32] = v.z; As[(kc + 3) * 68 + row + 32] = v.w;
      v = *(const float4*)&W[(long)(n0 + row) * K + k0 + kc];
      Ws[(kc + 0) * 68 + row] = v.x; Ws[(kc + 1) * 68 + row] = v.y;
      Ws[(kc + 2) * 68 + row] = v.z; Ws[(kc + 3) * 68 + row] = v.w;
      v = *(const float4*)&W[(long)(n0 + row + 32) * K + k0 + kc];
      Ws[(kc + 0) * 68 + row + 32] = v.x; Ws[(kc + 1) * 68 + row + 32] = v.y;
      Ws[(kc + 2) * 68 + row + 32] = v.z; Ws[(kc + 3) * 68 + row + 32] = v.w;
    }
    __syncthreads();
    for (int kk = 0; kk < 32; ++kk) {
      float4 a = *(const float4*)&As[kk * 68 + tm * 4];
      float4 w = *(const float4*)&Ws[kk * 68 + tn * 4];
      acc[0][0] += a.x * w.x; acc[0][1] += a.x * w.y; acc[0][2] += a.x * w.z; acc[0][3] += a.x * w.w;
      acc[1][0] += a.y * w.x; acc[1][1] += a.y * w.y; acc[1][2] += a.y * w.z; acc[1][3] += a.y * w.w;
      acc[2][0] += a.z * w.x; acc[2][1] += a.z * w.y; acc[2][2] += a.z * w.z; acc[2][3] += a.z * w.w;
      acc[3][0] += a.w * w.x; acc[3][1] += a.w * w.y; acc[3][2] += a.w * w.z; acc[3][3] += a.w * w.w;
    }
    __syncthreads();
  }
  float b0v = bias[n0 + tn * 4 + 0], b1v = bias[n0 + tn * 4 + 1];
  float b2v = bias[n0 + tn * 4 + 2], b3v = bias[n0 + tn * 4 + 3];
#pragma unroll
  for (int mi = 0; mi < 4; ++mi) {
    float4 o;
    o.x = acc[mi][0] + b0v; o.y = acc[mi][1] + b1v;
    o.z = acc[mi][2] + b2v; o.w = acc[mi][3] + b3v;
    if (GELU) {
      o.x = 0.5f * o.x * (1.f + erff(o.x * 0.7071067811865475f));
      o.y = 0.5f * o.y * (1.f + erff(o.y * 0.7071067811865475f));
      o.z = 0.5f * o.z * (1.f + erff(o.z * 0.7071067811865475f));
      o.w = 0.5f * o.w * (1.f + erff(o.w * 0.7071067811865475f));
    }
    *(float4*)&C[(long)(m0 + tm * 4 + mi) * N + n0 + tn * 4] = o;
  }
}

extern "C" void kernel_launch(void* const* d_in, const int* in_sizes, int n_in,
                              void* d_out, int out_size, void* d_ws, size_t ws_size,
                              hipStream_t stream) {
  const float* x    = (const float*)d_in[0];
  const float* a12  = (const float*)d_in[1];
  const float* a24  = (const float*)d_in[2];
  const float* a48  = (const float*)d_in[3];
  const float* a96  = (const float*)d_in[4];
  const float* sb   = (const float*)d_in[5];
  const float* g1iw = (const float*)d_in[6];
  const float* g1ib = (const float*)d_in[7];
  const float* g1ow = (const float*)d_in[8];
  const float* g1ob = (const float*)d_in[9];
  const float* g1lg = (const float*)d_in[10];
  const float* g1lb = (const float*)d_in[11];
  const float* g2iw = (const float*)d_in[12];
  const float* g2ib = (const float*)d_in[13];
  const float* g2ow = (const float*)d_in[14];
  const float* g2ob = (const float*)d_in[15];
  const float* g2lg = (const float*)d_in[16];
  const float* g2lb = (const float*)d_in[17];
  const float* fw1  = (const float*)d_in[18];
  const float* fb1  = (const float*)d_in[19];
  const float* fw2  = (const float*)d_in[20];
  const float* fb2  = (const float*)d_in[21];

  if (ws_size < (size_t)WS_FLOATS * sizeof(float)) return;

  float* ws   = (float*)d_ws;
  float* xT   = ws + OFF_XT;
  float* avg  = ws + OFF_AVG;
  int*   per  = (int*)(ws + OFF_PER);
  float* mp   = ws + OFF_MP;
  float* wa   = ws + OFF_WA;
  float* ova  = ws + OFF_OVA;
  float* cons = ws + OFF_CON;
  float* atb  = ws + OFF_AT;
  float* comb = ws + OFF_COMB;
  float* hbuf = ws + OFF_H;
  float* out  = (float*)d_out;

  transpose_kernel<<<192, 256, 0, stream>>>(x, xT);
  acf_kernel<<<Cn, 256, 0, stream>>>(xT, avg);
  periods_kernel<<<1, 128, 0, stream>>>(avg, per);
  build_mpinv_kernel<<<190, 256, 0, stream>>>(per, mp);
  at_kernel<<<32, 256, 0, stream>>>(a12, a24, a48, a96, atb);
  consts_kernel<<<2, 256, 0, stream>>>(g1iw, g1ib, g1ow, g1ob,
                                       g2iw, g2ib, g2ow, g2ob, sb, cons);
  // WA per anchor (grid: 2 slots * 12 row-tiles)
  wa_gemm<12><<<24, 256, 0, stream>>>(g1iw, g2iw, a12, wa + 0L, wa + 276480L);
  wa_gemm<24><<<24, 256, 0, stream>>>(g1iw, g2iw, a24, wa + 12L * 1536, wa + 276480L + 12L * 1536);
  wa_gemm<48><<<24, 256, 0, stream>>>(g1iw, g2iw, a48, wa + 36L * 1536, wa + 276480L + 36L * 1536);
  wa_gemm<96><<<24, 256, 0, stream>>>(g1iw, g2iw, a96, wa + 84L * 1536, wa + 276480L + 84L * 1536);
  // OVA per anchor (grid: 2 slots * 4 heads * 4 row-tiles)
  ova_gemm<12><<<32, 256, 0, stream>>>(g1ow, g2ow, wa + 0L, wa + 276480L,
                                       ova + 0L, ova + 368640L);
  ova_gemm<24><<<32, 256, 0, stream>>>(g1ow, g2ow, wa + 12L * 1536, wa + 276480L + 12L * 1536,
                                       ova + 12L * 2048, ova + 368640L + 12L * 2048);
  ova_gemm<48><<<32, 256, 0, stream>>>(g1ow, g2ow, wa + 36L * 1536, wa + 276480L + 36L * 1536,
                                       ova + 36L * 2048, ova + 368640L + 36L * 2048);
  ova_gemm<96><<<32, 256, 0, stream>>>(g1ow, g2ow, wa + 84L * 1536, wa + 276480L + 84L * 1536,
                                       ova + 84L * 2048, ova + 368640L + 84L * 2048);

  attn_kernel<<<1024, 256, 0, stream>>>(xT, per, mp, wa, ova, cons, atb, sb,
                                        g1lg, g1lb, g2lg, g2lb, comb);
  trend_kernel<<<Cn, 256, 0, stream>>>(xT, mp + 1634436L, atb + 84L * 512, sb, comb);
  fused_gemm<true><<<256, 256, 0, stream>>>(comb, fw1, fb1, hbuf, 512, 1536);
  fused_gemm<false><<<256, 256, 0, stream>>>(hbuf, fw2, fb2, out, 512, 512);
}

// Round 3
// 1492.729 us; speedup vs baseline: 5.2812x; 1.6901x over previous
//
#include <hip/hip_runtime.h>
#include <math.h>

#define Bn 16
#define Tn 384
#define Cn 128

// ---------------- workspace layout (floats) ----------------
static constexpr long OFF_XT   = 0;         // 128*16*384
static constexpr long OFF_AVG  = 786432;    // 384*128 (transposed: [t][c])
static constexpr long OFF_PER  = 835584;    // 256 ints
static constexpr long OFF_MP   = 835840;    // 1671300 (Mpinv for p=4..192 and 384)
static constexpr long OFF_WA   = 2507140;   // 552960: per (s,a): [QAt n*512][KAt 512*n][VA 512*n]
static constexpr long OFF_OVA  = 3060100;   // 737280: per (s,a): [ (h*n+k)*512 + i ]
static constexpr long OFF_CON  = 3797380;   // 3072: per slot: qc[512] kb[512] oc[512]
static constexpr long OFF_AT   = 3800452;   // 92160: anchors transposed, concat by a: [k*512+d]
static constexpr long OFF_COMB = 3892612;   // 2048*1536
static constexpr long OFF_H    = 7038340;   // 2048*512
static constexpr long WS_FLOATS = 8086916;  // ~32.4 MB

__host__ __device__ inline int nanch(int p) {
  if (p == 384) return 96;
  return (p <= 18) ? 12 : (p <= 36) ? 24 : (p <= 72) ? 48 : 96;
}
__host__ __device__ inline int apre(int n) {  // prefix of n over anchors {12,24,48,96}
  return (n == 12) ? 0 : (n == 24) ? 12 : (n == 48) ? 36 : 84;
}
__host__ __device__ inline long mpoff(int p) {
  if (p == 384) return 1634436L;
  long T = (long)(p - 1) * p / 2;
  if (p <= 18) return 12 * (T - 6);
  if (p <= 36) return 1980 + 24 * (T - 171);
  if (p <= 72) return 13860 + 48 * (T - 666);
  return 108036 + 96 * (T - 2628);
}

// interp row j of _interp_matrix(newl, oldl): nonzeros at (i0, 1-w), (i1, w)
__device__ inline void irow(int j, int newl, int oldl, int& i0, int& i1, float& w) {
  double src = ((double)j + 0.5) * (double)oldl / (double)newl - 0.5;
  if (src < 0.0) src = 0.0;
  double mx = (double)(oldl - 1);
  if (src > mx) src = mx;
  int a = (int)src;
  if (a > oldl - 1) a = oldl - 1;
  i0 = a;
  i1 = (a + 1 < oldl) ? (a + 1) : (oldl - 1);
  w = (float)(src - (double)a);
}

// ---------------- stage 0: transpose x -> xT[c][b][t] ----------------
__global__ __launch_bounds__(256) void transpose_kernel(const float* __restrict__ x,
                                                        float* __restrict__ xT) {
  __shared__ float tile[32 * 129];
  int bid = blockIdx.x;           // 16 b * 12 t-tiles
  int b = bid / 12, t0 = (bid % 12) * 32;
  int tid = threadIdx.x;
  for (int i = tid; i < 32 * 128; i += 256) {
    int tt = i >> 7, cc = i & 127;
    tile[tt * 129 + cc] = x[((long)b * Tn + t0 + tt) * Cn + cc];
  }
  __syncthreads();
  for (int i = tid; i < 32 * 128; i += 256) {
    int cc = i >> 5, tt = i & 31;
    xT[((long)cc * Bn + b) * Tn + t0 + tt] = tile[tt * 129 + cc];
  }
}

// ---------------- stage A1: batch-summed linear ACF per channel ----------------
// writes avgT[t][c] (transposed) so periods_kernel reads coalesced
__global__ __launch_bounds__(256) void acf_kernel(const float* __restrict__ xT,
                                                  float* __restrict__ avgT) {
  __shared__ float xb[Bn * Tn];
  __shared__ float mean[Bn];
  int c = blockIdx.x, tid = threadIdx.x;
  for (int i = tid; i < Bn * Tn; i += 256) xb[i] = xT[(long)c * Bn * Tn + i];
  __syncthreads();
  if (tid < Bn) {
    float s = 0.f;
    for (int t = 0; t < Tn; ++t) s += xb[tid * Tn + t];
    mean[tid] = s / (float)Tn;
  }
  __syncthreads();
  for (int i = tid; i < Bn * Tn; i += 256) xb[i] -= mean[i / Tn];
  __syncthreads();
  for (int tau = tid; tau < Tn; tau += 256) {
    float acc = 0.f;
    for (int b = 0; b < Bn; ++b) {
      const float* xr = xb + b * Tn;
      float s = 0.f;
      for (int t = 0; t + tau < Tn; ++t) s += xr[t] * xr[t + tau];
      acc += s;
    }
    avgT[(long)tau * Cn + c] = acc;
  }
}

// ---------------- stage A2: peak detect + top-2 + clip ----------------
__global__ __launch_bounds__(128) void periods_kernel(const float* __restrict__ avgT,
                                                      int* __restrict__ per) {
  int c = threadIdx.x;
  if (c >= Cn) return;
  const float* a = avgT + c;
  const float NEG = -1e30f;
  float b1v = NEG, b2v = NEG;
  int b1i = 0, b2i = 0;
  float pv = NEG;                  // avg[3] masked to -inf
  float v = a[4L * Cn];
  for (int t = 4; t < Tn; ++t) {
    float nv = (t == Tn - 1) ? NEG : a[(long)(t + 1) * Cn];  // circular next of last is -inf
    bool peak = (v > pv) && (v > nv) && (v > 0.f);
    float m = peak ? v : NEG;
    if (m > b1v)      { b2v = b1v; b2i = b1i; b1v = m; b1i = t; }
    else if (m > b2v) { b2v = m; b2i = t; }
    pv = v; v = nv;
  }
  per[c * 2 + 0] = min(max(b1i, 4), 192);
  per[c * 2 + 1] = min(max(b2i, 4), 192);
}

// ---------------- stage C: build Mpinv (p x n) via tridiagonal Thomas ----------------
// Both Grams are SPD tridiagonal (interp rows are 2-sparse with adjacent cols).
__global__ __launch_bounds__(256) void build_mpinv_kernel(const int* __restrict__ per,
                                                          float* __restrict__ mp) {
  __shared__ int ii[384];
  __shared__ float ww[384];
  __shared__ float dd_[96], ee[96], cp[96], idt[96];
  __shared__ float ginv[96 * 97];
  __shared__ float outp[96 * 97];
  __shared__ int flag;
  int tid = threadIdx.x;
  int p = (blockIdx.x < 189) ? (4 + (int)blockIdx.x) : 384;
  if (tid == 0) flag = (p == 384) ? 1 : 0;
  __syncthreads();
  if (p != 384) {
    for (int i = tid; i < Cn * 2; i += 256)
      if (per[i] == p) flag = 1;
  }
  __syncthreads();
  if (!flag) return;

  int n = nanch(p);
  int m = (p >= n) ? n : p;  // Gram dim
  float* dst = mp + mpoff(p);

  // irow tables
  for (int j = tid; j < p; j += 256) {
    int i0, i1; float w;
    irow(j, p, n, i0, i1, w);
    ii[j] = i0; ww[j] = w;
  }
  for (int i = tid; i < m; i += 256) { dd_[i] = 0.f; ee[i] = 0.f; }
  __syncthreads();

  if (p >= n) {  // G = M^T M (n x n tridiag), scatter rows
    for (int j = tid; j < p; j += 256) {
      int i0 = ii[j]; float w = ww[j];
      int i1 = min(i0 + 1, n - 1);
      if (i1 == i0) {
        atomicAdd(&dd_[i0], 1.0f);   // merged entry value (1-w)+w = 1
      } else {
        float a = 1.f - w, b = w;
        atomicAdd(&dd_[i0], a * a);
        atomicAdd(&dd_[i1], b * b);
        atomicAdd(&ee[i0], a * b);
      }
    }
  } else {       // H = M M^T (p x p tridiag), one writer per row
    for (int r = tid; r < p; r += 256) {
      int i0 = ii[r]; float w = ww[r];
      int i1 = min(i0 + 1, n - 1);
      float a, b; int c0 = i0, c1 = i1;
      if (i1 == i0) { a = 1.f; b = 0.f; c1 = -1; }
      else { a = 1.f - w; b = w; }
      dd_[r] = a * a + b * b;
      if (r < p - 1) {
        int j0 = ii[r + 1]; float w2 = ww[r + 1];
        int j1 = min(j0 + 1, n - 1);
        float a2, b2; int d0 = j0, d1 = j1;
        if (j1 == j0) { a2 = 1.f; b2 = 0.f; d1 = -2; }
        else { a2 = 1.f - w2; b2 = w2; }
        float s = 0.f;
        if (c0 == d0) s += a * a2;
        if (c0 == d1) s += a * b2;
        if (c1 == d0) s += b * a2;
        if (c1 == d1) s += b * b2;
        ee[r] = s;
      }
    }
  }
  __syncthreads();
  // LDL^T factorization (serial, m <= 96)
  if (tid == 0) {
    float dt = dd_[0];
    idt[0] = 1.f / dt;
    for (int i = 1; i < m; ++i) {
      float c = ee[i - 1] * idt[i - 1];
      cp[i - 1] = c;
      dt = dd_[i] - ee[i - 1] * c;
      idt[i] = 1.f / dt;
    }
  }
  __syncthreads();
  // per-column Thomas solve: thread j computes Ginv[:, j]
  if (tid < m) {
    int j = tid;
    float z = 1.f;
    ginv[j * 97 + j] = 1.f;
    for (int i = j + 1; i < m; ++i) {
      z = -cp[i - 1] * z;
      ginv[i * 97 + j] = z;
    }
    float xn = ginv[(m - 1) * 97 + j] * idt[m - 1];
    ginv[(m - 1) * 97 + j] = xn;
    for (int i = m - 2; i >= 0; --i) {
      float zi = (i >= j) ? ginv[i * 97 + j] : 0.f;
      xn = zi * idt[i] - cp[i] * xn;
      ginv[i * 97 + j] = xn;
    }
  }
  __syncthreads();
  if (p >= n) {  // Mpinv = M @ Ginv (row t = interp of two Ginv rows)
    for (int idx = tid; idx < p * n; idx += 256) {
      int t = idx / n, k = idx - t * n;
      int i0 = ii[t]; float w = ww[t];
      int i1 = min(i0 + 1, n - 1);
      dst[idx] = (1.f - w) * ginv[i0 * 97 + k] + w * ginv[i1 * 97 + k];
    }
  } else {       // Mpinv = Hinv @ M (scatter M's 2-sparse rows), one thread per row t
    for (int t = tid; t < p; t += 256) {
      for (int k = 0; k < n; ++k) outp[t * 97 + k] = 0.f;
      for (int j = 0; j < p; ++j) {
        float hv = ginv[t * 97 + j];
        int i0 = ii[j]; float w = ww[j];
        int i1 = min(i0 + 1, n - 1);
        outp[t * 97 + i0] += hv * (1.f - w);
        outp[t * 97 + i1] += hv * w;
      }
    }
    __syncthreads();
    for (int idx = tid; idx < p * n; idx += 256) {
      int t = idx / n, k = idx - t * n;
      dst[idx] = outp[t * 97 + k];
    }
  }
}

// ---------------- stage P1: transpose anchors -> At[k*512+d] ----------------
__global__ __launch_bounds__(256) void at_kernel(const float* __restrict__ a12,
                                                 const float* __restrict__ a24,
                                                 const float* __restrict__ a48,
                                                 const float* __restrict__ a96,
                                                 float* __restrict__ at_tab) {
  __shared__ float tile[64 * 97];
  int bid = blockIdx.x;     // 4 anchors * 8 d-chunks
  int a = bid >> 3, d0 = (bid & 7) * 64;
  int n = (a == 0) ? 12 : (a == 1) ? 24 : (a == 2) ? 48 : 96;
  const float* src = (a == 0) ? a12 : (a == 1) ? a24 : (a == 2) ? a48 : a96;
  float* dst = at_tab + (long)apre(n) * 512;
  int tid = threadIdx.x;
  for (int i = tid; i < 64 * n; i += 256) {
    int dd = i / n, k = i - dd * n;
    tile[dd * 97 + k] = src[(long)(d0 + dd) * n + (long)k];
  }
  __syncthreads();
  for (int i = tid; i < n * 64; i += 256) {
    int k = i >> 6, dd = i & 63;
    dst[(long)k * 512 + d0 + dd] = tile[dd * 97 + k];
  }
}

// ---------------- stage P3: bias folds qc/kb/oc per slot (16 waves) ----------------
__global__ __launch_bounds__(1024) void consts_kernel(
    const float* __restrict__ i1w, const float* __restrict__ i1b,
    const float* __restrict__ o1w, const float* __restrict__ o1b,
    const float* __restrict__ i2w, const float* __restrict__ i2b,
    const float* __restrict__ o2w, const float* __restrict__ o2b,
    const float* __restrict__ sb, float* __restrict__ cons) {
  __shared__ float sv[512];
  __shared__ float vb[512];
  int s = blockIdx.x, tid = threadIdx.x;
  const float* inw = s ? i2w : i1w;
  const float* inb = s ? i2b : i1b;
  const float* outw = s ? o2w : o1w;
  const float* outb = s ? o2b : o1b;
  float* dst = cons + s * 1536;
  if (tid < 512) sv[tid] = sb[tid];
  __syncthreads();
  int lane = tid & 63, w = tid >> 6;  // 16 waves
  for (int r = w; r < 1536; r += 16) {
    const float* row = inw + (long)r * 512;
    float part = 0.f;
    for (int kk = 0; kk < 8; ++kk) part += row[lane + 64 * kk] * sv[lane + 64 * kk];
    for (int off = 32; off > 0; off >>= 1) part += __shfl_down(part, off, 64);
    if (lane == 0) {
      float v = part + inb[r];
      if (r < 1024) dst[r] = v;
      else vb[r - 1024] = v;
    }
  }
  __syncthreads();
  for (int r = w; r < 512; r += 16) {
    const float* row = outw + (long)r * 512;
    float part = 0.f;
    for (int kk = 0; kk < 8; ++kk) part += row[lane + 64 * kk] * vb[lane + 64 * kk];
    for (int off = 32; off > 0; off >>= 1) part += __shfl_down(part, off, 64);
    if (lane == 0) dst[1024 + r] = part + outb[r];
  }
}

// ---------------- stage P2 body: WA = in_w @ anchor (1536 x n) per (s,a) ----------------
template <int N>
__device__ void wa_body(int sub, const float* __restrict__ iw0,
                        const float* __restrict__ iw1,
                        const float* __restrict__ anchor,
                        float* __restrict__ dst0, float* __restrict__ dst1,
                        float* smem) {
  constexpr int NQ = N / 4;
  float* Ws = smem;                 // [128][33]
  float* As = smem + 128 * 33;      // [32][N+1]
  int s = sub / 12, rt = sub % 12;
  const float* inw = s ? iw1 : iw0;
  float* dst = s ? dst1 : dst0;
  int r0 = rt * 128;
  int tid = threadIdx.x;
  int il = tid & 63, q = tid >> 6;
  float acc0[NQ], acc1[NQ];
#pragma unroll
  for (int j = 0; j < NQ; ++j) { acc0[j] = 0.f; acc1[j] = 0.f; }
  for (int d0 = 0; d0 < 512; d0 += 32) {
    for (int i = tid; i < 1024; i += 256) {
      int rr = i >> 3, dc = (i & 7) * 4;
      const float4 v = *(const float4*)&inw[(long)(r0 + rr) * 512 + d0 + dc];
      Ws[rr * 33 + dc + 0] = v.x; Ws[rr * 33 + dc + 1] = v.y;
      Ws[rr * 33 + dc + 2] = v.z; Ws[rr * 33 + dc + 3] = v.w;
    }
    for (int i = tid; i < 32 * N; i += 256) {
      int dd = i / N, k = i - dd * N;
      As[dd * (N + 1) + k] = anchor[(long)d0 * N + i];
    }
    __syncthreads();
    for (int dd = 0; dd < 32; ++dd) {
      float w0 = Ws[il * 33 + dd];
      float w1 = Ws[(il + 64) * 33 + dd];
      const float* ap = As + dd * (N + 1) + q * NQ;
#pragma unroll
      for (int j = 0; j < NQ; ++j) {
        float a = ap[j];
        acc0[j] += w0 * a;
        acc1[j] += w1 * a;
      }
    }
    __syncthreads();
  }
  if (r0 < 512) {  // QAt transpose path
    float* Ct = smem;  // [N][129]
#pragma unroll
    for (int j = 0; j < NQ; ++j) {
      int k = q * NQ + j;
      Ct[k * 129 + il] = acc0[j];
      Ct[k * 129 + il + 64] = acc1[j];
    }
    __syncthreads();
    for (int i = tid; i < N * 128; i += 256) {
      int k = i >> 7, rr = i & 127;
      dst[(long)k * 512 + r0 + rr] = Ct[k * 129 + rr];
    }
  } else if (r0 < 1024) {  // KAt direct
    float* kat = dst + (long)512 * N;
    int rk = r0 - 512 + il;
#pragma unroll
    for (int j = 0; j < NQ; ++j) {
      kat[(long)rk * N + q * NQ + j] = acc0[j];
      kat[(long)(rk + 64) * N + q * NQ + j] = acc1[j];
    }
  } else {  // VA direct
    float* va = dst + (long)1024 * N;
    int rk = r0 - 1024 + il;
#pragma unroll
    for (int j = 0; j < NQ; ++j) {
      va[(long)rk * N + q * NQ + j] = acc0[j];
      va[(long)(rk + 64) * N + q * NQ + j] = acc1[j];
    }
  }
}

__global__ __launch_bounds__(256) void wa_all(const float* __restrict__ iw0,
                                              const float* __restrict__ iw1,
                                              const float* __restrict__ a12,
                                              const float* __restrict__ a24,
                                              const float* __restrict__ a48,
                                              const float* __restrict__ a96,
                                              float* __restrict__ wa0,
                                              float* __restrict__ wa1) {
  extern __shared__ float smem[];
  int a = blockIdx.x / 24, sub = blockIdx.x % 24;
  switch (a) {
    case 0: wa_body<12>(sub, iw0, iw1, a12, wa0, wa1, smem); break;
    case 1: wa_body<24>(sub, iw0, iw1, a24, wa0 + 12L * 1536, wa1 + 12L * 1536, smem); break;
    case 2: wa_body<48>(sub, iw0, iw1, a48, wa0 + 36L * 1536, wa1 + 36L * 1536, smem); break;
    default: wa_body<96>(sub, iw0, iw1, a96, wa0 + 84L * 1536, wa1 + 84L * 1536, smem); break;
  }
}

// ---------------- stage P4 body: OVA_h = out_w[:,hblk] @ VA_h, stored transposed ----------------
template <int N>
__device__ void ova_body(int sub, const float* __restrict__ ow0,
                         const float* __restrict__ ow1,
                         const float* __restrict__ wa0, const float* __restrict__ wa1,
                         float* __restrict__ dst0, float* __restrict__ dst1,
                         float* smem) {
  constexpr int NQ = N / 4;
  float* Ws = smem;
  float* As = smem + 128 * 33;
  int s = sub >> 4, h = (sub >> 2) & 3, rt = sub & 3;
  const float* outw = s ? ow1 : ow0;
  const float* va = (s ? wa1 : wa0) + (long)1024 * N;  // VA rows (512 x N)
  float* dst = s ? dst1 : dst0;
  int r0 = rt * 128;
  int tid = threadIdx.x;
  int il = tid & 63, q = tid >> 6;
  float acc0[NQ], acc1[NQ];
#pragma unroll
  for (int j = 0; j < NQ; ++j) { acc0[j] = 0.f; acc1[j] = 0.f; }
  for (int d0 = 0; d0 < 128; d0 += 32) {
    for (int i = tid; i < 1024; i += 256) {
      int rr = i >> 3, dc = (i & 7) * 4;
      const float4 v = *(const float4*)&outw[(long)(r0 + rr) * 512 + h * 128 + d0 + dc];
      Ws[rr * 33 + dc + 0] = v.x; Ws[rr * 33 + dc + 1] = v.y;
      Ws[rr * 33 + dc + 2] = v.z; Ws[rr * 33 + dc + 3] = v.w;
    }
    for (int i = tid; i < 32 * N; i += 256) {
      int dd = i / N, k = i - dd * N;
      As[dd * (N + 1) + k] = va[(long)(h * 128 + d0) * N + i];
    }
    __syncthreads();
    for (int dd = 0; dd < 32; ++dd) {
      float w0 = Ws[il * 33 + dd];
      float w1 = Ws[(il + 64) * 33 + dd];
      const float* ap = As + dd * (N + 1) + q * NQ;
#pragma unroll
      for (int j = 0; j < NQ; ++j) {
        float a = ap[j];
        acc0[j] += w0 * a;
        acc1[j] += w1 * a;
      }
    }
    __syncthreads();
  }
  float* Ct = smem;
#pragma unroll
  for (int j = 0; j < NQ; ++j) {
    int k = q * NQ + j;
    Ct[k * 129 + il] = acc0[j];
    Ct[k * 129 + il + 64] = acc1[j];
  }
  __syncthreads();
  for (int i = tid; i < N * 128; i += 256) {
    int k = i >> 7, rr = i & 127;
    dst[(long)(h * N + k) * 512 + r0 + rr] = Ct[k * 129 + rr];
  }
}

__global__ __launch_bounds__(256) void ova_all(const float* __restrict__ ow0,
                                               const float* __restrict__ ow1,
                                               const float* __restrict__ wa,
                                               float* __restrict__ ova) {
  extern __shared__ float smem[];
  int a = blockIdx.x / 32, sub = blockIdx.x % 32;
  const float* wa0 = wa;
  const float* wa1 = wa + 276480L;
  float* ova0 = ova;
  float* ova1 = ova + 368640L;
  switch (a) {
    case 0: ova_body<12>(sub, ow0, ow1, wa0, wa1, ova0, ova1, smem); break;
    case 1: ova_body<24>(sub, ow0, ow1, wa0 + 12L * 1536, wa1 + 12L * 1536,
                         ova0 + 12L * 2048, ova1 + 12L * 2048, smem); break;
    case 2: ova_body<48>(sub, ow0, ow1, wa0 + 36L * 1536, wa1 + 36L * 1536,
                         ova0 + 36L * 2048, ova1 + 36L * 2048, smem); break;
    default: ova_body<96>(sub, ow0, ow1, wa0 + 84L * 1536, wa1 + 84L * 1536,
                          ova0 + 84L * 2048, ova1 + 84L * 2048, smem); break;
  }
}

// ---------------- stage B: fused anchor-folded attention, G=4 batches/block ----------------
__global__ __launch_bounds__(256) void attn_kernel(
    const float* __restrict__ xT, const int* __restrict__ per,
    const float* __restrict__ mp, const float* __restrict__ wa,
    const float* __restrict__ ova, const float* __restrict__ cons,
    const float* __restrict__ at_tab, const float* __restrict__ sb,
    const float* __restrict__ l1g, const float* __restrict__ l1b,
    const float* __restrict__ l2g, const float* __restrict__ l2b,
    float* __restrict__ comb) {
  __shared__ float xb[4 * 384];
  __shared__ float Z[4 * 1250];
  __shared__ float qy[4 * 512];
  __shared__ float arb[4 * 388];   // ar, later zh
  __shared__ float sc[4 * 388];
  __shared__ float qkc[16];
  __shared__ float red[8];

  int tid = threadIdx.x;
  int bid = blockIdx.x;
  int slot = bid & 1;
  int c = (bid >> 1) & 127;
  int b0 = (bid >> 8) * 4;
  int p = per[c * 2 + slot];
  int n = nanch(p);
  int np = Tn / p;
  int n1 = n + 1;
  float s = sqrtf((float)p / (float)n);
  const float rscale = 0.08838834764831845f;  // 1/sqrt(128)
  int pre = apre(n);
  const float* mpp = mp + mpoff(p);
  const float* qat = wa + (long)slot * 276480 + (long)pre * 1536;
  const float* kat = qat + (long)512 * n;
  const float* ovat = ova + (long)slot * 368640 + (long)pre * 2048;
  const float* atb = at_tab + (long)pre * 512;
  const float* qc = cons + slot * 1536;
  const float* kb = qc + 512;
  const float* oc = qc + 1024;
  const float* lng = slot ? l2g : l1g;
  const float* lnb = slot ? l2b : l1b;

  // Ph0: stage x rows
  for (int g = 0; g < 4; ++g)
    for (int t = tid; t < Tn; t += 256)
      xb[g * 384 + t] = xT[((long)c * Bn + b0 + g) * Tn + t];
  __syncthreads();

  // Ph1: Z = patches @ Mpinv  (np x n per batch)
  int znp = np * n;
  for (int g = 0; g < 4; ++g) {
    const float* xr0 = xb + g * 384;
    for (int idx = tid; idx < znp; idx += 256) {
      int j = idx / n, k = idx - j * n;
      const float* xr = xr0 + j * p;
      float acc = 0.f;
      for (int t = 0; t < p; ++t) acc += mpp[t * n + k] * xr[t];
      Z[g * 1250 + j * n1 + k] = acc;
    }
  }
  __syncthreads();

  int zlb0 = 0 * 1250 + (np - 1) * n1;
  int zlb1 = 1 * 1250 + (np - 1) * n1;
  int zlb2 = 2 * 1250 + (np - 1) * n1;
  int zlb3 = 3 * 1250 + (np - 1) * n1;

  // Ph2: q = s*QAt^T@Z_last + qc (batched over g; 2 rows/thread)
  {
    float a0[4] = {0.f, 0.f, 0.f, 0.f}, a1[4] = {0.f, 0.f, 0.f, 0.f};
    for (int k = 0; k < n; ++k) {
      float w0 = qat[(long)k * 512 + tid];
      float w1 = qat[(long)k * 512 + 256 + tid];
      float z0 = Z[zlb0 + k], z1 = Z[zlb1 + k], z2 = Z[zlb2 + k], z3 = Z[zlb3 + k];
      a0[0] += w0 * z0; a0[1] += w0 * z1; a0[2] += w0 * z2; a0[3] += w0 * z3;
      a1[0] += w1 * z0; a1[1] += w1 * z1; a1[2] += w1 * z2; a1[3] += w1 * z3;
    }
    float qc0 = qc[tid], qc1 = qc[256 + tid];
#pragma unroll
    for (int g = 0; g < 4; ++g) {
      qy[g * 512 + tid] = qc0 + s * a0[g];
      qy[g * 512 + 256 + tid] = qc1 + s * a1[g];
    }
  }
  __syncthreads();

  // Ph2b: qkc[g][h] = q_h . kb_h
  if (tid < 16) {
    int g = tid >> 2, h = tid & 3;
    float acc = 0.f;
    for (int i = 0; i < 128; ++i) acc += qy[g * 512 + h * 128 + i] * kb[h * 128 + i];
    qkc[g * 4 + h] = acc;
  }

  // Ph3: ar[g][h][k] = s * sum_i KAt[(h*128+i)*n+k] * q[g][h*128+i]
  {
    int tot = 16 * n;
    for (int idx = tid; idx < tot; idx += 256) {
      int g = idx / (4 * n);
      int r = idx - g * 4 * n;
      int h = r / n, k = r - h * n;
      float acc = 0.f;
      const float* kp = kat + (long)(h * 128) * n + k;
      const float* qp = qy + g * 512 + h * 128;
      for (int i = 0; i < 128; ++i) acc += kp[(long)i * n] * qp[i];
      arb[g * 388 + h * n + k] = s * acc;
    }
  }
  __syncthreads();

  // Ph4: scores
  {
    int tot = 16 * np;
    for (int idx = tid; idx < tot; idx += 256) {
      int g = idx / (4 * np);
      int r = idx - g * 4 * np;
      int h = r / np, j = r - h * np;
      const float* ap = arb + g * 388 + h * n;
      const float* zp = Z + g * 1250 + j * n1;
      float acc = 0.f;
      for (int k = 0; k < n; ++k) acc += ap[k] * zp[k];
      sc[g * 388 + h * np + j] = (acc + qkc[g * 4 + h]) * rscale;
    }
  }
  __syncthreads();

  // Ph5: softmax per (g,h), normalized probs in place
  if (tid < 16) {
    int g = tid >> 2, h = tid & 3;
    float* sp = sc + g * 388 + h * np;
    float m = -1e30f;
    for (int j = 0; j < np; ++j) m = fmaxf(m, sp[j]);
    float l = 0.f;
    for (int j = 0; j < np; ++j) { float e = expf(sp[j] - m); sp[j] = e; l += e; }
    float il = 1.f / l;
    for (int j = 0; j < np; ++j) sp[j] *= il;
  }
  __syncthreads();

  // Ph6: zh[g][h][k] = sum_j prob * Z[g][j][k]  (into arb)
  {
    int tot = 16 * n;
    for (int idx = tid; idx < tot; idx += 256) {
      int g = idx / (4 * n);
      int r = idx - g * 4 * n;
      int h = r / n, k = r - h * n;
      const float* sp = sc + g * 388 + h * np;
      const float* zp = Z + g * 1250 + k;
      float acc = 0.f;
      for (int j = 0; j < np; ++j) acc += sp[j] * zp[j * n1];
      arb[g * 388 + h * n + k] = acc;
    }
  }
  __syncthreads();

  // Ph7: y = s*(At@Z_last + sum_h OVAt@zh) + sb + oc  (into qy)
  {
    float a0[4] = {0.f, 0.f, 0.f, 0.f}, a1[4] = {0.f, 0.f, 0.f, 0.f};
    for (int k = 0; k < n; ++k) {
      float w0 = atb[(long)k * 512 + tid];
      float w1 = atb[(long)k * 512 + 256 + tid];
      float z0 = Z[zlb0 + k], z1 = Z[zlb1 + k], z2 = Z[zlb2 + k], z3 = Z[zlb3 + k];
      a0[0] += w0 * z0; a0[1] += w0 * z1; a0[2] += w0 * z2; a0[3] += w0 * z3;
      a1[0] += w1 * z0; a1[1] += w1 * z1; a1[2] += w1 * z2; a1[3] += w1 * z3;
    }
    for (int h = 0; h < 4; ++h) {
      const float* op = ovat + (long)(h * n) * 512;
      const float* zh0 = arb + 0 * 388 + h * n;
      const float* zh1 = arb + 1 * 388 + h * n;
      const float* zh2 = arb + 2 * 388 + h * n;
      const float* zh3 = arb + 3 * 388 + h * n;
      for (int k = 0; k < n; ++k) {
        float w0 = op[(long)k * 512 + tid];
        float w1 = op[(long)k * 512 + 256 + tid];
        float z0 = zh0[k], z1 = zh1[k], z2 = zh2[k], z3 = zh3[k];
        a0[0] += w0 * z0; a0[1] += w0 * z1; a0[2] += w0 * z2; a0[3] += w0 * z3;
        a1[0] += w1 * z0; a1[1] += w1 * z1; a1[2] += w1 * z2; a1[3] += w1 * z3;
      }
    }
    float s0 = sb[tid] + oc[tid];
    float s1 = sb[256 + tid] + oc[256 + tid];
    __syncthreads();
#pragma unroll
    for (int g = 0; g < 4; ++g) {
      qy[g * 512 + tid] = s * a0[g] + s0;
      qy[g * 512 + 256 + tid] = s * a1[g] + s1;
    }
  }
  __syncthreads();

  // Ph8: layernorm per batch row, write comb
  {
    int w = tid >> 6, lane = tid & 63;
    int g = w;
    float sm = 0.f, sq = 0.f;
    for (int kk = 0; kk < 8; ++kk) {
      float v = qy[g * 512 + lane + 64 * kk];
      sm += v; sq += v * v;
    }
    for (int off = 32; off > 0; off >>= 1) {
      sm += __shfl_down(sm, off, 64);
      sq += __shfl_down(sq, off, 64);
    }
    if (lane == 0) { red[g * 2] = sm; red[g * 2 + 1] = sq; }
    __syncthreads();
    float mu = red[g * 2] / 512.f;
    float var = red[g * 2 + 1] / 512.f - mu * mu;
    float rstd = rsqrtf(var + 1e-5f);
    long base = ((long)(b0 + g) * Cn + c) * 1536 + slot * 512;
    for (int kk = 0; kk < 8; ++kk) {
      int i = lane + 64 * kk;
      comb[base + i] = (qy[g * 512 + i] - mu) * rstd * lng[i] + lnb[i];
    }
  }
}

// ---------------- stage D: trend (anchor-folded) ----------------
__global__ __launch_bounds__(256) void trend_kernel(const float* __restrict__ xT,
                                                    const float* __restrict__ mp384,
                                                    const float* __restrict__ at96,
                                                    const float* __restrict__ sb,
                                                    float* __restrict__ comb) {
  __shared__ float xb[Bn * Tn];
  __shared__ float Ztr[Bn * 97];
  int c = blockIdx.x, tid = threadIdx.x;
  for (int i = tid; i < Bn * Tn; i += 256) xb[i] = xT[(long)c * Bn * Tn + i];
  __syncthreads();
  for (int idx = tid; idx < Bn * 96; idx += 256) {
    int b = idx / 96, k = idx - b * 96;
    const float* xr = xb + b * Tn;
    float acc = 0.f;
    for (int t = 0; t < Tn; ++t) acc += mp384[t * 96 + k] * xr[t];
    Ztr[b * 97 + k] = acc;
  }
  __syncthreads();
  float acc0[Bn], acc1[Bn];
#pragma unroll
  for (int b = 0; b < Bn; ++b) { acc0[b] = 0.f; acc1[b] = 0.f; }
  for (int k = 0; k < 96; ++k) {
    float w0 = at96[(long)k * 512 + tid];
    float w1 = at96[(long)k * 512 + 256 + tid];
#pragma unroll
    for (int b = 0; b < Bn; ++b) {
      float z = Ztr[b * 97 + k];
      acc0[b] += w0 * z;
      acc1[b] += w1 * z;
    }
  }
  float s0 = sb[tid], s1 = sb[256 + tid];
#pragma unroll
  for (int b = 0; b < Bn; ++b) {
    long base = ((long)b * Cn + c) * 1536 + 1024;
    comb[base + tid] = 2.f * acc0[b] + s0;          // sqrt(384/96)=2
    comb[base + 256 + tid] = 2.f * acc1[b] + s1;
  }
}

// ---------------- stage E: tiled GEMM  C = act(A @ W^T + bias) ----------------
template <bool GELU>
__global__ __launch_bounds__(256) void fused_gemm(const float* __restrict__ A,
                                                  const float* __restrict__ W,
                                                  const float* __restrict__ bias,
                                                  float* __restrict__ C,
                                                  int N, int K) {
  __shared__ float As[32 * 68];
  __shared__ float Ws[32 * 68];
  int nb = N >> 6;
  int m0 = (blockIdx.x / nb) * 64, n0 = (blockIdx.x % nb) * 64;
  int tid = threadIdx.x;
  int tm = tid & 15, tn = tid >> 4;
  float acc[4][4];
#pragma unroll
  for (int i = 0; i < 4; ++i)
#pragma unroll
    for (int j = 0; j < 4; ++j) acc[i][j] = 0.f;
  int row = tid >> 3, kc = (tid & 7) * 4;
  for (int k0 = 0; k0 < K; k0 += 32) {
    {
      float4 v = *(const float4*)&A[(long)(m0 + row) * K + k0 + kc];
      As[(kc + 0) * 68 + row] = v.x; As[(kc + 1) * 68 + row] = v.y;
      As[(kc + 2) * 68 + row] = v.z; As[(kc + 3) * 68 + row] = v.w;
      v = *(const float4*)&A[(long)(m0 + row + 32) * K + k0 + kc];
      As[(kc + 0) * 68 + row + 32] = v.x; As[(kc + 1) * 68 + row + 32] = v.y;
      As[(kc + 2) * 68 + row + 32] = v.z; As[(kc + 3) * 68 + row + 32] = v.w;
      v = *(const float4*)&W[(long)(n0 + row) * K + k0 + kc];
      Ws[(kc + 0) * 68 + row] = v.x; Ws[(kc + 1) * 68 + row] = v.y;
      Ws[(kc + 2) * 68 + row] = v.z; Ws[(kc + 3) * 68 + row] = v.w;
      v = *(const float4*)&W[(long)(n0 + row + 32) * K + k0 + kc];
      Ws[(kc + 0) * 68 + row + 32] = v.x; Ws[(kc + 1) * 68 + row + 32] = v.y;
      Ws[(kc + 2) * 68 + row + 32] = v.z; Ws[(kc + 3) * 68 + row + 32] = v.w;
    }
    __syncthreads();
    for (int kk = 0; kk < 32; ++kk) {
      float4 a = *(const float4*)&As[kk * 68 + tm * 4];
      float4 w = *(const float4*)&Ws[kk * 68 + tn * 4];
      acc[0][0] += a.x * w.x; acc[0][1] += a.x * w.y; acc[0][2] += a.x * w.z; acc[0][3] += a.x * w.w;
      acc[1][0] += a.y * w.x; acc[1][1] += a.y * w.y; acc[1][2] += a.y * w.z; acc[1][3] += a.y * w.w;
      acc[2][0] += a.z * w.x; acc[2][1] += a.z * w.y; acc[2][2] += a.z * w.z; acc[2][3] += a.z * w.w;
      acc[3][0] += a.w * w.x; acc[3][1] += a.w * w.y; acc[3][2] += a.w * w.z; acc[3][3] += a.w * w.w;
    }
    __syncthreads();
  }
  float b0v = bias[n0 + tn * 4 + 0], b1v = bias[n0 + tn * 4 + 1];
  float b2v = bias[n0 + tn * 4 + 2], b3v = bias[n0 + tn * 4 + 3];
#pragma unroll
  for (int mi = 0; mi < 4; ++mi) {
    float4 o;
    o.x = acc[mi][0] + b0v; o.y = acc[mi][1] + b1v;
    o.z = acc[mi][2] + b2v; o.w = acc[mi][3] + b3v;
    if (GELU) {
      o.x = 0.5f * o.x * (1.f + erff(o.x * 0.7071067811865475f));
      o.y = 0.5f * o.y * (1.f + erff(o.y * 0.7071067811865475f));
      o.z = 0.5f * o.z * (1.f + erff(o.z * 0.7071067811865475f));
      o.w = 0.5f * o.w * (1.f + erff(o.w * 0.7071067811865475f));
    }
    *(float4*)&C[(long)(m0 + tm * 4 + mi) * N + n0 + tn * 4] = o;
  }
}

extern "C" void kernel_launch(void* const* d_in, const int* in_sizes, int n_in,
                              void* d_out, int out_size, void* d_ws, size_t ws_size,
                              hipStream_t stream) {
  const float* x    = (const float*)d_in[0];
  const float* a12  = (const float*)d_in[1];
  const float* a24  = (const float*)d_in[2];
  const float* a48  = (const float*)d_in[3];
  const float* a96  = (const float*)d_in[4];
  const float* sb   = (const float*)d_in[5];
  const float* g1iw = (const float*)d_in[6];
  const float* g1ib = (const float*)d_in[7];
  const float* g1ow = (const float*)d_in[8];
  const float* g1ob = (const float*)d_in[9];
  const float* g1lg = (const float*)d_in[10];
  const float* g1lb = (const float*)d_in[11];
  const float* g2iw = (const float*)d_in[12];
  const float* g2ib = (const float*)d_in[13];
  const float* g2ow = (const float*)d_in[14];
  const float* g2ob = (const float*)d_in[15];
  const float* g2lg = (const float*)d_in[16];
  const float* g2lb = (const float*)d_in[17];
  const float* fw1  = (const float*)d_in[18];
  const float* fb1  = (const float*)d_in[19];
  const float* fw2  = (const float*)d_in[20];
  const float* fb2  = (const float*)d_in[21];

  if (ws_size < (size_t)WS_FLOATS * sizeof(float)) return;

  float* ws   = (float*)d_ws;
  float* xT   = ws + OFF_XT;
  float* avgT = ws + OFF_AVG;
  int*   per  = (int*)(ws + OFF_PER);
  float* mp   = ws + OFF_MP;
  float* wa   = ws + OFF_WA;
  float* ova  = ws + OFF_OVA;
  float* cons = ws + OFF_CON;
  float* atb  = ws + OFF_AT;
  float* comb = ws + OFF_COMB;
  float* hbuf = ws + OFF_H;
  float* out  = (float*)d_out;

  transpose_kernel<<<192, 256, 0, stream>>>(x, xT);
  acf_kernel<<<Cn, 256, 0, stream>>>(xT, avgT);
  periods_kernel<<<1, 128, 0, stream>>>(avgT, per);
  build_mpinv_kernel<<<190, 256, 0, stream>>>(per, mp);
  at_kernel<<<32, 256, 0, stream>>>(a12, a24, a48, a96, atb);
  consts_kernel<<<2, 1024, 0, stream>>>(g1iw, g1ib, g1ow, g1ob,
                                        g2iw, g2ib, g2ow, g2ob, sb, cons);
  wa_all<<<96, 256, 49536, stream>>>(g1iw, g2iw, a12, a24, a48, a96,
                                     wa, wa + 276480L);
  ova_all<<<128, 256, 49536, stream>>>(g1ow, g2ow, wa, ova);

  attn_kernel<<<1024, 256, 0, stream>>>(xT, per, mp, wa, ova, cons, atb, sb,
                                        g1lg, g1lb, g2lg, g2lb, comb);
  trend_kernel<<<Cn, 256, 0, stream>>>(xT, mp + 1634436L, atb + 84L * 512, sb, comb);
  fused_gemm<true><<<256, 256, 0, stream>>>(comb, fw1, fb1, hbuf, 512, 1536);
  fused_gemm<false><<<256, 256, 0, stream>>>(hbuf, fw2, fb2, out, 512, 512);
}

// Round 4
// 1097.791 us; speedup vs baseline: 7.1811x; 1.3598x over previous
//
#include <hip/hip_runtime.h>
#include <math.h>

#define Bn 16
#define Tn 384
#define Cn 128

// ---------------- workspace layout (floats) ----------------
static constexpr long OFF_XT   = 0;         // 128*16*384
static constexpr long OFF_AVG  = 786432;    // 384*128 (transposed: [t][c])
static constexpr long OFF_PER  = 835584;    // 256 ints
static constexpr long OFF_MP   = 835840;    // 1671300 (Mpinv for p=4..192 and 384)
static constexpr long OFF_WA   = 2507140;   // 552960: per (s,a): [QAt n*512][KAt 512*n][VA 512*n]
static constexpr long OFF_OVA  = 3060100;   // 737280: per (s,a): [ (h*n+k)*512 + i ]
static constexpr long OFF_CON  = 3797380;   // 3072: per slot: qc[512] kb[512] oc[512]
static constexpr long OFF_AT   = 3800452;   // 92160: anchors transposed, concat by a: [k*512+d]
static constexpr long OFF_COMB = 3892612;   // 2048*1536
static constexpr long OFF_H    = 7038340;   // 2048*512
static constexpr long WS_FLOATS = 8086916;  // ~32.4 MB

__host__ __device__ inline int nanch(int p) {
  if (p == 384) return 96;
  return (p <= 18) ? 12 : (p <= 36) ? 24 : (p <= 72) ? 48 : 96;
}
__host__ __device__ inline int apre(int n) {  // prefix of n over anchors {12,24,48,96}
  return (n == 12) ? 0 : (n == 24) ? 12 : (n == 48) ? 36 : 84;
}
__host__ __device__ inline long mpoff(int p) {
  if (p == 384) return 1634436L;
  long T = (long)(p - 1) * p / 2;
  if (p <= 18) return 12 * (T - 6);
  if (p <= 36) return 1980 + 24 * (T - 171);
  if (p <= 72) return 13860 + 48 * (T - 666);
  return 108036 + 96 * (T - 2628);
}

// interp row j of _interp_matrix(newl, oldl): nonzeros at (i0, 1-w), (i1, w)
__device__ inline void irow(int j, int newl, int oldl, int& i0, int& i1, float& w) {
  double src = ((double)j + 0.5) * (double)oldl / (double)newl - 0.5;
  if (src < 0.0) src = 0.0;
  double mx = (double)(oldl - 1);
  if (src > mx) src = mx;
  int a = (int)src;
  if (a > oldl - 1) a = oldl - 1;
  i0 = a;
  i1 = (a + 1 < oldl) ? (a + 1) : (oldl - 1);
  w = (float)(src - (double)a);
}

// ---------------- stage 0: transpose x -> xT[c][b][t] ----------------
__global__ __launch_bounds__(256) void transpose_kernel(const float* __restrict__ x,
                                                        float* __restrict__ xT) {
  __shared__ float tile[32 * 129];
  int bid = blockIdx.x;           // 16 b * 12 t-tiles
  int b = bid / 12, t0 = (bid % 12) * 32;
  int tid = threadIdx.x;
  for (int i = tid; i < 32 * 128; i += 256) {
    int tt = i >> 7, cc = i & 127;
    tile[tt * 129 + cc] = x[((long)b * Tn + t0 + tt) * Cn + cc];
  }
  __syncthreads();
  for (int i = tid; i < 32 * 128; i += 256) {
    int cc = i >> 5, tt = i & 31;
    xT[((long)cc * Bn + b) * Tn + t0 + tt] = tile[tt * 129 + cc];
  }
}

// ---------------- stage A1: batch-summed linear ACF per channel ----------------
// grid = 128 channels x 6 tau-tiles. Each thread: 4 adjacent taus (rolling
// window) x 1 batch; width-16 shuffle reduce over batches.
__global__ __launch_bounds__(256) void acf_kernel(const float* __restrict__ xT,
                                                  float* __restrict__ avgT) {
  __shared__ float xb[Bn * 397];   // rows padded to 397 (odd, bank-friendly)
  __shared__ float mean[Bn];
  int bid = blockIdx.x;
  int c = bid / 6, tile = bid % 6;
  int tid = threadIdx.x;
  for (int i = tid; i < Bn * Tn; i += 256) {
    int b = i / Tn, t = i - b * Tn;
    xb[b * 397 + t] = xT[(long)c * Bn * Tn + i];
  }
  for (int i = tid; i < Bn * 13; i += 256) {   // zero pad t=384..396
    int b = i / 13, t = Tn + (i - b * 13);
    xb[b * 397 + t] = 0.f;
  }
  __syncthreads();
  if (tid < Bn) {
    float s = 0.f;
    for (int t = 0; t < Tn; ++t) s += xb[tid * 397 + t];
    mean[tid] = s / (float)Tn;
  }
  __syncthreads();
  for (int i = tid; i < Bn * Tn; i += 256) {
    int b = i / Tn, t = i - b * Tn;
    xb[b * 397 + t] -= mean[b];
  }
  __syncthreads();
  int q = tid >> 4;        // 16 tau-quads per block
  int g = tid & 15;        // 16 batches
  int tau0 = tile * 64 + q * 4;
  const float* xr = xb + g * 397;
  float a0 = 0.f, a1 = 0.f, a2 = 0.f, a3 = 0.f;
  float w0 = xr[tau0], w1 = xr[tau0 + 1], w2 = xr[tau0 + 2], w3 = xr[tau0 + 3];
  int tmax = Tn - tau0;
  for (int t = 0; t < tmax; ++t) {
    float a = xr[t];
    float wn = xr[t + tau0 + 4];
    a0 += a * w0; a1 += a * w1; a2 += a * w2; a3 += a * w3;
    w0 = w1; w1 = w2; w2 = w3; w3 = wn;
  }
  // reduce over g (16 consecutive lanes)
  for (int off = 8; off > 0; off >>= 1) {
    a0 += __shfl_down(a0, off, 16);
    a1 += __shfl_down(a1, off, 16);
    a2 += __shfl_down(a2, off, 16);
    a3 += __shfl_down(a3, off, 16);
  }
  if (g == 0) {
    avgT[(long)(tau0 + 0) * Cn + c] = a0;
    avgT[(long)(tau0 + 1) * Cn + c] = a1;
    avgT[(long)(tau0 + 2) * Cn + c] = a2;
    avgT[(long)(tau0 + 3) * Cn + c] = a3;
  }
}

// ---------------- stage A2: peak detect + top-2 + clip ----------------
__global__ __launch_bounds__(128) void periods_kernel(const float* __restrict__ avgT,
                                                      int* __restrict__ per) {
  int c = threadIdx.x;
  if (c >= Cn) return;
  const float* a = avgT + c;
  const float NEG = -1e30f;
  float b1v = NEG, b2v = NEG;
  int b1i = 0, b2i = 0;
  float pv = NEG;                  // avg[3] masked to -inf
  float v = a[4L * Cn];
  for (int t = 4; t < Tn; ++t) {
    float nv = (t == Tn - 1) ? NEG : a[(long)(t + 1) * Cn];  // circular next of last is -inf
    bool peak = (v > pv) && (v > nv) && (v > 0.f);
    float m = peak ? v : NEG;
    if (m > b1v)      { b2v = b1v; b2i = b1i; b1v = m; b1i = t; }
    else if (m > b2v) { b2v = m; b2i = t; }
    pv = v; v = nv;
  }
  per[c * 2 + 0] = min(max(b1i, 4), 192);
  per[c * 2 + 1] = min(max(b2i, 4), 192);
}

// ---------------- stage C: build Mpinv (p x n) via tridiagonal Thomas ----------------
// Both Grams are SPD tridiagonal (interp rows are 2-sparse with adjacent cols).
__global__ __launch_bounds__(256) void build_mpinv_kernel(const int* __restrict__ per,
                                                          float* __restrict__ mp) {
  __shared__ int ii[384];
  __shared__ float ww[384];
  __shared__ float dd_[96], ee[96], cp[96], idt[96];
  __shared__ float ginv[96 * 97];
  __shared__ float outp[96 * 97];
  __shared__ int flag;
  int tid = threadIdx.x;
  int p = (blockIdx.x < 189) ? (4 + (int)blockIdx.x) : 384;
  if (tid == 0) flag = (p == 384) ? 1 : 0;
  __syncthreads();
  if (p != 384) {
    for (int i = tid; i < Cn * 2; i += 256)
      if (per[i] == p) flag = 1;
  }
  __syncthreads();
  if (!flag) return;

  int n = nanch(p);
  int m = (p >= n) ? n : p;  // Gram dim
  float* dst = mp + mpoff(p);

  // irow tables
  for (int j = tid; j < p; j += 256) {
    int i0, i1; float w;
    irow(j, p, n, i0, i1, w);
    ii[j] = i0; ww[j] = w;
  }
  for (int i = tid; i < m; i += 256) { dd_[i] = 0.f; ee[i] = 0.f; }
  __syncthreads();

  if (p >= n) {  // G = M^T M (n x n tridiag), scatter rows
    for (int j = tid; j < p; j += 256) {
      int i0 = ii[j]; float w = ww[j];
      int i1 = min(i0 + 1, n - 1);
      if (i1 == i0) {
        atomicAdd(&dd_[i0], 1.0f);   // merged entry value (1-w)+w = 1
      } else {
        float a = 1.f - w, b = w;
        atomicAdd(&dd_[i0], a * a);
        atomicAdd(&dd_[i1], b * b);
        atomicAdd(&ee[i0], a * b);
      }
    }
  } else {       // H = M M^T (p x p tridiag), one writer per row
    for (int r = tid; r < p; r += 256) {
      int i0 = ii[r]; float w = ww[r];
      int i1 = min(i0 + 1, n - 1);
      float a, b; int c0 = i0, c1 = i1;
      if (i1 == i0) { a = 1.f; b = 0.f; c1 = -1; }
      else { a = 1.f - w; b = w; }
      dd_[r] = a * a + b * b;
      if (r < p - 1) {
        int j0 = ii[r + 1]; float w2 = ww[r + 1];
        int j1 = min(j0 + 1, n - 1);
        float a2, b2; int d0 = j0, d1 = j1;
        if (j1 == j0) { a2 = 1.f; b2 = 0.f; d1 = -2; }
        else { a2 = 1.f - w2; b2 = w2; }
        float s = 0.f;
        if (c0 == d0) s += a * a2;
        if (c0 == d1) s += a * b2;
        if (c1 == d0) s += b * a2;
        if (c1 == d1) s += b * b2;
        ee[r] = s;
      }
    }
  }
  __syncthreads();
  // LDL^T factorization (serial, m <= 96)
  if (tid == 0) {
    float dt = dd_[0];
    idt[0] = 1.f / dt;
    for (int i = 1; i < m; ++i) {
      float c = ee[i - 1] * idt[i - 1];
      cp[i - 1] = c;
      dt = dd_[i] - ee[i - 1] * c;
      idt[i] = 1.f / dt;
    }
  }
  __syncthreads();
  // per-column Thomas solve: thread j computes Ginv[:, j]
  if (tid < m) {
    int j = tid;
    float z = 1.f;
    ginv[j * 97 + j] = 1.f;
    for (int i = j + 1; i < m; ++i) {
      z = -cp[i - 1] * z;
      ginv[i * 97 + j] = z;
    }
    float xn = ginv[(m - 1) * 97 + j] * idt[m - 1];
    ginv[(m - 1) * 97 + j] = xn;
    for (int i = m - 2; i >= 0; --i) {
      float zi = (i >= j) ? ginv[i * 97 + j] : 0.f;
      xn = zi * idt[i] - cp[i] * xn;
      ginv[i * 97 + j] = xn;
    }
  }
  __syncthreads();
  if (p >= n) {  // Mpinv = M @ Ginv (row t = interp of two Ginv rows)
    for (int idx = tid; idx < p * n; idx += 256) {
      int t = idx / n, k = idx - t * n;
      int i0 = ii[t]; float w = ww[t];
      int i1 = min(i0 + 1, n - 1);
      dst[idx] = (1.f - w) * ginv[i0 * 97 + k] + w * ginv[i1 * 97 + k];
    }
  } else {       // Mpinv = Hinv @ M (scatter M's 2-sparse rows), one thread per row t
    for (int t = tid; t < p; t += 256) {
      for (int k = 0; k < n; ++k) outp[t * 97 + k] = 0.f;
      for (int j = 0; j < p; ++j) {
        float hv = ginv[t * 97 + j];
        int i0 = ii[j]; float w = ww[j];
        int i1 = min(i0 + 1, n - 1);
        outp[t * 97 + i0] += hv * (1.f - w);
        outp[t * 97 + i1] += hv * w;
      }
    }
    __syncthreads();
    for (int idx = tid; idx < p * n; idx += 256) {
      int t = idx / n, k = idx - t * n;
      dst[idx] = outp[t * 97 + k];
    }
  }
}

// ---------------- stage P1: transpose anchors -> At[k*512+d] ----------------
__global__ __launch_bounds__(256) void at_kernel(const float* __restrict__ a12,
                                                 const float* __restrict__ a24,
                                                 const float* __restrict__ a48,
                                                 const float* __restrict__ a96,
                                                 float* __restrict__ at_tab) {
  __shared__ float tile[64 * 97];
  int bid = blockIdx.x;     // 4 anchors * 8 d-chunks
  int a = bid >> 3, d0 = (bid & 7) * 64;
  int n = (a == 0) ? 12 : (a == 1) ? 24 : (a == 2) ? 48 : 96;
  const float* src = (a == 0) ? a12 : (a == 1) ? a24 : (a == 2) ? a48 : a96;
  float* dst = at_tab + (long)apre(n) * 512;
  int tid = threadIdx.x;
  for (int i = tid; i < 64 * n; i += 256) {
    int dd = i / n, k = i - dd * n;
    tile[dd * 97 + k] = src[(long)(d0 + dd) * n + (long)k];
  }
  __syncthreads();
  for (int i = tid; i < n * 64; i += 256) {
    int k = i >> 6, dd = i & 63;
    dst[(long)k * 512 + d0 + dd] = tile[dd * 97 + k];
  }
}

// ---------------- stage P3: bias folds qc/kb/oc per slot (16 waves) ----------------
__global__ __launch_bounds__(1024) void consts_kernel(
    const float* __restrict__ i1w, const float* __restrict__ i1b,
    const float* __restrict__ o1w, const float* __restrict__ o1b,
    const float* __restrict__ i2w, const float* __restrict__ i2b,
    const float* __restrict__ o2w, const float* __restrict__ o2b,
    const float* __restrict__ sb, float* __restrict__ cons) {
  __shared__ float sv[512];
  __shared__ float vb[512];
  int s = blockIdx.x, tid = threadIdx.x;
  const float* inw = s ? i2w : i1w;
  const float* inb = s ? i2b : i1b;
  const float* outw = s ? o2w : o1w;
  const float* outb = s ? o2b : o1b;
  float* dst = cons + s * 1536;
  if (tid < 512) sv[tid] = sb[tid];
  __syncthreads();
  int lane = tid & 63, w = tid >> 6;  // 16 waves
  for (int r = w; r < 1536; r += 16) {
    const float* row = inw + (long)r * 512;
    float part = 0.f;
    for (int kk = 0; kk < 8; ++kk) part += row[lane + 64 * kk] * sv[lane + 64 * kk];
    for (int off = 32; off > 0; off >>= 1) part += __shfl_down(part, off, 64);
    if (lane == 0) {
      float v = part + inb[r];
      if (r < 1024) dst[r] = v;
      else vb[r - 1024] = v;
    }
  }
  __syncthreads();
  for (int r = w; r < 512; r += 16) {
    const float* row = outw + (long)r * 512;
    float part = 0.f;
    for (int kk = 0; kk < 8; ++kk) part += row[lane + 64 * kk] * vb[lane + 64 * kk];
    for (int off = 32; off > 0; off >>= 1) part += __shfl_down(part, off, 64);
    if (lane == 0) dst[1024 + r] = part + outb[r];
  }
}

// ---------------- stage P2 body: WA = in_w @ anchor (1536 x n) per (s,a) ----------------
template <int N>
__device__ void wa_body(int sub, const float* __restrict__ iw0,
                        const float* __restrict__ iw1,
                        const float* __restrict__ anchor,
                        float* __restrict__ dst0, float* __restrict__ dst1,
                        float* smem) {
  constexpr int NQ = N / 4;
  float* Ws = smem;                 // [128][33]
  float* As = smem + 128 * 33;      // [32][N+1]
  int s = sub / 12, rt = sub % 12;
  const float* inw = s ? iw1 : iw0;
  float* dst = s ? dst1 : dst0;
  int r0 = rt * 128;
  int tid = threadIdx.x;
  int il = tid & 63, q = tid >> 6;
  float acc0[NQ], acc1[NQ];
#pragma unroll
  for (int j = 0; j < NQ; ++j) { acc0[j] = 0.f; acc1[j] = 0.f; }
  for (int d0 = 0; d0 < 512; d0 += 32) {
    for (int i = tid; i < 1024; i += 256) {
      int rr = i >> 3, dc = (i & 7) * 4;
      const float4 v = *(const float4*)&inw[(long)(r0 + rr) * 512 + d0 + dc];
      Ws[rr * 33 + dc + 0] = v.x; Ws[rr * 33 + dc + 1] = v.y;
      Ws[rr * 33 + dc + 2] = v.z; Ws[rr * 33 + dc + 3] = v.w;
    }
    for (int i = tid; i < 32 * N; i += 256) {
      int dd = i / N, k = i - dd * N;
      As[dd * (N + 1) + k] = anchor[(long)d0 * N + i];
    }
    __syncthreads();
    for (int dd = 0; dd < 32; ++dd) {
      float w0 = Ws[il * 33 + dd];
      float w1 = Ws[(il + 64) * 33 + dd];
      const float* ap = As + dd * (N + 1) + q * NQ;
#pragma unroll
      for (int j = 0; j < NQ; ++j) {
        float a = ap[j];
        acc0[j] += w0 * a;
        acc1[j] += w1 * a;
      }
    }
    __syncthreads();
  }
  if (r0 < 512) {  // QAt transpose path
    float* Ct = smem;  // [N][129]
#pragma unroll
    for (int j = 0; j < NQ; ++j) {
      int k = q * NQ + j;
      Ct[k * 129 + il] = acc0[j];
      Ct[k * 129 + il + 64] = acc1[j];
    }
    __syncthreads();
    for (int i = tid; i < N * 128; i += 256) {
      int k = i >> 7, rr = i & 127;
      dst[(long)k * 512 + r0 + rr] = Ct[k * 129 + rr];
    }
  } else if (r0 < 1024) {  // KAt direct
    float* kat = dst + (long)512 * N;
    int rk = r0 - 512 + il;
#pragma unroll
    for (int j = 0; j < NQ; ++j) {
      kat[(long)rk * N + q * NQ + j] = acc0[j];
      kat[(long)(rk + 64) * N + q * NQ + j] = acc1[j];
    }
  } else {  // VA direct
    float* va = dst + (long)1024 * N;
    int rk = r0 - 1024 + il;
#pragma unroll
    for (int j = 0; j < NQ; ++j) {
      va[(long)rk * N + q * NQ + j] = acc0[j];
      va[(long)(rk + 64) * N + q * NQ + j] = acc1[j];
    }
  }
}

__global__ __launch_bounds__(256) void wa_all(const float* __restrict__ iw0,
                                              const float* __restrict__ iw1,
                                              const float* __restrict__ a12,
                                              const float* __restrict__ a24,
                                              const float* __restrict__ a48,
                                              const float* __restrict__ a96,
                                              float* __restrict__ wa0,
                                              float* __restrict__ wa1) {
  extern __shared__ float smem[];
  int a = blockIdx.x / 24, sub = blockIdx.x % 24;
  switch (a) {
    case 0: wa_body<12>(sub, iw0, iw1, a12, wa0, wa1, smem); break;
    case 1: wa_body<24>(sub, iw0, iw1, a24, wa0 + 12L * 1536, wa1 + 12L * 1536, smem); break;
    case 2: wa_body<48>(sub, iw0, iw1, a48, wa0 + 36L * 1536, wa1 + 36L * 1536, smem); break;
    default: wa_body<96>(sub, iw0, iw1, a96, wa0 + 84L * 1536, wa1 + 84L * 1536, smem); break;
  }
}

// ---------------- stage P4 body: OVA_h = out_w[:,hblk] @ VA_h, stored transposed ----------------
template <int N>
__device__ void ova_body(int sub, const float* __restrict__ ow0,
                         const float* __restrict__ ow1,
                         const float* __restrict__ wa0, const float* __restrict__ wa1,
                         float* __restrict__ dst0, float* __restrict__ dst1,
                         float* smem) {
  constexpr int NQ = N / 4;
  float* Ws = smem;
  float* As = smem + 128 * 33;
  int s = sub >> 4, h = (sub >> 2) & 3, rt = sub & 3;
  const float* outw = s ? ow1 : ow0;
  const float* va = (s ? wa1 : wa0) + (long)1024 * N;  // VA rows (512 x N)
  float* dst = s ? dst1 : dst0;
  int r0 = rt * 128;
  int tid = threadIdx.x;
  int il = tid & 63, q = tid >> 6;
  float acc0[NQ], acc1[NQ];
#pragma unroll
  for (int j = 0; j < NQ; ++j) { acc0[j] = 0.f; acc1[j] = 0.f; }
  for (int d0 = 0; d0 < 128; d0 += 32) {
    for (int i = tid; i < 1024; i += 256) {
      int rr = i >> 3, dc = (i & 7) * 4;
      const float4 v = *(const float4*)&outw[(long)(r0 + rr) * 512 + h * 128 + d0 + dc];
      Ws[rr * 33 + dc + 0] = v.x; Ws[rr * 33 + dc + 1] = v.y;
      Ws[rr * 33 + dc + 2] = v.z; Ws[rr * 33 + dc + 3] = v.w;
    }
    for (int i = tid; i < 32 * N; i += 256) {
      int dd = i / N, k = i - dd * N;
      As[dd * (N + 1) + k] = va[(long)(h * 128 + d0) * N + i];
    }
    __syncthreads();
    for (int dd = 0; dd < 32; ++dd) {
      float w0 = Ws[il * 33 + dd];
      float w1 = Ws[(il + 64) * 33 + dd];
      const float* ap = As + dd * (N + 1) + q * NQ;
#pragma unroll
      for (int j = 0; j < NQ; ++j) {
        float a = ap[j];
        acc0[j] += w0 * a;
        acc1[j] += w1 * a;
      }
    }
    __syncthreads();
  }
  float* Ct = smem;
#pragma unroll
  for (int j = 0; j < NQ; ++j) {
    int k = q * NQ + j;
    Ct[k * 129 + il] = acc0[j];
    Ct[k * 129 + il + 64] = acc1[j];
  }
  __syncthreads();
  for (int i = tid; i < N * 128; i += 256) {
    int k = i >> 7, rr = i & 127;
    dst[(long)(h * N + k) * 512 + r0 + rr] = Ct[k * 129 + rr];
  }
}

__global__ __launch_bounds__(256) void ova_all(const float* __restrict__ ow0,
                                               const float* __restrict__ ow1,
                                               const float* __restrict__ wa,
                                               float* __restrict__ ova) {
  extern __shared__ float smem[];
  int a = blockIdx.x / 32, sub = blockIdx.x % 32;
  const float* wa0 = wa;
  const float* wa1 = wa + 276480L;
  float* ova0 = ova;
  float* ova1 = ova + 368640L;
  switch (a) {
    case 0: ova_body<12>(sub, ow0, ow1, wa0, wa1, ova0, ova1, smem); break;
    case 1: ova_body<24>(sub, ow0, ow1, wa0 + 12L * 1536, wa1 + 12L * 1536,
                         ova0 + 12L * 2048, ova1 + 12L * 2048, smem); break;
    case 2: ova_body<48>(sub, ow0, ow1, wa0 + 36L * 1536, wa1 + 36L * 1536,
                         ova0 + 36L * 2048, ova1 + 36L * 2048, smem); break;
    default: ova_body<96>(sub, ow0, ow1, wa0 + 84L * 1536, wa1 + 84L * 1536,
                          ova0 + 84L * 2048, ova1 + 84L * 2048, smem); break;
  }
}

// ---------------- stage B: fused anchor-folded attention, G=4 batches/block ----------------
__global__ __launch_bounds__(256) void attn_kernel(
    const float* __restrict__ xT, const int* __restrict__ per,
    const float* __restrict__ mp, const float* __restrict__ wa,
    const float* __restrict__ ova, const float* __restrict__ cons,
    const float* __restrict__ at_tab, const float* __restrict__ sb,
    const float* __restrict__ l1g, const float* __restrict__ l1b,
    const float* __restrict__ l2g, const float* __restrict__ l2b,
    float* __restrict__ comb) {
  __shared__ float xb[4 * 384];
  __shared__ float Z[4 * 1250];
  __shared__ float qy[4 * 512];
  __shared__ float arb[4 * 388];   // ar, later zh
  __shared__ float sc[4 * 388];
  __shared__ float qkc[16];
  __shared__ float red[8];

  int tid = threadIdx.x;
  int bid = blockIdx.x;
  int slot = bid & 1;
  int c = (bid >> 1) & 127;
  int b0 = (bid >> 8) * 4;
  int p = per[c * 2 + slot];
  int n = nanch(p);
  int np = Tn / p;
  int n1 = n + 1;
  float s = sqrtf((float)p / (float)n);
  const float rscale = 0.08838834764831845f;  // 1/sqrt(128)
  int pre = apre(n);
  const float* mpp = mp + mpoff(p);
  const float* qat = wa + (long)slot * 276480 + (long)pre * 1536;
  const float* kat = qat + (long)512 * n;
  const float* ovat = ova + (long)slot * 368640 + (long)pre * 2048;
  const float* atb = at_tab + (long)pre * 512;
  const float* qc = cons + slot * 1536;
  const float* kb = qc + 512;
  const float* oc = qc + 1024;
  const float* lng = slot ? l2g : l1g;
  const float* lnb = slot ? l2b : l1b;

  // Ph0: stage x rows
  for (int g = 0; g < 4; ++g)
    for (int t = tid; t < Tn; t += 256)
      xb[g * 384 + t] = xT[((long)c * Bn + b0 + g) * Tn + t];
  __syncthreads();

  // Ph1: Z = patches @ Mpinv  (np x n per batch), g-fused: 1 mpp read -> 4 FMA
  int znp = np * n;
  for (int idx = tid; idx < znp; idx += 256) {
    int j = idx / n, k = idx - j * n;
    int jb = j * p;
    const float* mk = mpp + k;
    const float* x0 = xb + jb;
    const float* x1 = xb + 384 + jb;
    const float* x2 = xb + 768 + jb;
    const float* x3 = xb + 1152 + jb;
    float a0 = 0.f, a1 = 0.f, a2 = 0.f, a3 = 0.f;
    for (int t = 0; t < p; ++t) {
      float m = mk[(long)t * n];
      a0 += m * x0[t]; a1 += m * x1[t]; a2 += m * x2[t]; a3 += m * x3[t];
    }
    int zi = j * n1 + k;
    Z[zi] = a0;
    Z[1250 + zi] = a1;
    Z[2500 + zi] = a2;
    Z[3750 + zi] = a3;
  }
  __syncthreads();

  int zlb0 = 0 * 1250 + (np - 1) * n1;
  int zlb1 = 1 * 1250 + (np - 1) * n1;
  int zlb2 = 2 * 1250 + (np - 1) * n1;
  int zlb3 = 3 * 1250 + (np - 1) * n1;

  // Ph2: q = s*QAt^T@Z_last + qc (batched over g; 2 rows/thread)
  {
    float a0[4] = {0.f, 0.f, 0.f, 0.f}, a1[4] = {0.f, 0.f, 0.f, 0.f};
    for (int k = 0; k < n; ++k) {
      float w0 = qat[(long)k * 512 + tid];
      float w1 = qat[(long)k * 512 + 256 + tid];
      float z0 = Z[zlb0 + k], z1 = Z[zlb1 + k], z2 = Z[zlb2 + k], z3 = Z[zlb3 + k];
      a0[0] += w0 * z0; a0[1] += w0 * z1; a0[2] += w0 * z2; a0[3] += w0 * z3;
      a1[0] += w1 * z0; a1[1] += w1 * z1; a1[2] += w1 * z2; a1[3] += w1 * z3;
    }
    float qc0 = qc[tid], qc1 = qc[256 + tid];
#pragma unroll
    for (int g = 0; g < 4; ++g) {
      qy[g * 512 + tid] = qc0 + s * a0[g];
      qy[g * 512 + 256 + tid] = qc1 + s * a1[g];
    }
  }
  __syncthreads();

  // Ph2b: qkc[g][h] = q_h . kb_h
  if (tid < 16) {
    int g = tid >> 2, h = tid & 3;
    float acc = 0.f;
    for (int i = 0; i < 128; ++i) acc += qy[g * 512 + h * 128 + i] * kb[h * 128 + i];
    qkc[g * 4 + h] = acc;
  }

  // Ph3: ar[g][h][k] = s * sum_i KAt[(h*128+i)*n+k] * q[g][h*128+i]
  {
    int tot = 16 * n;
    for (int idx = tid; idx < tot; idx += 256) {
      int g = idx / (4 * n);
      int r = idx - g * 4 * n;
      int h = r / n, k = r - h * n;
      float acc = 0.f;
      const float* kp = kat + (long)(h * 128) * n + k;
      const float* qp = qy + g * 512 + h * 128;
      for (int i = 0; i < 128; ++i) acc += kp[(long)i * n] * qp[i];
      arb[g * 388 + h * n + k] = s * acc;
    }
  }
  __syncthreads();

  // Ph4: scores
  {
    int tot = 16 * np;
    for (int idx = tid; idx < tot; idx += 256) {
      int g = idx / (4 * np);
      int r = idx - g * 4 * np;
      int h = r / np, j = r - h * np;
      const float* ap = arb + g * 388 + h * n;
      const float* zp = Z + g * 1250 + j * n1;
      float acc = 0.f;
      for (int k = 0; k < n; ++k) acc += ap[k] * zp[k];
      sc[g * 388 + h * np + j] = (acc + qkc[g * 4 + h]) * rscale;
    }
  }
  __syncthreads();

  // Ph5: softmax per (g,h), normalized probs in place
  if (tid < 16) {
    int g = tid >> 2, h = tid & 3;
    float* sp = sc + g * 388 + h * np;
    float m = -1e30f;
    for (int j = 0; j < np; ++j) m = fmaxf(m, sp[j]);
    float l = 0.f;
    for (int j = 0; j < np; ++j) { float e = expf(sp[j] - m); sp[j] = e; l += e; }
    float il = 1.f / l;
    for (int j = 0; j < np; ++j) sp[j] *= il;
  }
  __syncthreads();

  // Ph6: zh[g][h][k] = sum_j prob * Z[g][j][k]  (into arb)
  {
    int tot = 16 * n;
    for (int idx = tid; idx < tot; idx += 256) {
      int g = idx / (4 * n);
      int r = idx - g * 4 * n;
      int h = r / n, k = r - h * n;
      const float* sp = sc + g * 388 + h * np;
      const float* zp = Z + g * 1250 + k;
      float acc = 0.f;
      for (int j = 0; j < np; ++j) acc += sp[j] * zp[j * n1];
      arb[g * 388 + h * n + k] = acc;
    }
  }
  __syncthreads();

  // Ph7: y = s*(At@Z_last + sum_h OVAt@zh) + sb + oc  (into qy)
  {
    float a0[4] = {0.f, 0.f, 0.f, 0.f}, a1[4] = {0.f, 0.f, 0.f, 0.f};
    for (int k = 0; k < n; ++k) {
      float w0 = atb[(long)k * 512 + tid];
      float w1 = atb[(long)k * 512 + 256 + tid];
      float z0 = Z[zlb0 + k], z1 = Z[zlb1 + k], z2 = Z[zlb2 + k], z3 = Z[zlb3 + k];
      a0[0] += w0 * z0; a0[1] += w0 * z1; a0[2] += w0 * z2; a0[3] += w0 * z3;
      a1[0] += w1 * z0; a1[1] += w1 * z1; a1[2] += w1 * z2; a1[3] += w1 * z3;
    }
    for (int h = 0; h < 4; ++h) {
      const float* op = ovat + (long)(h * n) * 512;
      const float* zh0 = arb + 0 * 388 + h * n;
      const float* zh1 = arb + 1 * 388 + h * n;
      const float* zh2 = arb + 2 * 388 + h * n;
      const float* zh3 = arb + 3 * 388 + h * n;
      for (int k = 0; k < n; ++k) {
        float w0 = op[(long)k * 512 + tid];
        float w1 = op[(long)k * 512 + 256 + tid];
        float z0 = zh0[k], z1 = zh1[k], z2 = zh2[k], z3 = zh3[k];
        a0[0] += w0 * z0; a0[1] += w0 * z1; a0[2] += w0 * z2; a0[3] += w0 * z3;
        a1[0] += w1 * z0; a1[1] += w1 * z1; a1[2] += w1 * z2; a1[3] += w1 * z3;
      }
    }
    float s0 = sb[tid] + oc[tid];
    float s1 = sb[256 + tid] + oc[256 + tid];
    __syncthreads();
#pragma unroll
    for (int g = 0; g < 4; ++g) {
      qy[g * 512 + tid] = s * a0[g] + s0;
      qy[g * 512 + 256 + tid] = s * a1[g] + s1;
    }
  }
  __syncthreads();

  // Ph8: layernorm per batch row, write comb
  {
    int w = tid >> 6, lane = tid & 63;
    int g = w;
    float sm = 0.f, sq = 0.f;
    for (int kk = 0; kk < 8; ++kk) {
      float v = qy[g * 512 + lane + 64 * kk];
      sm += v; sq += v * v;
    }
    for (int off = 32; off > 0; off >>= 1) {
      sm += __shfl_down(sm, off, 64);
      sq += __shfl_down(sq, off, 64);
    }
    if (lane == 0) { red[g * 2] = sm; red[g * 2 + 1] = sq; }
    __syncthreads();
    float mu = red[g * 2] / 512.f;
    float var = red[g * 2 + 1] / 512.f - mu * mu;
    float rstd = rsqrtf(var + 1e-5f);
    long base = ((long)(b0 + g) * Cn + c) * 1536 + slot * 512;
    for (int kk = 0; kk < 8; ++kk) {
      int i = lane + 64 * kk;
      comb[base + i] = (qy[g * 512 + i] - mu) * rstd * lng[i] + lnb[i];
    }
  }
}

// ---------------- stage D: trend (anchor-folded) ----------------
__global__ __launch_bounds__(256) void trend_kernel(const float* __restrict__ xT,
                                                    const float* __restrict__ mp384,
                                                    const float* __restrict__ at96,
                                                    const float* __restrict__ sb,
                                                    float* __restrict__ comb) {
  __shared__ float xb[Bn * Tn];
  __shared__ float Ztr[Bn * 97];
  int c = blockIdx.x, tid = threadIdx.x;
  for (int i = tid; i < Bn * Tn; i += 256) xb[i] = xT[(long)c * Bn * Tn + i];
  __syncthreads();
  // Ztr: b-fused (1 mp384 read -> 4 FMA); items = 4 bq-groups x 96 k
  for (int idx = tid; idx < 4 * 96; idx += 256) {
    int bq = idx / 96, k = idx - bq * 96;
    const float* x0 = xb + (bq * 4 + 0) * Tn;
    const float* x1 = xb + (bq * 4 + 1) * Tn;
    const float* x2 = xb + (bq * 4 + 2) * Tn;
    const float* x3 = xb + (bq * 4 + 3) * Tn;
    const float* mk = mp384 + k;
    float a0 = 0.f, a1 = 0.f, a2 = 0.f, a3 = 0.f;
    for (int t = 0; t < Tn; ++t) {
      float m = mk[(long)t * 96];
      a0 += m * x0[t]; a1 += m * x1[t]; a2 += m * x2[t]; a3 += m * x3[t];
    }
    Ztr[(bq * 4 + 0) * 97 + k] = a0;
    Ztr[(bq * 4 + 1) * 97 + k] = a1;
    Ztr[(bq * 4 + 2) * 97 + k] = a2;
    Ztr[(bq * 4 + 3) * 97 + k] = a3;
  }
  __syncthreads();
  float acc0[Bn], acc1[Bn];
#pragma unroll
  for (int b = 0; b < Bn; ++b) { acc0[b] = 0.f; acc1[b] = 0.f; }
  for (int k = 0; k < 96; ++k) {
    float w0 = at96[(long)k * 512 + tid];
    float w1 = at96[(long)k * 512 + 256 + tid];
#pragma unroll
    for (int b = 0; b < Bn; ++b) {
      float z = Ztr[b * 97 + k];
      acc0[b] += w0 * z;
      acc1[b] += w1 * z;
    }
  }
  float s0 = sb[tid], s1 = sb[256 + tid];
#pragma unroll
  for (int b = 0; b < Bn; ++b) {
    long base = ((long)b * Cn + c) * 1536 + 1024;
    comb[base + tid] = 2.f * acc0[b] + s0;          // sqrt(384/96)=2
    comb[base + 256 + tid] = 2.f * acc1[b] + s1;
  }
}

// ---------------- stage E: tiled GEMM  C = act(A @ W^T + bias) ----------------
template <bool GELU>
__global__ __launch_bounds__(256) void fused_gemm(const float* __restrict__ A,
                                                  const float* __restrict__ W,
                                                  const float* __restrict__ bias,
                                                  float* __restrict__ C,
                                                  int N, int K) {
  __shared__ float As[32 * 68];
  __shared__ float Ws[32 * 68];
  int nb = N >> 6;
  int m0 = (blockIdx.x / nb) * 64, n0 = (blockIdx.x % nb) * 64;
  int tid = threadIdx.x;
  int tm = tid & 15, tn = tid >> 4;
  float acc[4][4];
#pragma unroll
  for (int i = 0; i < 4; ++i)
#pragma unroll
    for (int j = 0; j < 4; ++j) acc[i][j] = 0.f;
  int row = tid >> 3, kc = (tid & 7) * 4;
  for (int k0 = 0; k0 < K; k0 += 32) {
    {
      float4 v = *(const float4*)&A[(long)(m0 + row) * K + k0 + kc];
      As[(kc + 0) * 68 + row] = v.x; As[(kc + 1) * 68 + row] = v.y;
      As[(kc + 2) * 68 + row] = v.z; As[(kc + 3) * 68 + row] = v.w;
      v = *(const float4*)&A[(long)(m0 + row + 32) * K + k0 + kc];
      As[(kc + 0) * 68 + row + 32] = v.x; As[(kc + 1) * 68 + row + 32] = v.y;
      As[(kc + 2) * 68 + row + 32] = v.z; As[(kc + 3) * 68 + row + 32] = v.w;
      v = *(const float4*)&W[(long)(n0 + row) * K + k0 + kc];
      Ws[(kc + 0) * 68 + row] = v.x; Ws[(kc + 1) * 68 + row] = v.y;
      Ws[(kc + 2) * 68 + row] = v.z; Ws[(kc + 3) * 68 + row] = v.w;
      v = *(const float4*)&W[(long)(n0 + row + 32) * K + k0 + kc];
      Ws[(kc + 0) * 68 + row + 32] = v.x; Ws[(kc + 1) * 68 + row + 32] = v.y;
      Ws[(kc + 2) * 68 + row + 32] = v.z; Ws[(kc + 3) * 68 + row + 32] = v.w;
    }
    __syncthreads();
    for (int kk = 0; kk < 32; ++kk) {
      float4 a = *(const float4*)&As[kk * 68 + tm * 4];
      float4 w = *(const float4*)&Ws[kk * 68 + tn * 4];
      acc[0][0] += a.x * w.x; acc[0][1] += a.x * w.y; acc[0][2] += a.x * w.z; acc[0][3] += a.x * w.w;
      acc[1][0] += a.y * w.x; acc[1][1] += a.y * w.y; acc[1][2] += a.y * w.z; acc[1][3] += a.y * w.w;
      acc[2][0] += a.z * w.x; acc[2][1] += a.z * w.y; acc[2][2] += a.z * w.z; acc[2][3] += a.z * w.w;
      acc[3][0] += a.w * w.x; acc[3][1] += a.w * w.y; acc[3][2] += a.w * w.z; acc[3][3] += a.w * w.w;
    }
    __syncthreads();
  }
  float b0v = bias[n0 + tn * 4 + 0], b1v = bias[n0 + tn * 4 + 1];
  float b2v = bias[n0 + tn * 4 + 2], b3v = bias[n0 + tn * 4 + 3];
#pragma unroll
  for (int mi = 0; mi < 4; ++mi) {
    float4 o;
    o.x = acc[mi][0] + b0v; o.y = acc[mi][1] + b1v;
    o.z = acc[mi][2] + b2v; o.w = acc[mi][3] + b3v;
    if (GELU) {
      o.x = 0.5f * o.x * (1.f + erff(o.x * 0.7071067811865475f));
      o.y = 0.5f * o.y * (1.f + erff(o.y * 0.7071067811865475f));
      o.z = 0.5f * o.z * (1.f + erff(o.z * 0.7071067811865475f));
      o.w = 0.5f * o.w * (1.f + erff(o.w * 0.7071067811865475f));
    }
    *(float4*)&C[(long)(m0 + tm * 4 + mi) * N + n0 + tn * 4] = o;
  }
}

extern "C" void kernel_launch(void* const* d_in, const int* in_sizes, int n_in,
                              void* d_out, int out_size, void* d_ws, size_t ws_size,
                              hipStream_t stream) {
  const float* x    = (const float*)d_in[0];
  const float* a12  = (const float*)d_in[1];
  const float* a24  = (const float*)d_in[2];
  const float* a48  = (const float*)d_in[3];
  const float* a96  = (const float*)d_in[4];
  const float* sb   = (const float*)d_in[5];
  const float* g1iw = (const float*)d_in[6];
  const float* g1ib = (const float*)d_in[7];
  const float* g1ow = (const float*)d_in[8];
  const float* g1ob = (const float*)d_in[9];
  const float* g1lg = (const float*)d_in[10];
  const float* g1lb = (const float*)d_in[11];
  const float* g2iw = (const float*)d_in[12];
  const float* g2ib = (const float*)d_in[13];
  const float* g2ow = (const float*)d_in[14];
  const float* g2ob = (const float*)d_in[15];
  const float* g2lg = (const float*)d_in[16];
  const float* g2lb = (const float*)d_in[17];
  const float* fw1  = (const float*)d_in[18];
  const float* fb1  = (const float*)d_in[19];
  const float* fw2  = (const float*)d_in[20];
  const float* fb2  = (const float*)d_in[21];

  if (ws_size < (size_t)WS_FLOATS * sizeof(float)) return;

  float* ws   = (float*)d_ws;
  float* xT   = ws + OFF_XT;
  float* avgT = ws + OFF_AVG;
  int*   per  = (int*)(ws + OFF_PER);
  float* mp   = ws + OFF_MP;
  float* wa   = ws + OFF_WA;
  float* ova  = ws + OFF_OVA;
  float* cons = ws + OFF_CON;
  float* atb  = ws + OFF_AT;
  float* comb = ws + OFF_COMB;
  float* hbuf = ws + OFF_H;
  float* out  = (float*)d_out;

  transpose_kernel<<<192, 256, 0, stream>>>(x, xT);
  acf_kernel<<<Cn * 6, 256, 0, stream>>>(xT, avgT);
  periods_kernel<<<1, 128, 0, stream>>>(avgT, per);
  build_mpinv_kernel<<<190, 256, 0, stream>>>(per, mp);
  at_kernel<<<32, 256, 0, stream>>>(a12, a24, a48, a96, atb);
  consts_kernel<<<2, 1024, 0, stream>>>(g1iw, g1ib, g1ow, g1ob,
                                        g2iw, g2ib, g2ow, g2ob, sb, cons);
  wa_all<<<96, 256, 49536, stream>>>(g1iw, g2iw, a12, a24, a48, a96,
                                     wa, wa + 276480L);
  ova_all<<<128, 256, 49536, stream>>>(g1ow, g2ow, wa, ova);

  attn_kernel<<<1024, 256, 0, stream>>>(xT, per, mp, wa, ova, cons, atb, sb,
                                        g1lg, g1lb, g2lg, g2lb, comb);
  trend_kernel<<<Cn, 256, 0, stream>>>(xT, mp + 1634436L, atb + 84L * 512, sb, comb);
  fused_gemm<true><<<256, 256, 0, stream>>>(comb, fw1, fb1, hbuf, 512, 1536);
  fused_gemm<false><<<256, 256, 0, stream>>>(hbuf, fw2, fb2, out, 512, 512);
}

// Round 5
// 683.330 us; speedup vs baseline: 11.5367x; 1.6065x over previous
//
#include <hip/hip_runtime.h>
#include <math.h>

#define Bn 16
#define Tn 384
#define Cn 128

// ---------------- workspace layout (floats) ----------------
static constexpr long OFF_XT   = 0;         // 786432
static constexpr long OFF_AVG  = 786432;    // 49152
static constexpr long OFF_PER  = 835584;    // 256 ints
static constexpr long OFF_MP   = 835840;    // 1671300
static constexpr long OFF_AT   = 2507140;   // 98304: anchors^T padded to 192 rows [k*512+d]
static constexpr long OFF_WAF  = 2605444;   // 589824: per slot 1536x192 (in_w @ A_cat)
static constexpr long OFF_QAT  = 3195268;   // 196608: per slot 192x512 (Q-part transposed)
static constexpr long OFF_VAT  = 3391876;   // 196608: per slot 192x512 (V-part transposed)
static constexpr long OFF_OVT  = 3588484;   // 786432: per (slot,h) 192x512 OVA^T
static constexpr long OFF_CON  = 4374916;   // 3072
static constexpr long OFF_COMB = 4377988;   // 3145728
static constexpr long OFF_H    = 7523716;   // 1048576
static constexpr long WS_FLOATS = 8572292;  // ~34.3 MB

__host__ __device__ inline int nanch(int p) {
  if (p == 384) return 96;
  return (p <= 18) ? 12 : (p <= 36) ? 24 : (p <= 72) ? 48 : 96;
}
__host__ __device__ inline int apre(int n) {
  return (n == 12) ? 0 : (n == 24) ? 12 : (n == 48) ? 36 : 84;
}
__host__ __device__ inline long mpoff(int p) {
  if (p == 384) return 1634436L;
  long T = (long)(p - 1) * p / 2;
  if (p <= 18) return 12 * (T - 6);
  if (p <= 36) return 1980 + 24 * (T - 171);
  if (p <= 72) return 13860 + 48 * (T - 666);
  return 108036 + 96 * (T - 2628);
}

__device__ inline void irow(int j, int newl, int oldl, int& i0, int& i1, float& w) {
  double src = ((double)j + 0.5) * (double)oldl / (double)newl - 0.5;
  if (src < 0.0) src = 0.0;
  double mx = (double)(oldl - 1);
  if (src > mx) src = mx;
  int a = (int)src;
  if (a > oldl - 1) a = oldl - 1;
  i0 = a;
  i1 = (a + 1 < oldl) ? (a + 1) : (oldl - 1);
  w = (float)(src - (double)a);
}

// ---------------- stage 0: transpose x -> xT[c][b][t] ----------------
__global__ __launch_bounds__(256) void transpose_kernel(const float* __restrict__ x,
                                                        float* __restrict__ xT) {
  __shared__ float tile[32 * 129];
  int bid = blockIdx.x;
  int b = bid / 12, t0 = (bid % 12) * 32;
  int tid = threadIdx.x;
  for (int i = tid; i < 32 * 128; i += 256) {
    int tt = i >> 7, cc = i & 127;
    tile[tt * 129 + cc] = x[((long)b * Tn + t0 + tt) * Cn + cc];
  }
  __syncthreads();
  for (int i = tid; i < 32 * 128; i += 256) {
    int cc = i >> 5, tt = i & 31;
    xT[((long)cc * Bn + b) * Tn + t0 + tt] = tile[tt * 129 + cc];
  }
}

// ---------------- stage A1: ACF ----------------
__global__ __launch_bounds__(256) void acf_kernel(const float* __restrict__ xT,
                                                  float* __restrict__ avgT) {
  __shared__ float xb[Bn * 397];
  __shared__ float mean[Bn];
  int bid = blockIdx.x;
  int c = bid / 6, tile = bid % 6;
  int tid = threadIdx.x;
  for (int i = tid; i < Bn * Tn; i += 256) {
    int b = i / Tn, t = i - b * Tn;
    xb[b * 397 + t] = xT[(long)c * Bn * Tn + i];
  }
  for (int i = tid; i < Bn * 13; i += 256) {
    int b = i / 13, t = Tn + (i - b * 13);
    xb[b * 397 + t] = 0.f;
  }
  __syncthreads();
  if (tid < Bn) {
    float s = 0.f;
    for (int t = 0; t < Tn; ++t) s += xb[tid * 397 + t];
    mean[tid] = s / (float)Tn;
  }
  __syncthreads();
  for (int i = tid; i < Bn * Tn; i += 256) {
    int b = i / Tn, t = i - b * Tn;
    xb[b * 397 + t] -= mean[b];
  }
  __syncthreads();
  int q = tid >> 4;
  int g = tid & 15;
  int tau0 = tile * 64 + q * 4;
  const float* xr = xb + g * 397;
  float a0 = 0.f, a1 = 0.f, a2 = 0.f, a3 = 0.f;
  float w0 = xr[tau0], w1 = xr[tau0 + 1], w2 = xr[tau0 + 2], w3 = xr[tau0 + 3];
  int tmax = Tn - tau0;
  for (int t = 0; t < tmax; ++t) {
    float a = xr[t];
    float wn = xr[t + tau0 + 4];
    a0 += a * w0; a1 += a * w1; a2 += a * w2; a3 += a * w3;
    w0 = w1; w1 = w2; w2 = w3; w3 = wn;
  }
  for (int off = 8; off > 0; off >>= 1) {
    a0 += __shfl_down(a0, off, 16);
    a1 += __shfl_down(a1, off, 16);
    a2 += __shfl_down(a2, off, 16);
    a3 += __shfl_down(a3, off, 16);
  }
  if (g == 0) {
    avgT[(long)(tau0 + 0) * Cn + c] = a0;
    avgT[(long)(tau0 + 1) * Cn + c] = a1;
    avgT[(long)(tau0 + 2) * Cn + c] = a2;
    avgT[(long)(tau0 + 3) * Cn + c] = a3;
  }
}

// ---------------- stage A2: peaks ----------------
__global__ __launch_bounds__(128) void periods_kernel(const float* __restrict__ avgT,
                                                      int* __restrict__ per) {
  int c = threadIdx.x;
  if (c >= Cn) return;
  const float* a = avgT + c;
  const float NEG = -1e30f;
  float b1v = NEG, b2v = NEG;
  int b1i = 0, b2i = 0;
  float pv = NEG;
  float v = a[4L * Cn];
  for (int t = 4; t < Tn; ++t) {
    float nv = (t == Tn - 1) ? NEG : a[(long)(t + 1) * Cn];
    bool peak = (v > pv) && (v > nv) && (v > 0.f);
    float m = peak ? v : NEG;
    if (m > b1v)      { b2v = b1v; b2i = b1i; b1v = m; b1i = t; }
    else if (m > b2v) { b2v = m; b2i = t; }
    pv = v; v = nv;
  }
  per[c * 2 + 0] = min(max(b1i, 4), 192);
  per[c * 2 + 1] = min(max(b2i, 4), 192);
}

// ---------------- stage C: Mpinv via tridiagonal Thomas ----------------
__global__ __launch_bounds__(256) void build_mpinv_kernel(const int* __restrict__ per,
                                                          float* __restrict__ mp) {
  __shared__ int ii[384];
  __shared__ float ww[384];
  __shared__ float dd_[96], ee[96], cp[96], idt[96];
  __shared__ float ginv[96 * 97];
  __shared__ float outp[96 * 97];
  __shared__ int flag;
  int tid = threadIdx.x;
  int p = (blockIdx.x < 189) ? (4 + (int)blockIdx.x) : 384;
  if (tid == 0) flag = (p == 384) ? 1 : 0;
  __syncthreads();
  if (p != 384) {
    for (int i = tid; i < Cn * 2; i += 256)
      if (per[i] == p) flag = 1;
  }
  __syncthreads();
  if (!flag) return;

  int n = nanch(p);
  int m = (p >= n) ? n : p;
  float* dst = mp + mpoff(p);

  for (int j = tid; j < p; j += 256) {
    int i0, i1; float w;
    irow(j, p, n, i0, i1, w);
    ii[j] = i0; ww[j] = w;
  }
  for (int i = tid; i < m; i += 256) { dd_[i] = 0.f; ee[i] = 0.f; }
  __syncthreads();

  if (p >= n) {
    for (int j = tid; j < p; j += 256) {
      int i0 = ii[j]; float w = ww[j];
      int i1 = min(i0 + 1, n - 1);
      if (i1 == i0) {
        atomicAdd(&dd_[i0], 1.0f);
      } else {
        float a = 1.f - w, b = w;
        atomicAdd(&dd_[i0], a * a);
        atomicAdd(&dd_[i1], b * b);
        atomicAdd(&ee[i0], a * b);
      }
    }
  } else {
    for (int r = tid; r < p; r += 256) {
      int i0 = ii[r]; float w = ww[r];
      int i1 = min(i0 + 1, n - 1);
      float a, b; int c0 = i0, c1 = i1;
      if (i1 == i0) { a = 1.f; b = 0.f; c1 = -1; }
      else { a = 1.f - w; b = w; }
      dd_[r] = a * a + b * b;
      if (r < p - 1) {
        int j0 = ii[r + 1]; float w2 = ww[r + 1];
        int j1 = min(j0 + 1, n - 1);
        float a2, b2; int d0 = j0, d1 = j1;
        if (j1 == j0) { a2 = 1.f; b2 = 0.f; d1 = -2; }
        else { a2 = 1.f - w2; b2 = w2; }
        float s = 0.f;
        if (c0 == d0) s += a * a2;
        if (c0 == d1) s += a * b2;
        if (c1 == d0) s += b * a2;
        if (c1 == d1) s += b * b2;
        ee[r] = s;
      }
    }
  }
  __syncthreads();
  if (tid == 0) {
    float dt = dd_[0];
    idt[0] = 1.f / dt;
    for (int i = 1; i < m; ++i) {
      float c = ee[i - 1] * idt[i - 1];
      cp[i - 1] = c;
      dt = dd_[i] - ee[i - 1] * c;
      idt[i] = 1.f / dt;
    }
  }
  __syncthreads();
  if (tid < m) {
    int j = tid;
    float z = 1.f;
    ginv[j * 97 + j] = 1.f;
    for (int i = j + 1; i < m; ++i) {
      z = -cp[i - 1] * z;
      ginv[i * 97 + j] = z;
    }
    float xn = ginv[(m - 1) * 97 + j] * idt[m - 1];
    ginv[(m - 1) * 97 + j] = xn;
    for (int i = m - 2; i >= 0; --i) {
      float zi = (i >= j) ? ginv[i * 97 + j] : 0.f;
      xn = zi * idt[i] - cp[i] * xn;
      ginv[i * 97 + j] = xn;
    }
  }
  __syncthreads();
  if (p >= n) {
    for (int idx = tid; idx < p * n; idx += 256) {
      int t = idx / n, k = idx - t * n;
      int i0 = ii[t]; float w = ww[t];
      int i1 = min(i0 + 1, n - 1);
      dst[idx] = (1.f - w) * ginv[i0 * 97 + k] + w * ginv[i1 * 97 + k];
    }
  } else {
    for (int t = tid; t < p; t += 256) {
      for (int k = 0; k < n; ++k) outp[t * 97 + k] = 0.f;
      for (int j = 0; j < p; ++j) {
        float hv = ginv[t * 97 + j];
        int i0 = ii[j]; float w = ww[j];
        int i1 = min(i0 + 1, n - 1);
        outp[t * 97 + i0] += hv * (1.f - w);
        outp[t * 97 + i1] += hv * w;
      }
    }
    __syncthreads();
    for (int idx = tid; idx < p * n; idx += 256) {
      int t = idx / n, k = idx - t * n;
      dst[idx] = outp[t * 97 + k];
    }
  }
}

// ---------------- stage P1: anchors^T -> at_tab (192x512, pad zeroed) ----------------
__global__ __launch_bounds__(256) void at_kernel(const float* __restrict__ a12,
                                                 const float* __restrict__ a24,
                                                 const float* __restrict__ a48,
                                                 const float* __restrict__ a96,
                                                 float* __restrict__ at_tab) {
  __shared__ float tile[64 * 97];
  int bid = blockIdx.x;     // 4 anchors * 8 d-chunks
  int a = bid >> 3, d0 = (bid & 7) * 64;
  int n = (a == 0) ? 12 : (a == 1) ? 24 : (a == 2) ? 48 : 96;
  const float* src = (a == 0) ? a12 : (a == 1) ? a24 : (a == 2) ? a48 : a96;
  float* dst = at_tab + (long)apre(n) * 512;
  int tid = threadIdx.x;
  for (int i = tid; i < 64 * n; i += 256) {
    int dd = i / n, k = i - dd * n;
    tile[dd * 97 + k] = src[(long)(d0 + dd) * n + (long)k];
  }
  __syncthreads();
  for (int i = tid; i < n * 64; i += 256) {
    int k = i >> 6, dd = i & 63;
    dst[(long)k * 512 + d0 + dd] = tile[dd * 97 + k];
  }
  if (bid == 0) {  // zero pad rows 180..191
    for (int i = tid; i < 12 * 512; i += 256) at_tab[180L * 512 + i] = 0.f;
  }
}

// ---------------- stage P3: bias folds ----------------
__global__ __launch_bounds__(1024) void consts_kernel(
    const float* __restrict__ i1w, const float* __restrict__ i1b,
    const float* __restrict__ o1w, const float* __restrict__ o1b,
    const float* __restrict__ i2w, const float* __restrict__ i2b,
    const float* __restrict__ o2w, const float* __restrict__ o2b,
    const float* __restrict__ sb, float* __restrict__ cons) {
  __shared__ float sv[512];
  __shared__ float vb[512];
  int s = blockIdx.x, tid = threadIdx.x;
  const float* inw = s ? i2w : i1w;
  const float* inb = s ? i2b : i1b;
  const float* outw = s ? o2w : o1w;
  const float* outb = s ? o2b : o1b;
  float* dst = cons + s * 1536;
  if (tid < 512) sv[tid] = sb[tid];
  __syncthreads();
  int lane = tid & 63, w = tid >> 6;
  for (int r = w; r < 1536; r += 16) {
    const float* row = inw + (long)r * 512;
    float part = 0.f;
    for (int kk = 0; kk < 8; ++kk) part += row[lane + 64 * kk] * sv[lane + 64 * kk];
    for (int off = 32; off > 0; off >>= 1) part += __shfl_down(part, off, 64);
    if (lane == 0) {
      float v = part + inb[r];
      if (r < 1024) dst[r] = v;
      else vb[r - 1024] = v;
    }
  }
  __syncthreads();
  for (int r = w; r < 512; r += 16) {
    const float* row = outw + (long)r * 512;
    float part = 0.f;
    for (int kk = 0; kk < 8; ++kk) part += row[lane + 64 * kk] * vb[lane + 64 * kk];
    for (int off = 32; off > 0; off >>= 1) part += __shfl_down(part, off, 64);
    if (lane == 0) dst[1024 + r] = part + outb[r];
  }
}

// ---------------- stage P2: WAfull = in_w @ A_cat (1536x192 per slot) ----------------
// grid: 2 slots x 24 mtiles x 3 ntiles. Epilogue also writes QAt/VAt transposed.
__global__ __launch_bounds__(256) void wa_gemm2(const float* __restrict__ iw0,
                                                const float* __restrict__ iw1,
                                                const float* __restrict__ atb,
                                                float* __restrict__ waf,
                                                float* __restrict__ qat,
                                                float* __restrict__ vat) {
  __shared__ float smem[2 * 32 * 68];
  float* As = smem;
  float* Ws = smem + 32 * 68;
  int bid = blockIdx.x;
  int s = bid / 72, r = bid % 72;
  int m0 = (r / 3) * 64, n0 = (r % 3) * 64;
  const float* A = s ? iw1 : iw0;
  float* wafs = waf + (long)s * 294912;
  int tid = threadIdx.x;
  int tm = tid & 15, tn = tid >> 4;
  float acc[4][4];
#pragma unroll
  for (int i = 0; i < 4; ++i)
#pragma unroll
    for (int j = 0; j < 4; ++j) acc[i][j] = 0.f;
  int row = tid >> 3, kc = (tid & 7) * 4;
  for (int k0 = 0; k0 < 512; k0 += 32) {
    float4 v = *(const float4*)&A[(long)(m0 + row) * 512 + k0 + kc];
    As[(kc + 0) * 68 + row] = v.x; As[(kc + 1) * 68 + row] = v.y;
    As[(kc + 2) * 68 + row] = v.z; As[(kc + 3) * 68 + row] = v.w;
    v = *(const float4*)&A[(long)(m0 + row + 32) * 512 + k0 + kc];
    As[(kc + 0) * 68 + row + 32] = v.x; As[(kc + 1) * 68 + row + 32] = v.y;
    As[(kc + 2) * 68 + row + 32] = v.z; As[(kc + 3) * 68 + row + 32] = v.w;
    v = *(const float4*)&atb[(long)(n0 + row) * 512 + k0 + kc];
    Ws[(kc + 0) * 68 + row] = v.x; Ws[(kc + 1) * 68 + row] = v.y;
    Ws[(kc + 2) * 68 + row] = v.z; Ws[(kc + 3) * 68 + row] = v.w;
    v = *(const float4*)&atb[(long)(n0 + row + 32) * 512 + k0 + kc];
    Ws[(kc + 0) * 68 + row + 32] = v.x; Ws[(kc + 1) * 68 + row + 32] = v.y;
    Ws[(kc + 2) * 68 + row + 32] = v.z; Ws[(kc + 3) * 68 + row + 32] = v.w;
    __syncthreads();
    for (int kk = 0; kk < 32; ++kk) {
      float4 a = *(const float4*)&As[kk * 68 + tm * 4];
      float4 w = *(const float4*)&Ws[kk * 68 + tn * 4];
      acc[0][0] += a.x * w.x; acc[0][1] += a.x * w.y; acc[0][2] += a.x * w.z; acc[0][3] += a.x * w.w;
      acc[1][0] += a.y * w.x; acc[1][1] += a.y * w.y; acc[1][2] += a.y * w.z; acc[1][3] += a.y * w.w;
      acc[2][0] += a.z * w.x; acc[2][1] += a.z * w.y; acc[2][2] += a.z * w.z; acc[2][3] += a.z * w.w;
      acc[3][0] += a.w * w.x; acc[3][1] += a.w * w.y; acc[3][2] += a.w * w.z; acc[3][3] += a.w * w.w;
    }
    __syncthreads();
  }
  // row-major write (K-part rows 512..1023 are consumed this way)
#pragma unroll
  for (int mi = 0; mi < 4; ++mi) {
    float4 o;
    o.x = acc[mi][0]; o.y = acc[mi][1]; o.z = acc[mi][2]; o.w = acc[mi][3];
    *(float4*)&wafs[(long)(m0 + tm * 4 + mi) * 192 + n0 + tn * 4] = o;
  }
  // transposed write for Q (rows<512) and V (rows>=1024) regions
  if (m0 < 512 || m0 >= 1024) {
    float* Ct = smem;  // 64*65 = 4160 <= 4352
#pragma unroll
    for (int mi = 0; mi < 4; ++mi)
#pragma unroll
      for (int j = 0; j < 4; ++j)
        Ct[(tn * 4 + j) * 65 + tm * 4 + mi] = acc[mi][j];
    __syncthreads();
    float* dst = ((m0 < 512) ? qat : vat) + (long)s * 98304;
    int mr = m0 & 511;
    for (int i = tid; i < 64 * 64; i += 256) {
      int cc = i >> 6, rr = i & 63;
      dst[(long)(n0 + cc) * 512 + mr + rr] = Ct[cc * 65 + rr];
    }
  }
}

// ---------------- stage P4: OVA^T per (slot,head): VAt_h @ out_w_h^T (192x512) ----------------
// grid: 2 slots x 4 heads x 3 mtiles x 8 ntiles
__global__ __launch_bounds__(256) void ova_gemm2(const float* __restrict__ ow0,
                                                 const float* __restrict__ ow1,
                                                 const float* __restrict__ vat,
                                                 float* __restrict__ ovt) {
  __shared__ float As[32 * 68];
  __shared__ float Ws[32 * 68];
  int bid = blockIdx.x;
  int s = bid / 96, r = bid % 96;
  int h = r / 24, r2 = r % 24;
  int m0 = (r2 / 8) * 64, n0 = (r2 % 8) * 64;
  const float* A = vat + (long)s * 98304 + h * 128;
  const float* W = (s ? ow1 : ow0) + h * 128;
  float* C = ovt + ((long)(s * 4 + h) * 192) * 512;
  int tid = threadIdx.x;
  int tm = tid & 15, tn = tid >> 4;
  float acc[4][4];
#pragma unroll
  for (int i = 0; i < 4; ++i)
#pragma unroll
    for (int j = 0; j < 4; ++j) acc[i][j] = 0.f;
  int row = tid >> 3, kc = (tid & 7) * 4;
  for (int k0 = 0; k0 < 128; k0 += 32) {
    float4 v = *(const float4*)&A[(long)(m0 + row) * 512 + k0 + kc];
    As[(kc + 0) * 68 + row] = v.x; As[(kc + 1) * 68 + row] = v.y;
    As[(kc + 2) * 68 + row] = v.z; As[(kc + 3) * 68 + row] = v.w;
    v = *(const float4*)&A[(long)(m0 + row + 32) * 512 + k0 + kc];
    As[(kc + 0) * 68 + row + 32] = v.x; As[(kc + 1) * 68 + row + 32] = v.y;
    As[(kc + 2) * 68 + row + 32] = v.z; As[(kc + 3) * 68 + row + 32] = v.w;
    v = *(const float4*)&W[(long)(n0 + row) * 512 + k0 + kc];
    Ws[(kc + 0) * 68 + row] = v.x; Ws[(kc + 1) * 68 + row] = v.y;
    Ws[(kc + 2) * 68 + row] = v.z; Ws[(kc + 3) * 68 + row] = v.w;
    v = *(const float4*)&W[(long)(n0 + row + 32) * 512 + k0 + kc];
    Ws[(kc + 0) * 68 + row + 32] = v.x; Ws[(kc + 1) * 68 + row + 32] = v.y;
    Ws[(kc + 2) * 68 + row + 32] = v.z; Ws[(kc + 3) * 68 + row + 32] = v.w;
    __syncthreads();
    for (int kk = 0; kk < 32; ++kk) {
      float4 a = *(const float4*)&As[kk * 68 + tm * 4];
      float4 w = *(const float4*)&Ws[kk * 68 + tn * 4];
      acc[0][0] += a.x * w.x; acc[0][1] += a.x * w.y; acc[0][2] += a.x * w.z; acc[0][3] += a.x * w.w;
      acc[1][0] += a.y * w.x; acc[1][1] += a.y * w.y; acc[1][2] += a.y * w.z; acc[1][3] += a.y * w.w;
      acc[2][0] += a.z * w.x; acc[2][1] += a.z * w.y; acc[2][2] += a.z * w.z; acc[2][3] += a.z * w.w;
      acc[3][0] += a.w * w.x; acc[3][1] += a.w * w.y; acc[3][2] += a.w * w.z; acc[3][3] += a.w * w.w;
    }
    __syncthreads();
  }
#pragma unroll
  for (int mi = 0; mi < 4; ++mi) {
    float4 o;
    o.x = acc[mi][0]; o.y = acc[mi][1]; o.z = acc[mi][2]; o.w = acc[mi][3];
    *(float4*)&C[(long)(m0 + tm * 4 + mi) * 512 + n0 + tn * 4] = o;
  }
}

// ---------------- stage B: fused anchor-folded attention ----------------
__global__ __launch_bounds__(256) void attn_kernel(
    const float* __restrict__ xT, const int* __restrict__ per,
    const float* __restrict__ mp, const float* __restrict__ qat_tab,
    const float* __restrict__ wafull, const float* __restrict__ ovt,
    const float* __restrict__ cons, const float* __restrict__ at_tab,
    const float* __restrict__ sb,
    const float* __restrict__ l1g, const float* __restrict__ l1b,
    const float* __restrict__ l2g, const float* __restrict__ l2b,
    float* __restrict__ comb) {
  __shared__ float xb[4 * 384];
  __shared__ float Z[4 * 1250];
  __shared__ float qy[4 * 512];
  __shared__ float arb[4 * 388];
  __shared__ float sc[4 * 388];
  __shared__ float qkc[16];
  __shared__ float red[8];

  int tid = threadIdx.x;
  int bid = blockIdx.x;
  int slot = bid & 1;
  int c = (bid >> 1) & 127;
  int b0 = (bid >> 8) * 4;
  int p = per[c * 2 + slot];
  int n = nanch(p);
  int np = Tn / p;
  int n1 = n + 1;
  float s = sqrtf((float)p / (float)n);
  const float rscale = 0.08838834764831845f;
  int pre = apre(n);
  const float* mpp = mp + mpoff(p);
  const float* qat = qat_tab + (long)slot * 98304 + (long)pre * 512;
  const float* katb = wafull + (long)slot * 294912 + 98304 + pre;  // rows 512.., col pre
  const float* ovs = ovt + (long)slot * 4 * 98304;
  const float* atb = at_tab + (long)pre * 512;
  const float* qc = cons + slot * 1536;
  const float* kb = qc + 512;
  const float* oc = qc + 1024;
  const float* lng = slot ? l2g : l1g;
  const float* lnb = slot ? l2b : l1b;

  for (int g = 0; g < 4; ++g)
    for (int t = tid; t < Tn; t += 256)
      xb[g * 384 + t] = xT[((long)c * Bn + b0 + g) * Tn + t];
  __syncthreads();

  // Ph1: Z = patches @ Mpinv (g-fused)
  int znp = np * n;
  for (int idx = tid; idx < znp; idx += 256) {
    int j = idx / n, k = idx - j * n;
    int jb = j * p;
    const float* mk = mpp + k;
    const float* x0 = xb + jb;
    const float* x1 = xb + 384 + jb;
    const float* x2 = xb + 768 + jb;
    const float* x3 = xb + 1152 + jb;
    float a0 = 0.f, a1 = 0.f, a2 = 0.f, a3 = 0.f;
    for (int t = 0; t < p; ++t) {
      float m = mk[(long)t * n];
      a0 += m * x0[t]; a1 += m * x1[t]; a2 += m * x2[t]; a3 += m * x3[t];
    }
    int zi = j * n1 + k;
    Z[zi] = a0;
    Z[1250 + zi] = a1;
    Z[2500 + zi] = a2;
    Z[3750 + zi] = a3;
  }
  __syncthreads();

  int zlb0 = 0 * 1250 + (np - 1) * n1;
  int zlb1 = 1 * 1250 + (np - 1) * n1;
  int zlb2 = 2 * 1250 + (np - 1) * n1;
  int zlb3 = 3 * 1250 + (np - 1) * n1;

  // Ph2: q
  {
    float a0[4] = {0.f, 0.f, 0.f, 0.f}, a1[4] = {0.f, 0.f, 0.f, 0.f};
    for (int k = 0; k < n; ++k) {
      float w0 = qat[(long)k * 512 + tid];
      float w1 = qat[(long)k * 512 + 256 + tid];
      float z0 = Z[zlb0 + k], z1 = Z[zlb1 + k], z2 = Z[zlb2 + k], z3 = Z[zlb3 + k];
      a0[0] += w0 * z0; a0[1] += w0 * z1; a0[2] += w0 * z2; a0[3] += w0 * z3;
      a1[0] += w1 * z0; a1[1] += w1 * z1; a1[2] += w1 * z2; a1[3] += w1 * z3;
    }
    float qc0 = qc[tid], qc1 = qc[256 + tid];
#pragma unroll
    for (int g = 0; g < 4; ++g) {
      qy[g * 512 + tid] = qc0 + s * a0[g];
      qy[g * 512 + 256 + tid] = qc1 + s * a1[g];
    }
  }
  __syncthreads();

  if (tid < 16) {
    int g = tid >> 2, h = tid & 3;
    float acc = 0.f;
    for (int i = 0; i < 128; ++i) acc += qy[g * 512 + h * 128 + i] * kb[h * 128 + i];
    qkc[g * 4 + h] = acc;
  }

  // Ph3: ar
  {
    int tot = 16 * n;
    for (int idx = tid; idx < tot; idx += 256) {
      int g = idx / (4 * n);
      int r = idx - g * 4 * n;
      int h = r / n, k = r - h * n;
      float acc = 0.f;
      const float* kp = katb + (long)(h * 128) * 192 + k;
      const float* qp = qy + g * 512 + h * 128;
      for (int i = 0; i < 128; ++i) acc += kp[(long)i * 192] * qp[i];
      arb[g * 388 + h * n + k] = s * acc;
    }
  }
  __syncthreads();

  // Ph4: scores
  {
    int tot = 16 * np;
    for (int idx = tid; idx < tot; idx += 256) {
      int g = idx / (4 * np);
      int r = idx - g * 4 * np;
      int h = r / np, j = r - h * np;
      const float* ap = arb + g * 388 + h * n;
      const float* zp = Z + g * 1250 + j * n1;
      float acc = 0.f;
      for (int k = 0; k < n; ++k) acc += ap[k] * zp[k];
      sc[g * 388 + h * np + j] = (acc + qkc[g * 4 + h]) * rscale;
    }
  }
  __syncthreads();

  // Ph5: softmax
  if (tid < 16) {
    int g = tid >> 2, h = tid & 3;
    float* sp = sc + g * 388 + h * np;
    float m = -1e30f;
    for (int j = 0; j < np; ++j) m = fmaxf(m, sp[j]);
    float l = 0.f;
    for (int j = 0; j < np; ++j) { float e = expf(sp[j] - m); sp[j] = e; l += e; }
    float il = 1.f / l;
    for (int j = 0; j < np; ++j) sp[j] *= il;
  }
  __syncthreads();

  // Ph6: zh
  {
    int tot = 16 * n;
    for (int idx = tid; idx < tot; idx += 256) {
      int g = idx / (4 * n);
      int r = idx - g * 4 * n;
      int h = r / n, k = r - h * n;
      const float* sp = sc + g * 388 + h * np;
      const float* zp = Z + g * 1250 + k;
      float acc = 0.f;
      for (int j = 0; j < np; ++j) acc += sp[j] * zp[j * n1];
      arb[g * 388 + h * n + k] = acc;
    }
  }
  __syncthreads();

  // Ph7: y
  {
    float a0[4] = {0.f, 0.f, 0.f, 0.f}, a1[4] = {0.f, 0.f, 0.f, 0.f};
    for (int k = 0; k < n; ++k) {
      float w0 = atb[(long)k * 512 + tid];
      float w1 = atb[(long)k * 512 + 256 + tid];
      float z0 = Z[zlb0 + k], z1 = Z[zlb1 + k], z2 = Z[zlb2 + k], z3 = Z[zlb3 + k];
      a0[0] += w0 * z0; a0[1] += w0 * z1; a0[2] += w0 * z2; a0[3] += w0 * z3;
      a1[0] += w1 * z0; a1[1] += w1 * z1; a1[2] += w1 * z2; a1[3] += w1 * z3;
    }
    for (int h = 0; h < 4; ++h) {
      const float* op = ovs + ((long)h * 192 + pre) * 512;
      const float* zh0 = arb + 0 * 388 + h * n;
      const float* zh1 = arb + 1 * 388 + h * n;
      const float* zh2 = arb + 2 * 388 + h * n;
      const float* zh3 = arb + 3 * 388 + h * n;
      for (int k = 0; k < n; ++k) {
        float w0 = op[(long)k * 512 + tid];
        float w1 = op[(long)k * 512 + 256 + tid];
        float z0 = zh0[k], z1 = zh1[k], z2 = zh2[k], z3 = zh3[k];
        a0[0] += w0 * z0; a0[1] += w0 * z1; a0[2] += w0 * z2; a0[3] += w0 * z3;
        a1[0] += w1 * z0; a1[1] += w1 * z1; a1[2] += w1 * z2; a1[3] += w1 * z3;
      }
    }
    float s0 = sb[tid] + oc[tid];
    float s1 = sb[256 + tid] + oc[256 + tid];
    __syncthreads();
#pragma unroll
    for (int g = 0; g < 4; ++g) {
      qy[g * 512 + tid] = s * a0[g] + s0;
      qy[g * 512 + 256 + tid] = s * a1[g] + s1;
    }
  }
  __syncthreads();

  // Ph8: layernorm
  {
    int w = tid >> 6, lane = tid & 63;
    int g = w;
    float sm = 0.f, sq = 0.f;
    for (int kk = 0; kk < 8; ++kk) {
      float v = qy[g * 512 + lane + 64 * kk];
      sm += v; sq += v * v;
    }
    for (int off = 32; off > 0; off >>= 1) {
      sm += __shfl_down(sm, off, 64);
      sq += __shfl_down(sq, off, 64);
    }
    if (lane == 0) { red[g * 2] = sm; red[g * 2 + 1] = sq; }
    __syncthreads();
    float mu = red[g * 2] / 512.f;
    float var = red[g * 2 + 1] / 512.f - mu * mu;
    float rstd = rsqrtf(var + 1e-5f);
    long base = ((long)(b0 + g) * Cn + c) * 1536 + slot * 512;
    for (int kk = 0; kk < 8; ++kk) {
      int i = lane + 64 * kk;
      comb[base + i] = (qy[g * 512 + i] - mu) * rstd * lng[i] + lnb[i];
    }
  }
}

// ---------------- stage D: trend ----------------
__global__ __launch_bounds__(256) void trend_kernel(const float* __restrict__ xT,
                                                    const float* __restrict__ mp384,
                                                    const float* __restrict__ at96,
                                                    const float* __restrict__ sb,
                                                    float* __restrict__ comb) {
  __shared__ float xb[Bn * Tn];
  __shared__ float Ztr[Bn * 97];
  int c = blockIdx.x, tid = threadIdx.x;
  for (int i = tid; i < Bn * Tn; i += 256) xb[i] = xT[(long)c * Bn * Tn + i];
  __syncthreads();
  for (int idx = tid; idx < 4 * 96; idx += 256) {
    int bq = idx / 96, k = idx - bq * 96;
    const float* x0 = xb + (bq * 4 + 0) * Tn;
    const float* x1 = xb + (bq * 4 + 1) * Tn;
    const float* x2 = xb + (bq * 4 + 2) * Tn;
    const float* x3 = xb + (bq * 4 + 3) * Tn;
    const float* mk = mp384 + k;
    float a0 = 0.f, a1 = 0.f, a2 = 0.f, a3 = 0.f;
    for (int t = 0; t < Tn; ++t) {
      float m = mk[(long)t * 96];
      a0 += m * x0[t]; a1 += m * x1[t]; a2 += m * x2[t]; a3 += m * x3[t];
    }
    Ztr[(bq * 4 + 0) * 97 + k] = a0;
    Ztr[(bq * 4 + 1) * 97 + k] = a1;
    Ztr[(bq * 4 + 2) * 97 + k] = a2;
    Ztr[(bq * 4 + 3) * 97 + k] = a3;
  }
  __syncthreads();
  float acc0[Bn], acc1[Bn];
#pragma unroll
  for (int b = 0; b < Bn; ++b) { acc0[b] = 0.f; acc1[b] = 0.f; }
  for (int k = 0; k < 96; ++k) {
    float w0 = at96[(long)k * 512 + tid];
    float w1 = at96[(long)k * 512 + 256 + tid];
#pragma unroll
    for (int b = 0; b < Bn; ++b) {
      float z = Ztr[b * 97 + k];
      acc0[b] += w0 * z;
      acc1[b] += w1 * z;
    }
  }
  float s0 = sb[tid], s1 = sb[256 + tid];
#pragma unroll
  for (int b = 0; b < Bn; ++b) {
    long base = ((long)b * Cn + c) * 1536 + 1024;
    comb[base + tid] = 2.f * acc0[b] + s0;
    comb[base + 256 + tid] = 2.f * acc1[b] + s1;
  }
}

// ---------------- stage E: fusion GEMM ----------------
template <bool GELU>
__global__ __launch_bounds__(256) void fused_gemm(const float* __restrict__ A,
                                                  const float* __restrict__ W,
                                                  const float* __restrict__ bias,
                                                  float* __restrict__ C,
                                                  int N, int K) {
  __shared__ float As[32 * 68];
  __shared__ float Ws[32 * 68];
  int nb = N >> 6;
  int m0 = (blockIdx.x / nb) * 64, n0 = (blockIdx.x % nb) * 64;
  int tid = threadIdx.x;
  int tm = tid & 15, tn = tid >> 4;
  float acc[4][4];
#pragma unroll
  for (int i = 0; i < 4; ++i)
#pragma unroll
    for (int j = 0; j < 4; ++j) acc[i][j] = 0.f;
  int row = tid >> 3, kc = (tid & 7) * 4;
  for (int k0 = 0; k0 < K; k0 += 32) {
    {
      float4 v = *(const float4*)&A[(long)(m0 + row) * K + k0 + kc];
      As[(kc + 0) * 68 + row] = v.x; As[(kc + 1) * 68 + row] = v.y;
      As[(kc + 2) * 68 + row] = v.z; As[(kc + 3) * 68 + row] = v.w;
      v = *(const float4*)&A[(long)(m0 + row + 32) * K + k0 + kc];
      As[(kc + 0) * 68 + row + 32] = v.x; As[(kc + 1) * 68 + row + 32] = v.y;
      As[(kc + 2) * 68 + row + 32] = v.z; As[(kc + 3) * 68 + row + 32] = v.w;
      v = *(const float4*)&W[(long)(n0 + row) * K + k0 + kc];
      Ws[(kc + 0) * 68 + row] = v.x; Ws[(kc + 1) * 68 + row] = v.y;
      Ws[(kc + 2) * 68 + row] = v.z; Ws[(kc + 3) * 68 + row] = v.w;
      v = *(const float4*)&W[(long)(n0 + row + 32) * K + k0 + kc];
      Ws[(kc + 0) * 68 + row + 32] = v.x; Ws[(kc + 1) * 68 + row + 32] = v.y;
      Ws[(kc + 2) * 68 + row + 32] = v.z; Ws[(kc + 3) * 68 + row + 32] = v.w;
    }
    __syncthreads();
    for (int kk = 0; kk < 32; ++kk) {
      float4 a = *(const float4*)&As[kk * 68 + tm * 4];
      float4 w = *(const float4*)&Ws[kk * 68 + tn * 4];
      acc[0][0] += a.x * w.x; acc[0][1] += a.x * w.y; acc[0][2] += a.x * w.z; acc[0][3] += a.x * w.w;
      acc[1][0] += a.y * w.x; acc[1][1] += a.y * w.y; acc[1][2] += a.y * w.z; acc[1][3] += a.y * w.w;
      acc[2][0] += a.z * w.x; acc[2][1] += a.z * w.y; acc[2][2] += a.z * w.z; acc[2][3] += a.z * w.w;
      acc[3][0] += a.w * w.x; acc[3][1] += a.w * w.y; acc[3][2] += a.w * w.z; acc[3][3] += a.w * w.w;
    }
    __syncthreads();
  }
  float b0v = bias[n0 + tn * 4 + 0], b1v = bias[n0 + tn * 4 + 1];
  float b2v = bias[n0 + tn * 4 + 2], b3v = bias[n0 + tn * 4 + 3];
#pragma unroll
  for (int mi = 0; mi < 4; ++mi) {
    float4 o;
    o.x = acc[mi][0] + b0v; o.y = acc[mi][1] + b1v;
    o.z = acc[mi][2] + b2v; o.w = acc[mi][3] + b3v;
    if (GELU) {
      o.x = 0.5f * o.x * (1.f + erff(o.x * 0.7071067811865475f));
      o.y = 0.5f * o.y * (1.f + erff(o.y * 0.7071067811865475f));
      o.z = 0.5f * o.z * (1.f + erff(o.z * 0.7071067811865475f));
      o.w = 0.5f * o.w * (1.f + erff(o.w * 0.7071067811865475f));
    }
    *(float4*)&C[(long)(m0 + tm * 4 + mi) * N + n0 + tn * 4] = o;
  }
}

extern "C" void kernel_launch(void* const* d_in, const int* in_sizes, int n_in,
                              void* d_out, int out_size, void* d_ws, size_t ws_size,
                              hipStream_t stream) {
  const float* x    = (const float*)d_in[0];
  const float* a12  = (const float*)d_in[1];
  const float* a24  = (const float*)d_in[2];
  const float* a48  = (const float*)d_in[3];
  const float* a96  = (const float*)d_in[4];
  const float* sb   = (const float*)d_in[5];
  const float* g1iw = (const float*)d_in[6];
  const float* g1ib = (const float*)d_in[7];
  const float* g1ow = (const float*)d_in[8];
  const float* g1ob = (const float*)d_in[9];
  const float* g1lg = (const float*)d_in[10];
  const float* g1lb = (const float*)d_in[11];
  const float* g2iw = (const float*)d_in[12];
  const float* g2ib = (const float*)d_in[13];
  const float* g2ow = (const float*)d_in[14];
  const float* g2ob = (const float*)d_in[15];
  const float* g2lg = (const float*)d_in[16];
  const float* g2lb = (const float*)d_in[17];
  const float* fw1  = (const float*)d_in[18];
  const float* fb1  = (const float*)d_in[19];
  const float* fw2  = (const float*)d_in[20];
  const float* fb2  = (const float*)d_in[21];

  if (ws_size < (size_t)WS_FLOATS * sizeof(float)) return;

  float* ws   = (float*)d_ws;
  float* xT   = ws + OFF_XT;
  float* avgT = ws + OFF_AVG;
  int*   per  = (int*)(ws + OFF_PER);
  float* mp   = ws + OFF_MP;
  float* atb  = ws + OFF_AT;
  float* waf  = ws + OFF_WAF;
  float* qat  = ws + OFF_QAT;
  float* vat  = ws + OFF_VAT;
  float* ovt  = ws + OFF_OVT;
  float* cons = ws + OFF_CON;
  float* comb = ws + OFF_COMB;
  float* hbuf = ws + OFF_H;
  float* out  = (float*)d_out;

  transpose_kernel<<<192, 256, 0, stream>>>(x, xT);
  acf_kernel<<<Cn * 6, 256, 0, stream>>>(xT, avgT);
  periods_kernel<<<1, 128, 0, stream>>>(avgT, per);
  build_mpinv_kernel<<<190, 256, 0, stream>>>(per, mp);
  at_kernel<<<32, 256, 0, stream>>>(a12, a24, a48, a96, atb);
  consts_kernel<<<2, 1024, 0, stream>>>(g1iw, g1ib, g1ow, g1ob,
                                        g2iw, g2ib, g2ow, g2ob, sb, cons);
  wa_gemm2<<<144, 256, 0, stream>>>(g1iw, g2iw, atb, waf, qat, vat);
  ova_gemm2<<<192, 256, 0, stream>>>(g1ow, g2ow, vat, ovt);

  attn_kernel<<<1024, 256, 0, stream>>>(xT, per, mp, qat, waf, ovt, cons, atb, sb,
                                        g1lg, g1lb, g2lg, g2lb, comb);
  trend_kernel<<<Cn, 256, 0, stream>>>(xT, mp + 1634436L, atb + 84L * 512, sb, comb);
  fused_gemm<true><<<256, 256, 0, stream>>>(comb, fw1, fb1, hbuf, 512, 1536);
  fused_gemm<false><<<256, 256, 0, stream>>>(hbuf, fw2, fb2, out, 512, 512);
}

// Round 6
// 581.761 us; speedup vs baseline: 13.5509x; 1.1746x over previous
//
#include <hip/hip_runtime.h>
#include <math.h>

#define Bn 16
#define Tn 384
#define Cn 128

// ---------------- workspace layout (floats) ----------------
static constexpr long OFF_XT   = 0;         // 786432
static constexpr long OFF_AVG  = 786432;    // 49152
static constexpr long OFF_PER  = 835584;    // 256 ints
static constexpr long OFF_MP   = 835840;    // 1671300
static constexpr long OFF_AT   = 2507140;   // 98304: anchors^T padded to 192 rows [k*512+d]
static constexpr long OFF_WAF  = 2605444;   // 589824: per slot 1536x192 (in_w @ A_cat)
static constexpr long OFF_QAT  = 3195268;   // 196608: per slot 192x512 (Q-part transposed)
static constexpr long OFF_VAT  = 3391876;   // 196608: per slot 192x512 (V-part transposed)
static constexpr long OFF_OVT  = 3588484;   // 786432: per (slot,h) 192x512 OVA^T
static constexpr long OFF_CON  = 4374916;   // 3072
static constexpr long OFF_VB   = 4377988;   // 1024 (vb scratch per slot)
static constexpr long OFF_COMB = 4379012;   // 3145728
static constexpr long OFF_H    = 7524740;   // 1048576
static constexpr long WS_FLOATS = 8573316;  // ~34.3 MB

__host__ __device__ inline int nanch(int p) {
  if (p == 384) return 96;
  return (p <= 18) ? 12 : (p <= 36) ? 24 : (p <= 72) ? 48 : 96;
}
__host__ __device__ inline int apre(int n) {
  return (n == 12) ? 0 : (n == 24) ? 12 : (n == 48) ? 36 : 84;
}
__host__ __device__ inline long mpoff(int p) {
  if (p == 384) return 1634436L;
  long T = (long)(p - 1) * p / 2;
  if (p <= 18) return 12 * (T - 6);
  if (p <= 36) return 1980 + 24 * (T - 171);
  if (p <= 72) return 13860 + 48 * (T - 666);
  return 108036 + 96 * (T - 2628);
}

__device__ inline void irow(int j, int newl, int oldl, int& i0, int& i1, float& w) {
  double src = ((double)j + 0.5) * (double)oldl / (double)newl - 0.5;
  if (src < 0.0) src = 0.0;
  double mx = (double)(oldl - 1);
  if (src > mx) src = mx;
  int a = (int)src;
  if (a > oldl - 1) a = oldl - 1;
  i0 = a;
  i1 = (a + 1 < oldl) ? (a + 1) : (oldl - 1);
  w = (float)(src - (double)a);
}

// ---------------- stage 0: transpose x -> xT[c][b][t] ----------------
__global__ __launch_bounds__(256) void transpose_kernel(const float* __restrict__ x,
                                                        float* __restrict__ xT) {
  __shared__ float tile[32 * 129];
  int bid = blockIdx.x;
  int b = bid / 12, t0 = (bid % 12) * 32;
  int tid = threadIdx.x;
  for (int i = tid; i < 32 * 128; i += 256) {
    int tt = i >> 7, cc = i & 127;
    tile[tt * 129 + cc] = x[((long)b * Tn + t0 + tt) * Cn + cc];
  }
  __syncthreads();
  for (int i = tid; i < 32 * 128; i += 256) {
    int cc = i >> 5, tt = i & 31;
    xT[((long)cc * Bn + b) * Tn + t0 + tt] = tile[tt * 129 + cc];
  }
}

// ---------------- stage A1: ACF ----------------
__global__ __launch_bounds__(256) void acf_kernel(const float* __restrict__ xT,
                                                  float* __restrict__ avgT) {
  __shared__ float xb[Bn * 397];
  __shared__ float mean[Bn];
  int bid = blockIdx.x;
  int c = bid / 6, tile = bid % 6;
  int tid = threadIdx.x;
  for (int i = tid; i < Bn * Tn; i += 256) {
    int b = i / Tn, t = i - b * Tn;
    xb[b * 397 + t] = xT[(long)c * Bn * Tn + i];
  }
  for (int i = tid; i < Bn * 13; i += 256) {
    int b = i / 13, t = Tn + (i - b * 13);
    xb[b * 397 + t] = 0.f;
  }
  __syncthreads();
  if (tid < Bn) {
    float s = 0.f;
    for (int t = 0; t < Tn; ++t) s += xb[tid * 397 + t];
    mean[tid] = s / (float)Tn;
  }
  __syncthreads();
  for (int i = tid; i < Bn * Tn; i += 256) {
    int b = i / Tn, t = i - b * Tn;
    xb[b * 397 + t] -= mean[b];
  }
  __syncthreads();
  int q = tid >> 4;
  int g = tid & 15;
  int tau0 = tile * 64 + q * 4;
  const float* xr = xb + g * 397;
  float a0 = 0.f, a1 = 0.f, a2 = 0.f, a3 = 0.f;
  float w0 = xr[tau0], w1 = xr[tau0 + 1], w2 = xr[tau0 + 2], w3 = xr[tau0 + 3];
  int tmax = Tn - tau0;
  for (int t = 0; t < tmax; ++t) {
    float a = xr[t];
    float wn = xr[t + tau0 + 4];
    a0 += a * w0; a1 += a * w1; a2 += a * w2; a3 += a * w3;
    w0 = w1; w1 = w2; w2 = w3; w3 = wn;
  }
  for (int off = 8; off > 0; off >>= 1) {
    a0 += __shfl_down(a0, off, 16);
    a1 += __shfl_down(a1, off, 16);
    a2 += __shfl_down(a2, off, 16);
    a3 += __shfl_down(a3, off, 16);
  }
  if (g == 0) {
    avgT[(long)(tau0 + 0) * Cn + c] = a0;
    avgT[(long)(tau0 + 1) * Cn + c] = a1;
    avgT[(long)(tau0 + 2) * Cn + c] = a2;
    avgT[(long)(tau0 + 3) * Cn + c] = a3;
  }
}

// ---------------- stage A2: peaks ----------------
__global__ __launch_bounds__(128) void periods_kernel(const float* __restrict__ avgT,
                                                      int* __restrict__ per) {
  int c = threadIdx.x;
  if (c >= Cn) return;
  const float* a = avgT + c;
  const float NEG = -1e30f;
  float b1v = NEG, b2v = NEG;
  int b1i = 0, b2i = 0;
  float pv = NEG;
  float v = a[4L * Cn];
  for (int t = 4; t < Tn; ++t) {
    float nv = (t == Tn - 1) ? NEG : a[(long)(t + 1) * Cn];
    bool peak = (v > pv) && (v > nv) && (v > 0.f);
    float m = peak ? v : NEG;
    if (m > b1v)      { b2v = b1v; b2i = b1i; b1v = m; b1i = t; }
    else if (m > b2v) { b2v = m; b2i = t; }
    pv = v; v = nv;
  }
  per[c * 2 + 0] = min(max(b1i, 4), 192);
  per[c * 2 + 1] = min(max(b2i, 4), 192);
}

// ---------------- stage C: Mpinv via tridiagonal Thomas ----------------
__global__ __launch_bounds__(256) void build_mpinv_kernel(const int* __restrict__ per,
                                                          float* __restrict__ mp) {
  __shared__ int ii[384];
  __shared__ float ww[384];
  __shared__ float dd_[96], ee[96], cp[96], idt[96];
  __shared__ float ginv[96 * 97];
  __shared__ float outp[96 * 97];
  __shared__ int flag;
  int tid = threadIdx.x;
  int p = (blockIdx.x < 189) ? (4 + (int)blockIdx.x) : 384;
  if (tid == 0) flag = (p == 384) ? 1 : 0;
  __syncthreads();
  if (p != 384) {
    for (int i = tid; i < Cn * 2; i += 256)
      if (per[i] == p) flag = 1;
  }
  __syncthreads();
  if (!flag) return;

  int n = nanch(p);
  int m = (p >= n) ? n : p;
  float* dst = mp + mpoff(p);

  for (int j = tid; j < p; j += 256) {
    int i0, i1; float w;
    irow(j, p, n, i0, i1, w);
    ii[j] = i0; ww[j] = w;
  }
  for (int i = tid; i < m; i += 256) { dd_[i] = 0.f; ee[i] = 0.f; }
  __syncthreads();

  if (p >= n) {
    for (int j = tid; j < p; j += 256) {
      int i0 = ii[j]; float w = ww[j];
      int i1 = min(i0 + 1, n - 1);
      if (i1 == i0) {
        atomicAdd(&dd_[i0], 1.0f);
      } else {
        float a = 1.f - w, b = w;
        atomicAdd(&dd_[i0], a * a);
        atomicAdd(&dd_[i1], b * b);
        atomicAdd(&ee[i0], a * b);
      }
    }
  } else {
    for (int r = tid; r < p; r += 256) {
      int i0 = ii[r]; float w = ww[r];
      int i1 = min(i0 + 1, n - 1);
      float a, b; int c0 = i0, c1 = i1;
      if (i1 == i0) { a = 1.f; b = 0.f; c1 = -1; }
      else { a = 1.f - w; b = w; }
      dd_[r] = a * a + b * b;
      if (r < p - 1) {
        int j0 = ii[r + 1]; float w2 = ww[r + 1];
        int j1 = min(j0 + 1, n - 1);
        float a2, b2; int d0 = j0, d1 = j1;
        if (j1 == j0) { a2 = 1.f; b2 = 0.f; d1 = -2; }
        else { a2 = 1.f - w2; b2 = w2; }
        float s = 0.f;
        if (c0 == d0) s += a * a2;
        if (c0 == d1) s += a * b2;
        if (c1 == d0) s += b * a2;
        if (c1 == d1) s += b * b2;
        ee[r] = s;
      }
    }
  }
  __syncthreads();
  if (tid == 0) {
    float dt = dd_[0];
    idt[0] = 1.f / dt;
    for (int i = 1; i < m; ++i) {
      float c = ee[i - 1] * idt[i - 1];
      cp[i - 1] = c;
      dt = dd_[i] - ee[i - 1] * c;
      idt[i] = 1.f / dt;
    }
  }
  __syncthreads();
  if (tid < m) {
    int j = tid;
    float z = 1.f;
    ginv[j * 97 + j] = 1.f;
    for (int i = j + 1; i < m; ++i) {
      z = -cp[i - 1] * z;
      ginv[i * 97 + j] = z;
    }
    float xn = ginv[(m - 1) * 97 + j] * idt[m - 1];
    ginv[(m - 1) * 97 + j] = xn;
    for (int i = m - 2; i >= 0; --i) {
      float zi = (i >= j) ? ginv[i * 97 + j] : 0.f;
      xn = zi * idt[i] - cp[i] * xn;
      ginv[i * 97 + j] = xn;
    }
  }
  __syncthreads();
  if (p >= n) {
    for (int idx = tid; idx < p * n; idx += 256) {
      int t = idx / n, k = idx - t * n;
      int i0 = ii[t]; float w = ww[t];
      int i1 = min(i0 + 1, n - 1);
      dst[idx] = (1.f - w) * ginv[i0 * 97 + k] + w * ginv[i1 * 97 + k];
    }
  } else {
    for (int t = tid; t < p; t += 256) {
      for (int k = 0; k < n; ++k) outp[t * 97 + k] = 0.f;
      for (int j = 0; j < p; ++j) {
        float hv = ginv[t * 97 + j];
        int i0 = ii[j]; float w = ww[j];
        int i1 = min(i0 + 1, n - 1);
        outp[t * 97 + i0] += hv * (1.f - w);
        outp[t * 97 + i1] += hv * w;
      }
    }
    __syncthreads();
    for (int idx = tid; idx < p * n; idx += 256) {
      int t = idx / n, k = idx - t * n;
      dst[idx] = outp[t * 97 + k];
    }
  }
}

// ---------------- stage P1: anchors^T -> at_tab (192x512, pad zeroed) ----------------
__global__ __launch_bounds__(256) void at_kernel(const float* __restrict__ a12,
                                                 const float* __restrict__ a24,
                                                 const float* __restrict__ a48,
                                                 const float* __restrict__ a96,
                                                 float* __restrict__ at_tab) {
  __shared__ float tile[64 * 97];
  int bid = blockIdx.x;     // 4 anchors * 8 d-chunks
  int a = bid >> 3, d0 = (bid & 7) * 64;
  int n = (a == 0) ? 12 : (a == 1) ? 24 : (a == 2) ? 48 : 96;
  const float* src = (a == 0) ? a12 : (a == 1) ? a24 : (a == 2) ? a48 : a96;
  float* dst = at_tab + (long)apre(n) * 512;
  int tid = threadIdx.x;
  for (int i = tid; i < 64 * n; i += 256) {
    int dd = i / n, k = i - dd * n;
    tile[dd * 97 + k] = src[(long)(d0 + dd) * n + (long)k];
  }
  __syncthreads();
  for (int i = tid; i < n * 64; i += 256) {
    int k = i >> 6, dd = i & 63;
    dst[(long)k * 512 + d0 + dd] = tile[dd * 97 + k];
  }
  if (bid == 0) {
    for (int i = tid; i < 12 * 512; i += 256) at_tab[180L * 512 + i] = 0.f;
  }
}

// ---------------- stage P3a: qc/kb folds + vb scratch (parallel) ----------------
__global__ __launch_bounds__(256) void constsA(const float* __restrict__ i1w,
                                               const float* __restrict__ i1b,
                                               const float* __restrict__ i2w,
                                               const float* __restrict__ i2b,
                                               const float* __restrict__ sb,
                                               float* __restrict__ cons,
                                               float* __restrict__ vbuf) {
  __shared__ float sv[512];
  int bid = blockIdx.x;                 // 2 slots * 96
  int s = bid / 96, r0 = (bid % 96) * 16;
  const float* inw = s ? i2w : i1w;
  const float* inb = s ? i2b : i1b;
  int tid = threadIdx.x;
  for (int i = tid; i < 512; i += 256) sv[i] = sb[i];
  __syncthreads();
  int lane = tid & 63, w = tid >> 6;    // 4 waves, 4 rows each
  for (int rr = 0; rr < 4; ++rr) {
    int r = r0 + w * 4 + rr;
    const float* row = inw + (long)r * 512;
    float part = 0.f;
    for (int kk = 0; kk < 8; ++kk) part += row[lane + 64 * kk] * sv[lane + 64 * kk];
    for (int off = 32; off > 0; off >>= 1) part += __shfl_down(part, off, 64);
    if (lane == 0) {
      float v = part + inb[r];
      if (r < 1024) cons[s * 1536 + r] = v;
      else vbuf[s * 512 + (r - 1024)] = v;
    }
  }
}

// ---------------- stage P3b: oc = out_w @ vb + outb ----------------
__global__ __launch_bounds__(256) void constsB(const float* __restrict__ o1w,
                                               const float* __restrict__ o1b,
                                               const float* __restrict__ o2w,
                                               const float* __restrict__ o2b,
                                               const float* __restrict__ vbuf,
                                               float* __restrict__ cons) {
  __shared__ float vv[512];
  int bid = blockIdx.x;                 // 2 slots * 32
  int s = bid / 32, r0 = (bid % 32) * 16;
  const float* outw = s ? o2w : o1w;
  const float* outb = s ? o2b : o1b;
  int tid = threadIdx.x;
  for (int i = tid; i < 512; i += 256) vv[i] = vbuf[s * 512 + i];
  __syncthreads();
  int lane = tid & 63, w = tid >> 6;
  for (int rr = 0; rr < 4; ++rr) {
    int r = r0 + w * 4 + rr;
    const float* row = outw + (long)r * 512;
    float part = 0.f;
    for (int kk = 0; kk < 8; ++kk) part += row[lane + 64 * kk] * vv[lane + 64 * kk];
    for (int off = 32; off > 0; off >>= 1) part += __shfl_down(part, off, 64);
    if (lane == 0) cons[s * 1536 + 1024 + r] = part + outb[r];
  }
}

// ---------------- stage P2: WAfull = in_w @ A_cat (1536x192 per slot) ----------------
__global__ __launch_bounds__(256) void wa_gemm2(const float* __restrict__ iw0,
                                                const float* __restrict__ iw1,
                                                const float* __restrict__ atb,
                                                float* __restrict__ waf,
                                                float* __restrict__ qat,
                                                float* __restrict__ vat) {
  __shared__ float smem[2 * 32 * 68];
  float* As = smem;
  float* Ws = smem + 32 * 68;
  int bid = blockIdx.x;
  int s = bid / 72, r = bid % 72;
  int m0 = (r / 3) * 64, n0 = (r % 3) * 64;
  const float* A = s ? iw1 : iw0;
  float* wafs = waf + (long)s * 294912;
  int tid = threadIdx.x;
  int tm = tid & 15, tn = tid >> 4;
  float acc[4][4];
#pragma unroll
  for (int i = 0; i < 4; ++i)
#pragma unroll
    for (int j = 0; j < 4; ++j) acc[i][j] = 0.f;
  int row = tid >> 3, kc = (tid & 7) * 4;
  for (int k0 = 0; k0 < 512; k0 += 32) {
    float4 v = *(const float4*)&A[(long)(m0 + row) * 512 + k0 + kc];
    As[(kc + 0) * 68 + row] = v.x; As[(kc + 1) * 68 + row] = v.y;
    As[(kc + 2) * 68 + row] = v.z; As[(kc + 3) * 68 + row] = v.w;
    v = *(const float4*)&A[(long)(m0 + row + 32) * 512 + k0 + kc];
    As[(kc + 0) * 68 + row + 32] = v.x; As[(kc + 1) * 68 + row + 32] = v.y;
    As[(kc + 2) * 68 + row + 32] = v.z; As[(kc + 3) * 68 + row + 32] = v.w;
    v = *(const float4*)&atb[(long)(n0 + row) * 512 + k0 + kc];
    Ws[(kc + 0) * 68 + row] = v.x; Ws[(kc + 1) * 68 + row] = v.y;
    Ws[(kc + 2) * 68 + row] = v.z; Ws[(kc + 3) * 68 + row] = v.w;
    v = *(const float4*)&atb[(long)(n0 + row + 32) * 512 + k0 + kc];
    Ws[(kc + 0) * 68 + row + 32] = v.x; Ws[(kc + 1) * 68 + row + 32] = v.y;
    Ws[(kc + 2) * 68 + row + 32] = v.z; Ws[(kc + 3) * 68 + row + 32] = v.w;
    __syncthreads();
    for (int kk = 0; kk < 32; ++kk) {
      float4 a = *(const float4*)&As[kk * 68 + tm * 4];
      float4 w = *(const float4*)&Ws[kk * 68 + tn * 4];
      acc[0][0] += a.x * w.x; acc[0][1] += a.x * w.y; acc[0][2] += a.x * w.z; acc[0][3] += a.x * w.w;
      acc[1][0] += a.y * w.x; acc[1][1] += a.y * w.y; acc[1][2] += a.y * w.z; acc[1][3] += a.y * w.w;
      acc[2][0] += a.z * w.x; acc[2][1] += a.z * w.y; acc[2][2] += a.z * w.z; acc[2][3] += a.z * w.w;
      acc[3][0] += a.w * w.x; acc[3][1] += a.w * w.y; acc[3][2] += a.w * w.z; acc[3][3] += a.w * w.w;
    }
    __syncthreads();
  }
#pragma unroll
  for (int mi = 0; mi < 4; ++mi) {
    float4 o;
    o.x = acc[mi][0]; o.y = acc[mi][1]; o.z = acc[mi][2]; o.w = acc[mi][3];
    *(float4*)&wafs[(long)(m0 + tm * 4 + mi) * 192 + n0 + tn * 4] = o;
  }
  if (m0 < 512 || m0 >= 1024) {
    float* Ct = smem;
#pragma unroll
    for (int mi = 0; mi < 4; ++mi)
#pragma unroll
      for (int j = 0; j < 4; ++j)
        Ct[(tn * 4 + j) * 65 + tm * 4 + mi] = acc[mi][j];
    __syncthreads();
    float* dst = ((m0 < 512) ? qat : vat) + (long)s * 98304;
    int mr = m0 & 511;
    for (int i = tid; i < 64 * 64; i += 256) {
      int cc = i >> 6, rr = i & 63;
      dst[(long)(n0 + cc) * 512 + mr + rr] = Ct[cc * 65 + rr];
    }
  }
}

// ---------------- stage P4: OVA^T per (slot,head) ----------------
__global__ __launch_bounds__(256) void ova_gemm2(const float* __restrict__ ow0,
                                                 const float* __restrict__ ow1,
                                                 const float* __restrict__ vat,
                                                 float* __restrict__ ovt) {
  __shared__ float As[32 * 68];
  __shared__ float Ws[32 * 68];
  int bid = blockIdx.x;
  int s = bid / 96, r = bid % 96;
  int h = r / 24, r2 = r % 24;
  int m0 = (r2 / 8) * 64, n0 = (r2 % 8) * 64;
  const float* A = vat + (long)s * 98304 + h * 128;
  const float* W = (s ? ow1 : ow0) + h * 128;
  float* C = ovt + ((long)(s * 4 + h) * 192) * 512;
  int tid = threadIdx.x;
  int tm = tid & 15, tn = tid >> 4;
  float acc[4][4];
#pragma unroll
  for (int i = 0; i < 4; ++i)
#pragma unroll
    for (int j = 0; j < 4; ++j) acc[i][j] = 0.f;
  int row = tid >> 3, kc = (tid & 7) * 4;
  for (int k0 = 0; k0 < 128; k0 += 32) {
    float4 v = *(const float4*)&A[(long)(m0 + row) * 512 + k0 + kc];
    As[(kc + 0) * 68 + row] = v.x; As[(kc + 1) * 68 + row] = v.y;
    As[(kc + 2) * 68 + row] = v.z; As[(kc + 3) * 68 + row] = v.w;
    v = *(const float4*)&A[(long)(m0 + row + 32) * 512 + k0 + kc];
    As[(kc + 0) * 68 + row + 32] = v.x; As[(kc + 1) * 68 + row + 32] = v.y;
    As[(kc + 2) * 68 + row + 32] = v.z; As[(kc + 3) * 68 + row + 32] = v.w;
    v = *(const float4*)&W[(long)(n0 + row) * 512 + k0 + kc];
    Ws[(kc + 0) * 68 + row] = v.x; Ws[(kc + 1) * 68 + row] = v.y;
    Ws[(kc + 2) * 68 + row] = v.z; Ws[(kc + 3) * 68 + row] = v.w;
    v = *(const float4*)&W[(long)(n0 + row + 32) * 512 + k0 + kc];
    Ws[(kc + 0) * 68 + row + 32] = v.x; Ws[(kc + 1) * 68 + row + 32] = v.y;
    Ws[(kc + 2) * 68 + row + 32] = v.z; Ws[(kc + 3) * 68 + row + 32] = v.w;
    __syncthreads();
    for (int kk = 0; kk < 32; ++kk) {
      float4 a = *(const float4*)&As[kk * 68 + tm * 4];
      float4 w = *(const float4*)&Ws[kk * 68 + tn * 4];
      acc[0][0] += a.x * w.x; acc[0][1] += a.x * w.y; acc[0][2] += a.x * w.z; acc[0][3] += a.x * w.w;
      acc[1][0] += a.y * w.x; acc[1][1] += a.y * w.y; acc[1][2] += a.y * w.z; acc[1][3] += a.y * w.w;
      acc[2][0] += a.z * w.x; acc[2][1] += a.z * w.y; acc[2][2] += a.z * w.z; acc[2][3] += a.z * w.w;
      acc[3][0] += a.w * w.x; acc[3][1] += a.w * w.y; acc[3][2] += a.w * w.z; acc[3][3] += a.w * w.w;
    }
    __syncthreads();
  }
#pragma unroll
  for (int mi = 0; mi < 4; ++mi) {
    float4 o;
    o.x = acc[mi][0]; o.y = acc[mi][1]; o.z = acc[mi][2]; o.w = acc[mi][3];
    *(float4*)&C[(long)(m0 + tm * 4 + mi) * 512 + n0 + tn * 4] = o;
  }
}

// ---------------- stage B: fused anchor-folded attention ----------------
__global__ __launch_bounds__(256) void attn_kernel(
    const float* __restrict__ xT, const int* __restrict__ per,
    const float* __restrict__ mp, const float* __restrict__ qat_tab,
    const float* __restrict__ wafull, const float* __restrict__ ovt,
    const float* __restrict__ cons, const float* __restrict__ at_tab,
    const float* __restrict__ sb,
    const float* __restrict__ l1g, const float* __restrict__ l1b,
    const float* __restrict__ l2g, const float* __restrict__ l2b,
    float* __restrict__ comb) {
  __shared__ float xb[4 * 384];
  __shared__ float Z[4 * 1250];
  __shared__ float qy[4 * 512];
  __shared__ float arb[4 * 388];
  __shared__ float sc[4 * 388];
  __shared__ float qkc[16];
  __shared__ float red[8];

  int tid = threadIdx.x;
  int bid = blockIdx.x;
  int slot = bid & 1;
  int c = (bid >> 1) & 127;
  int b0 = (bid >> 8) * 4;
  int p = per[c * 2 + slot];
  int n = nanch(p);
  int np = Tn / p;
  int n1 = n + 1;
  float s = sqrtf((float)p / (float)n);
  const float rscale = 0.08838834764831845f;
  int pre = apre(n);
  const float* mpp = mp + mpoff(p);
  const float* qat = qat_tab + (long)slot * 98304 + (long)pre * 512;
  const float* katb = wafull + (long)slot * 294912 + 98304 + pre;
  const float* ovs = ovt + (long)slot * 4 * 98304;
  const float* atb = at_tab + (long)pre * 512;
  const float* qc = cons + slot * 1536;
  const float* kb = qc + 512;
  const float* oc = qc + 1024;
  const float* lng = slot ? l2g : l1g;
  const float* lnb = slot ? l2b : l1b;

  for (int g = 0; g < 4; ++g)
    for (int t = tid; t < Tn; t += 256)
      xb[g * 384 + t] = xT[((long)c * Bn + b0 + g) * Tn + t];
  __syncthreads();

  // Ph1: Z = patches @ Mpinv (g-fused)
  int znp = np * n;
  for (int idx = tid; idx < znp; idx += 256) {
    int j = idx / n, k = idx - j * n;
    int jb = j * p;
    const float* mk = mpp + k;
    const float* x0 = xb + jb;
    const float* x1 = xb + 384 + jb;
    const float* x2 = xb + 768 + jb;
    const float* x3 = xb + 1152 + jb;
    float a0 = 0.f, a1 = 0.f, a2 = 0.f, a3 = 0.f;
    for (int t = 0; t < p; ++t) {
      float m = mk[(long)t * n];
      a0 += m * x0[t]; a1 += m * x1[t]; a2 += m * x2[t]; a3 += m * x3[t];
    }
    int zi = j * n1 + k;
    Z[zi] = a0;
    Z[1250 + zi] = a1;
    Z[2500 + zi] = a2;
    Z[3750 + zi] = a3;
  }
  __syncthreads();

  int zlb0 = 0 * 1250 + (np - 1) * n1;
  int zlb1 = 1 * 1250 + (np - 1) * n1;
  int zlb2 = 2 * 1250 + (np - 1) * n1;
  int zlb3 = 3 * 1250 + (np - 1) * n1;
  int d0 = 2 * tid, d1 = 2 * tid + 1;

  // Ph2: q (float2 column pairs)
  {
    float a0[4] = {0.f, 0.f, 0.f, 0.f}, a1[4] = {0.f, 0.f, 0.f, 0.f};
    for (int k = 0; k < n; ++k) {
      float2 w = *(const float2*)&qat[(long)k * 512 + d0];
      float z0 = Z[zlb0 + k], z1 = Z[zlb1 + k], z2 = Z[zlb2 + k], z3 = Z[zlb3 + k];
      a0[0] += w.x * z0; a0[1] += w.x * z1; a0[2] += w.x * z2; a0[3] += w.x * z3;
      a1[0] += w.y * z0; a1[1] += w.y * z1; a1[2] += w.y * z2; a1[3] += w.y * z3;
    }
    float2 qcv = *(const float2*)&qc[d0];
#pragma unroll
    for (int g = 0; g < 4; ++g) {
      float2 o; o.x = qcv.x + s * a0[g]; o.y = qcv.y + s * a1[g];
      *(float2*)&qy[g * 512 + d0] = o;
    }
  }
  __syncthreads();

  // Ph2b: qkc, 16-lane groups
  {
    int pair = tid >> 4, l = tid & 15;
    int g = pair >> 2, h = pair & 3;
    float acc = 0.f;
    for (int i = l; i < 128; i += 16) acc += qy[g * 512 + h * 128 + i] * kb[h * 128 + i];
    for (int off = 8; off > 0; off >>= 1) acc += __shfl_down(acc, off, 16);
    if (l == 0) qkc[pair] = acc;
  }

  // Ph3: ar
  {
    int tot = 16 * n;
    for (int idx = tid; idx < tot; idx += 256) {
      int g = idx / (4 * n);
      int r = idx - g * 4 * n;
      int h = r / n, k = r - h * n;
      float acc = 0.f;
      const float* kp = katb + (long)(h * 128) * 192 + k;
      const float* qp = qy + g * 512 + h * 128;
      for (int i = 0; i < 128; ++i) acc += kp[(long)i * 192] * qp[i];
      arb[g * 388 + h * n + k] = s * acc;
    }
  }
  __syncthreads();

  // Ph4: scores
  {
    int tot = 16 * np;
    for (int idx = tid; idx < tot; idx += 256) {
      int g = idx / (4 * np);
      int r = idx - g * 4 * np;
      int h = r / np, j = r - h * np;
      const float* ap = arb + g * 388 + h * n;
      const float* zp = Z + g * 1250 + j * n1;
      float acc = 0.f;
      for (int k = 0; k < n; ++k) acc += ap[k] * zp[k];
      sc[g * 388 + h * np + j] = (acc + qkc[g * 4 + h]) * rscale;
    }
  }
  __syncthreads();

  // Ph5: softmax, 16-lane groups
  {
    int pair = tid >> 4, l = tid & 15;
    int g = pair >> 2, h = pair & 3;
    float* sp = sc + g * 388 + h * np;
    float m = -1e30f;
    for (int j = l; j < np; j += 16) m = fmaxf(m, sp[j]);
    for (int off = 8; off > 0; off >>= 1) m = fmaxf(m, __shfl_xor(m, off, 16));
    float lsum = 0.f;
    for (int j = l; j < np; j += 16) { float e = expf(sp[j] - m); sp[j] = e; lsum += e; }
    for (int off = 8; off > 0; off >>= 1) lsum += __shfl_xor(lsum, off, 16);
    float il = 1.f / lsum;
    for (int j = l; j < np; j += 16) sp[j] *= il;
  }
  __syncthreads();

  // Ph6: zh
  {
    int tot = 16 * n;
    for (int idx = tid; idx < tot; idx += 256) {
      int g = idx / (4 * n);
      int r = idx - g * 4 * n;
      int h = r / n, k = r - h * n;
      const float* sp = sc + g * 388 + h * np;
      const float* zp = Z + g * 1250 + k;
      float acc = 0.f;
      for (int j = 0; j < np; ++j) acc += sp[j] * zp[j * n1];
      arb[g * 388 + h * n + k] = acc;
    }
  }
  __syncthreads();

  // Ph7: y (float2 column pairs)
  {
    float a0[4] = {0.f, 0.f, 0.f, 0.f}, a1[4] = {0.f, 0.f, 0.f, 0.f};
    for (int k = 0; k < n; ++k) {
      float2 w = *(const float2*)&atb[(long)k * 512 + d0];
      float z0 = Z[zlb0 + k], z1 = Z[zlb1 + k], z2 = Z[zlb2 + k], z3 = Z[zlb3 + k];
      a0[0] += w.x * z0; a0[1] += w.x * z1; a0[2] += w.x * z2; a0[3] += w.x * z3;
      a1[0] += w.y * z0; a1[1] += w.y * z1; a1[2] += w.y * z2; a1[3] += w.y * z3;
    }
    for (int h = 0; h < 4; ++h) {
      const float* op = ovs + ((long)h * 192 + pre) * 512;
      const float* zh0 = arb + 0 * 388 + h * n;
      const float* zh1 = arb + 1 * 388 + h * n;
      const float* zh2 = arb + 2 * 388 + h * n;
      const float* zh3 = arb + 3 * 388 + h * n;
      for (int k = 0; k < n; ++k) {
        float2 w = *(const float2*)&op[(long)k * 512 + d0];
        float z0 = zh0[k], z1 = zh1[k], z2 = zh2[k], z3 = zh3[k];
        a0[0] += w.x * z0; a0[1] += w.x * z1; a0[2] += w.x * z2; a0[3] += w.x * z3;
        a1[0] += w.y * z0; a1[1] += w.y * z1; a1[2] += w.y * z2; a1[3] += w.y * z3;
      }
    }
    float2 sbv = *(const float2*)&sb[d0];
    float2 ocv = *(const float2*)&oc[d0];
    float s0 = sbv.x + ocv.x;
    float s1 = sbv.y + ocv.y;
    __syncthreads();
#pragma unroll
    for (int g = 0; g < 4; ++g) {
      float2 o; o.x = s * a0[g] + s0; o.y = s * a1[g] + s1;
      *(float2*)&qy[g * 512 + d0] = o;
    }
  }
  __syncthreads();

  // Ph8: layernorm
  {
    int w = tid >> 6, lane = tid & 63;
    int g = w;
    float sm = 0.f, sq = 0.f;
    for (int kk = 0; kk < 8; ++kk) {
      float v = qy[g * 512 + lane + 64 * kk];
      sm += v; sq += v * v;
    }
    for (int off = 32; off > 0; off >>= 1) {
      sm += __shfl_down(sm, off, 64);
      sq += __shfl_down(sq, off, 64);
    }
    if (lane == 0) { red[g * 2] = sm; red[g * 2 + 1] = sq; }
    __syncthreads();
    float mu = red[g * 2] / 512.f;
    float var = red[g * 2 + 1] / 512.f - mu * mu;
    float rstd = rsqrtf(var + 1e-5f);
    long base = ((long)(b0 + g) * Cn + c) * 1536 + slot * 512;
    for (int kk = 0; kk < 8; ++kk) {
      int i = lane + 64 * kk;
      comb[base + i] = (qy[g * 512 + i] - mu) * rstd * lng[i] + lnb[i];
    }
  }
}

// ---------------- stage D: trend ----------------
__global__ __launch_bounds__(256) void trend_kernel(const float* __restrict__ xT,
                                                    const float* __restrict__ mp384,
                                                    const float* __restrict__ at96,
                                                    const float* __restrict__ sb,
                                                    float* __restrict__ comb) {
  __shared__ float xb[Bn * Tn];
  __shared__ float Ztr[Bn * 97];
  int c = blockIdx.x, tid = threadIdx.x;
  for (int i = tid; i < Bn * Tn; i += 256) xb[i] = xT[(long)c * Bn * Tn + i];
  __syncthreads();
  for (int idx = tid; idx < 4 * 96; idx += 256) {
    int bq = idx / 96, k = idx - bq * 96;
    const float* x0 = xb + (bq * 4 + 0) * Tn;
    const float* x1 = xb + (bq * 4 + 1) * Tn;
    const float* x2 = xb + (bq * 4 + 2) * Tn;
    const float* x3 = xb + (bq * 4 + 3) * Tn;
    const float* mk = mp384 + k;
    float a0 = 0.f, a1 = 0.f, a2 = 0.f, a3 = 0.f;
    for (int t = 0; t < Tn; ++t) {
      float m = mk[(long)t * 96];
      a0 += m * x0[t]; a1 += m * x1[t]; a2 += m * x2[t]; a3 += m * x3[t];
    }
    Ztr[(bq * 4 + 0) * 97 + k] = a0;
    Ztr[(bq * 4 + 1) * 97 + k] = a1;
    Ztr[(bq * 4 + 2) * 97 + k] = a2;
    Ztr[(bq * 4 + 3) * 97 + k] = a3;
  }
  __syncthreads();
  float acc0[Bn], acc1[Bn];
#pragma unroll
  for (int b = 0; b < Bn; ++b) { acc0[b] = 0.f; acc1[b] = 0.f; }
  for (int k = 0; k < 96; ++k) {
    float w0 = at96[(long)k * 512 + tid];
    float w1 = at96[(long)k * 512 + 256 + tid];
#pragma unroll
    for (int b = 0; b < Bn; ++b) {
      float z = Ztr[b * 97 + k];
      acc0[b] += w0 * z;
      acc1[b] += w1 * z;
    }
  }
  float s0 = sb[tid], s1 = sb[256 + tid];
#pragma unroll
  for (int b = 0; b < Bn; ++b) {
    long base = ((long)b * Cn + c) * 1536 + 1024;
    comb[base + tid] = 2.f * acc0[b] + s0;
    comb[base + 256 + tid] = 2.f * acc1[b] + s1;
  }
}

// ---------------- stage E: fusion GEMM ----------------
template <bool GELU>
__global__ __launch_bounds__(256) void fused_gemm(const float* __restrict__ A,
                                                  const float* __restrict__ W,
                                                  const float* __restrict__ bias,
                                                  float* __restrict__ C,
                                                  int N, int K) {
  __shared__ float As[32 * 68];
  __shared__ float Ws[32 * 68];
  int nb = N >> 6;
  int m0 = (blockIdx.x / nb) * 64, n0 = (blockIdx.x % nb) * 64;
  int tid = threadIdx.x;
  int tm = tid & 15, tn = tid >> 4;
  float acc[4][4];
#pragma unroll
  for (int i = 0; i < 4; ++i)
#pragma unroll
    for (int j = 0; j < 4; ++j) acc[i][j] = 0.f;
  int row = tid >> 3, kc = (tid & 7) * 4;
  for (int k0 = 0; k0 < K; k0 += 32) {
    {
      float4 v = *(const float4*)&A[(long)(m0 + row) * K + k0 + kc];
      As[(kc + 0) * 68 + row] = v.x; As[(kc + 1) * 68 + row] = v.y;
      As[(kc + 2) * 68 + row] = v.z; As[(kc + 3) * 68 + row] = v.w;
      v = *(const float4*)&A[(long)(m0 + row + 32) * K + k0 + kc];
      As[(kc + 0) * 68 + row + 32] = v.x; As[(kc + 1) * 68 + row + 32] = v.y;
      As[(kc + 2) * 68 + row + 32] = v.z; As[(kc + 3) * 68 + row + 32] = v.w;
      v = *(const float4*)&W[(long)(n0 + row) * K + k0 + kc];
      Ws[(kc + 0) * 68 + row] = v.x; Ws[(kc + 1) * 68 + row] = v.y;
      Ws[(kc + 2) * 68 + row] = v.z; Ws[(kc + 3) * 68 + row] = v.w;
      v = *(const float4*)&W[(long)(n0 + row + 32) * K + k0 + kc];
      Ws[(kc + 0) * 68 + row + 32] = v.x; Ws[(kc + 1) * 68 + row + 32] = v.y;
      Ws[(kc + 2) * 68 + row + 32] = v.z; Ws[(kc + 3) * 68 + row + 32] = v.w;
    }
    __syncthreads();
    for (int kk = 0; kk < 32; ++kk) {
      float4 a = *(const float4*)&As[kk * 68 + tm * 4];
      float4 w = *(const float4*)&Ws[kk * 68 + tn * 4];
      acc[0][0] += a.x * w.x; acc[0][1] += a.x * w.y; acc[0][2] += a.x * w.z; acc[0][3] += a.x * w.w;
      acc[1][0] += a.y * w.x; acc[1][1] += a.y * w.y; acc[1][2] += a.y * w.z; acc[1][3] += a.y * w.w;
      acc[2][0] += a.z * w.x; acc[2][1] += a.z * w.y; acc[2][2] += a.z * w.z; acc[2][3] += a.z * w.w;
      acc[3][0] += a.w * w.x; acc[3][1] += a.w * w.y; acc[3][2] += a.w * w.z; acc[3][3] += a.w * w.w;
    }
    __syncthreads();
  }
  float b0v = bias[n0 + tn * 4 + 0], b1v = bias[n0 + tn * 4 + 1];
  float b2v = bias[n0 + tn * 4 + 2], b3v = bias[n0 + tn * 4 + 3];
#pragma unroll
  for (int mi = 0; mi < 4; ++mi) {
    float4 o;
    o.x = acc[mi][0] + b0v; o.y = acc[mi][1] + b1v;
    o.z = acc[mi][2] + b2v; o.w = acc[mi][3] + b3v;
    if (GELU) {
      o.x = 0.5f * o.x * (1.f + erff(o.x * 0.7071067811865475f));
      o.y = 0.5f * o.y * (1.f + erff(o.y * 0.7071067811865475f));
      o.z = 0.5f * o.z * (1.f + erff(o.z * 0.7071067811865475f));
      o.w = 0.5f * o.w * (1.f + erff(o.w * 0.7071067811865475f));
    }
    *(float4*)&C[(long)(m0 + tm * 4 + mi) * N + n0 + tn * 4] = o;
  }
}

extern "C" void kernel_launch(void* const* d_in, const int* in_sizes, int n_in,
                              void* d_out, int out_size, void* d_ws, size_t ws_size,
                              hipStream_t stream) {
  const float* x    = (const float*)d_in[0];
  const float* a12  = (const float*)d_in[1];
  const float* a24  = (const float*)d_in[2];
  const float* a48  = (const float*)d_in[3];
  const float* a96  = (const float*)d_in[4];
  const float* sb   = (const float*)d_in[5];
  const float* g1iw = (const float*)d_in[6];
  const float* g1ib = (const float*)d_in[7];
  const float* g1ow = (const float*)d_in[8];
  const float* g1ob = (const float*)d_in[9];
  const float* g1lg = (const float*)d_in[10];
  const float* g1lb = (const float*)d_in[11];
  const float* g2iw = (const float*)d_in[12];
  const float* g2ib = (const float*)d_in[13];
  const float* g2ow = (const float*)d_in[14];
  const float* g2ob = (const float*)d_in[15];
  const float* g2lg = (const float*)d_in[16];
  const float* g2lb = (const float*)d_in[17];
  const float* fw1  = (const float*)d_in[18];
  const float* fb1  = (const float*)d_in[19];
  const float* fw2  = (const float*)d_in[20];
  const float* fb2  = (const float*)d_in[21];

  if (ws_size < (size_t)WS_FLOATS * sizeof(float)) return;

  float* ws   = (float*)d_ws;
  float* xT   = ws + OFF_XT;
  float* avgT = ws + OFF_AVG;
  int*   per  = (int*)(ws + OFF_PER);
  float* mp   = ws + OFF_MP;
  float* atb  = ws + OFF_AT;
  float* waf  = ws + OFF_WAF;
  float* qat  = ws + OFF_QAT;
  float* vat  = ws + OFF_VAT;
  float* ovt  = ws + OFF_OVT;
  float* cons = ws + OFF_CON;
  float* vbuf = ws + OFF_VB;
  float* comb = ws + OFF_COMB;
  float* hbuf = ws + OFF_H;
  float* out  = (float*)d_out;

  transpose_kernel<<<192, 256, 0, stream>>>(x, xT);
  acf_kernel<<<Cn * 6, 256, 0, stream>>>(xT, avgT);
  periods_kernel<<<1, 128, 0, stream>>>(avgT, per);
  build_mpinv_kernel<<<190, 256, 0, stream>>>(per, mp);
  at_kernel<<<32, 256, 0, stream>>>(a12, a24, a48, a96, atb);
  constsA<<<192, 256, 0, stream>>>(g1iw, g1ib, g2iw, g2ib, sb, cons, vbuf);
  constsB<<<64, 256, 0, stream>>>(g1ow, g1ob, g2ow, g2ob, vbuf, cons);
  wa_gemm2<<<144, 256, 0, stream>>>(g1iw, g2iw, atb, waf, qat, vat);
  ova_gemm2<<<192, 256, 0, stream>>>(g1ow, g2ow, vat, ovt);

  attn_kernel<<<1024, 256, 0, stream>>>(xT, per, mp, qat, waf, ovt, cons, atb, sb,
                                        g1lg, g1lb, g2lg, g2lb, comb);
  trend_kernel<<<Cn, 256, 0, stream>>>(xT, mp + 1634436L, atb + 84L * 512, sb, comb);
  fused_gemm<true><<<256, 256, 0, stream>>>(comb, fw1, fb1, hbuf, 512, 1536);
  fused_gemm<false><<<256, 256, 0, stream>>>(hbuf, fw2, fb2, out, 512, 512);
}

// Round 7
// 548.586 us; speedup vs baseline: 14.3704x; 1.0605x over previous
//
#include <hip/hip_runtime.h>
#include <math.h>

#define Bn 16
#define Tn 384
#define Cn 128

// ---------------- workspace layout (floats) ----------------
static constexpr long OFF_XT   = 0;         // 786432
static constexpr long OFF_AVG  = 786432;    // 49152
static constexpr long OFF_PER  = 835584;    // 256 ints
static constexpr long OFF_MP   = 835840;    // 1671300
static constexpr long OFF_AT   = 2507140;   // 98304: anchors^T padded to 192 rows [k*512+d]
static constexpr long OFF_WAF  = 2605444;   // 589824: per slot 1536x192 (in_w @ A_cat)
static constexpr long OFF_QAT  = 3195268;   // 196608: per slot 192x512 (Q-part transposed)
static constexpr long OFF_VAT  = 3391876;   // 196608: per slot 192x512 (V-part transposed)
static constexpr long OFF_OVT  = 3588484;   // 786432: per (slot,h) 192x512 OVA^T
static constexpr long OFF_CON  = 4374916;   // 3072
static constexpr long OFF_VB   = 4377988;   // 1024
static constexpr long OFF_MT   = 4379012;   // 294912: per (slot,h) 192x192 MT[j][k]=KAh^T QAh [k][j]
static constexpr long OFF_DEF  = 4673924;   // 1536 d + 1536 e + 8 f
static constexpr long OFF_COMB = 4677004;   // 3145728
static constexpr long OFF_H    = 7822732;   // 1048576
static constexpr long WS_FLOATS = 8871308;  // ~35.5 MB

__host__ __device__ inline int nanch(int p) {
  if (p == 384) return 96;
  return (p <= 18) ? 12 : (p <= 36) ? 24 : (p <= 72) ? 48 : 96;
}
__host__ __device__ inline int apre(int n) {
  return (n == 12) ? 0 : (n == 24) ? 12 : (n == 48) ? 36 : 84;
}
__host__ __device__ inline long mpoff(int p) {
  if (p == 384) return 1634436L;
  long T = (long)(p - 1) * p / 2;
  if (p <= 18) return 12 * (T - 6);
  if (p <= 36) return 1980 + 24 * (T - 171);
  if (p <= 72) return 13860 + 48 * (T - 666);
  return 108036 + 96 * (T - 2628);
}

__device__ inline void irow(int j, int newl, int oldl, int& i0, int& i1, float& w) {
  double src = ((double)j + 0.5) * (double)oldl / (double)newl - 0.5;
  if (src < 0.0) src = 0.0;
  double mx = (double)(oldl - 1);
  if (src > mx) src = mx;
  int a = (int)src;
  if (a > oldl - 1) a = oldl - 1;
  i0 = a;
  i1 = (a + 1 < oldl) ? (a + 1) : (oldl - 1);
  w = (float)(src - (double)a);
}

// ---------------- stage 0: transpose x -> xT[c][b][t] ----------------
__global__ __launch_bounds__(256) void transpose_kernel(const float* __restrict__ x,
                                                        float* __restrict__ xT) {
  __shared__ float tile[32 * 129];
  int bid = blockIdx.x;
  int b = bid / 12, t0 = (bid % 12) * 32;
  int tid = threadIdx.x;
  for (int i = tid; i < 32 * 128; i += 256) {
    int tt = i >> 7, cc = i & 127;
    tile[tt * 129 + cc] = x[((long)b * Tn + t0 + tt) * Cn + cc];
  }
  __syncthreads();
  for (int i = tid; i < 32 * 128; i += 256) {
    int cc = i >> 5, tt = i & 31;
    xT[((long)cc * Bn + b) * Tn + t0 + tt] = tile[tt * 129 + cc];
  }
}

// ---------------- stage A1: ACF ----------------
__global__ __launch_bounds__(256) void acf_kernel(const float* __restrict__ xT,
                                                  float* __restrict__ avgT) {
  __shared__ float xb[Bn * 397];
  __shared__ float mean[Bn];
  int bid = blockIdx.x;
  int c = bid / 6, tile = bid % 6;
  int tid = threadIdx.x;
  for (int i = tid; i < Bn * Tn; i += 256) {
    int b = i / Tn, t = i - b * Tn;
    xb[b * 397 + t] = xT[(long)c * Bn * Tn + i];
  }
  for (int i = tid; i < Bn * 13; i += 256) {
    int b = i / 13, t = Tn + (i - b * 13);
    xb[b * 397 + t] = 0.f;
  }
  __syncthreads();
  if (tid < Bn) {
    float s = 0.f;
    for (int t = 0; t < Tn; ++t) s += xb[tid * 397 + t];
    mean[tid] = s / (float)Tn;
  }
  __syncthreads();
  for (int i = tid; i < Bn * Tn; i += 256) {
    int b = i / Tn, t = i - b * Tn;
    xb[b * 397 + t] -= mean[b];
  }
  __syncthreads();
  int q = tid >> 4;
  int g = tid & 15;
  int tau0 = tile * 64 + q * 4;
  const float* xr = xb + g * 397;
  float a0 = 0.f, a1 = 0.f, a2 = 0.f, a3 = 0.f;
  float w0 = xr[tau0], w1 = xr[tau0 + 1], w2 = xr[tau0 + 2], w3 = xr[tau0 + 3];
  int tmax = Tn - tau0;
  for (int t = 0; t < tmax; ++t) {
    float a = xr[t];
    float wn = xr[t + tau0 + 4];
    a0 += a * w0; a1 += a * w1; a2 += a * w2; a3 += a * w3;
    w0 = w1; w1 = w2; w2 = w3; w3 = wn;
  }
  for (int off = 8; off > 0; off >>= 1) {
    a0 += __shfl_down(a0, off, 16);
    a1 += __shfl_down(a1, off, 16);
    a2 += __shfl_down(a2, off, 16);
    a3 += __shfl_down(a3, off, 16);
  }
  if (g == 0) {
    avgT[(long)(tau0 + 0) * Cn + c] = a0;
    avgT[(long)(tau0 + 1) * Cn + c] = a1;
    avgT[(long)(tau0 + 2) * Cn + c] = a2;
    avgT[(long)(tau0 + 3) * Cn + c] = a3;
  }
}

// ---------------- stage A2: peaks ----------------
__global__ __launch_bounds__(128) void periods_kernel(const float* __restrict__ avgT,
                                                      int* __restrict__ per) {
  int c = threadIdx.x;
  if (c >= Cn) return;
  const float* a = avgT + c;
  const float NEG = -1e30f;
  float b1v = NEG, b2v = NEG;
  int b1i = 0, b2i = 0;
  float pv = NEG;
  float v = a[4L * Cn];
  for (int t = 4; t < Tn; ++t) {
    float nv = (t == Tn - 1) ? NEG : a[(long)(t + 1) * Cn];
    bool peak = (v > pv) && (v > nv) && (v > 0.f);
    float m = peak ? v : NEG;
    if (m > b1v)      { b2v = b1v; b2i = b1i; b1v = m; b1i = t; }
    else if (m > b2v) { b2v = m; b2i = t; }
    pv = v; v = nv;
  }
  per[c * 2 + 0] = min(max(b1i, 4), 192);
  per[c * 2 + 1] = min(max(b2i, 4), 192);
}

// ---------------- stage C: Mpinv via tridiagonal Thomas ----------------
__global__ __launch_bounds__(256) void build_mpinv_kernel(const int* __restrict__ per,
                                                          float* __restrict__ mp) {
  __shared__ int ii[384];
  __shared__ float ww[384];
  __shared__ float dd_[96], ee[96], cp[96], idt[96];
  __shared__ float ginv[96 * 97];
  __shared__ float outp[96 * 97];
  __shared__ int flag;
  int tid = threadIdx.x;
  int p = (blockIdx.x < 189) ? (4 + (int)blockIdx.x) : 384;
  if (tid == 0) flag = (p == 384) ? 1 : 0;
  __syncthreads();
  if (p != 384) {
    for (int i = tid; i < Cn * 2; i += 256)
      if (per[i] == p) flag = 1;
  }
  __syncthreads();
  if (!flag) return;

  int n = nanch(p);
  int m = (p >= n) ? n : p;
  float* dst = mp + mpoff(p);

  for (int j = tid; j < p; j += 256) {
    int i0, i1; float w;
    irow(j, p, n, i0, i1, w);
    ii[j] = i0; ww[j] = w;
  }
  for (int i = tid; i < m; i += 256) { dd_[i] = 0.f; ee[i] = 0.f; }
  __syncthreads();

  if (p >= n) {
    for (int j = tid; j < p; j += 256) {
      int i0 = ii[j]; float w = ww[j];
      int i1 = min(i0 + 1, n - 1);
      if (i1 == i0) {
        atomicAdd(&dd_[i0], 1.0f);
      } else {
        float a = 1.f - w, b = w;
        atomicAdd(&dd_[i0], a * a);
        atomicAdd(&dd_[i1], b * b);
        atomicAdd(&ee[i0], a * b);
      }
    }
  } else {
    for (int r = tid; r < p; r += 256) {
      int i0 = ii[r]; float w = ww[r];
      int i1 = min(i0 + 1, n - 1);
      float a, b; int c0 = i0, c1 = i1;
      if (i1 == i0) { a = 1.f; b = 0.f; c1 = -1; }
      else { a = 1.f - w; b = w; }
      dd_[r] = a * a + b * b;
      if (r < p - 1) {
        int j0 = ii[r + 1]; float w2 = ww[r + 1];
        int j1 = min(j0 + 1, n - 1);
        float a2, b2; int d0 = j0, d1 = j1;
        if (j1 == j0) { a2 = 1.f; b2 = 0.f; d1 = -2; }
        else { a2 = 1.f - w2; b2 = w2; }
        float s = 0.f;
        if (c0 == d0) s += a * a2;
        if (c0 == d1) s += a * b2;
        if (c1 == d0) s += b * a2;
        if (c1 == d1) s += b * b2;
        ee[r] = s;
      }
    }
  }
  __syncthreads();
  if (tid == 0) {
    float dt = dd_[0];
    idt[0] = 1.f / dt;
    for (int i = 1; i < m; ++i) {
      float c = ee[i - 1] * idt[i - 1];
      cp[i - 1] = c;
      dt = dd_[i] - ee[i - 1] * c;
      idt[i] = 1.f / dt;
    }
  }
  __syncthreads();
  if (tid < m) {
    int j = tid;
    float z = 1.f;
    ginv[j * 97 + j] = 1.f;
    for (int i = j + 1; i < m; ++i) {
      z = -cp[i - 1] * z;
      ginv[i * 97 + j] = z;
    }
    float xn = ginv[(m - 1) * 97 + j] * idt[m - 1];
    ginv[(m - 1) * 97 + j] = xn;
    for (int i = m - 2; i >= 0; --i) {
      float zi = (i >= j) ? ginv[i * 97 + j] : 0.f;
      xn = zi * idt[i] - cp[i] * xn;
      ginv[i * 97 + j] = xn;
    }
  }
  __syncthreads();
  if (p >= n) {
    for (int idx = tid; idx < p * n; idx += 256) {
      int t = idx / n, k = idx - t * n;
      int i0 = ii[t]; float w = ww[t];
      int i1 = min(i0 + 1, n - 1);
      dst[idx] = (1.f - w) * ginv[i0 * 97 + k] + w * ginv[i1 * 97 + k];
    }
  } else {
    for (int t = tid; t < p; t += 256) {
      for (int k = 0; k < n; ++k) outp[t * 97 + k] = 0.f;
      for (int j = 0; j < p; ++j) {
        float hv = ginv[t * 97 + j];
        int i0 = ii[j]; float w = ww[j];
        int i1 = min(i0 + 1, n - 1);
        outp[t * 97 + i0] += hv * (1.f - w);
        outp[t * 97 + i1] += hv * w;
      }
    }
    __syncthreads();
    for (int idx = tid; idx < p * n; idx += 256) {
      int t = idx / n, k = idx - t * n;
      dst[idx] = outp[t * 97 + k];
    }
  }
}

// ---------------- stage P1: anchors^T -> at_tab (192x512, pad zeroed) ----------------
__global__ __launch_bounds__(256) void at_kernel(const float* __restrict__ a12,
                                                 const float* __restrict__ a24,
                                                 const float* __restrict__ a48,
                                                 const float* __restrict__ a96,
                                                 float* __restrict__ at_tab) {
  __shared__ float tile[64 * 97];
  int bid = blockIdx.x;
  int a = bid >> 3, d0 = (bid & 7) * 64;
  int n = (a == 0) ? 12 : (a == 1) ? 24 : (a == 2) ? 48 : 96;
  const float* src = (a == 0) ? a12 : (a == 1) ? a24 : (a == 2) ? a48 : a96;
  float* dst = at_tab + (long)apre(n) * 512;
  int tid = threadIdx.x;
  for (int i = tid; i < 64 * n; i += 256) {
    int dd = i / n, k = i - dd * n;
    tile[dd * 97 + k] = src[(long)(d0 + dd) * n + (long)k];
  }
  __syncthreads();
  for (int i = tid; i < n * 64; i += 256) {
    int k = i >> 6, dd = i & 63;
    dst[(long)k * 512 + d0 + dd] = tile[dd * 97 + k];
  }
  if (bid == 0) {
    for (int i = tid; i < 12 * 512; i += 256) at_tab[180L * 512 + i] = 0.f;
  }
}

// ---------------- stage P3a: qc/kb folds + vb scratch ----------------
__global__ __launch_bounds__(256) void constsA(const float* __restrict__ i1w,
                                               const float* __restrict__ i1b,
                                               const float* __restrict__ i2w,
                                               const float* __restrict__ i2b,
                                               const float* __restrict__ sb,
                                               float* __restrict__ cons,
                                               float* __restrict__ vbuf) {
  __shared__ float sv[512];
  int bid = blockIdx.x;
  int s = bid / 96, r0 = (bid % 96) * 16;
  const float* inw = s ? i2w : i1w;
  const float* inb = s ? i2b : i1b;
  int tid = threadIdx.x;
  for (int i = tid; i < 512; i += 256) sv[i] = sb[i];
  __syncthreads();
  int lane = tid & 63, w = tid >> 6;
  for (int rr = 0; rr < 4; ++rr) {
    int r = r0 + w * 4 + rr;
    const float* row = inw + (long)r * 512;
    float part = 0.f;
    for (int kk = 0; kk < 8; ++kk) part += row[lane + 64 * kk] * sv[lane + 64 * kk];
    for (int off = 32; off > 0; off >>= 1) part += __shfl_down(part, off, 64);
    if (lane == 0) {
      float v = part + inb[r];
      if (r < 1024) cons[s * 1536 + r] = v;
      else vbuf[s * 512 + (r - 1024)] = v;
    }
  }
}

// ---------------- stage P3b: oc = out_w @ vb + outb ----------------
__global__ __launch_bounds__(256) void constsB(const float* __restrict__ o1w,
                                               const float* __restrict__ o1b,
                                               const float* __restrict__ o2w,
                                               const float* __restrict__ o2b,
                                               const float* __restrict__ vbuf,
                                               float* __restrict__ cons) {
  __shared__ float vv[512];
  int bid = blockIdx.x;
  int s = bid / 32, r0 = (bid % 32) * 16;
  const float* outw = s ? o2w : o1w;
  const float* outb = s ? o2b : o1b;
  int tid = threadIdx.x;
  for (int i = tid; i < 512; i += 256) vv[i] = vbuf[s * 512 + i];
  __syncthreads();
  int lane = tid & 63, w = tid >> 6;
  for (int rr = 0; rr < 4; ++rr) {
    int r = r0 + w * 4 + rr;
    const float* row = outw + (long)r * 512;
    float part = 0.f;
    for (int kk = 0; kk < 8; ++kk) part += row[lane + 64 * kk] * vv[lane + 64 * kk];
    for (int off = 32; off > 0; off >>= 1) part += __shfl_down(part, off, 64);
    if (lane == 0) cons[s * 1536 + 1024 + r] = part + outb[r];
  }
}

// ---------------- stage P2: WAfull = in_w @ A_cat (1536x192 per slot) ----------------
__global__ __launch_bounds__(256) void wa_gemm2(const float* __restrict__ iw0,
                                                const float* __restrict__ iw1,
                                                const float* __restrict__ atb,
                                                float* __restrict__ waf,
                                                float* __restrict__ qat,
                                                float* __restrict__ vat) {
  __shared__ float smem[2 * 32 * 68];
  float* As = smem;
  float* Ws = smem + 32 * 68;
  int bid = blockIdx.x;
  int s = bid / 72, r = bid % 72;
  int m0 = (r / 3) * 64, n0 = (r % 3) * 64;
  const float* A = s ? iw1 : iw0;
  float* wafs = waf + (long)s * 294912;
  int tid = threadIdx.x;
  int tm = tid & 15, tn = tid >> 4;
  float acc[4][4];
#pragma unroll
  for (int i = 0; i < 4; ++i)
#pragma unroll
    for (int j = 0; j < 4; ++j) acc[i][j] = 0.f;
  int row = tid >> 3, kc = (tid & 7) * 4;
  for (int k0 = 0; k0 < 512; k0 += 32) {
    float4 v = *(const float4*)&A[(long)(m0 + row) * 512 + k0 + kc];
    As[(kc + 0) * 68 + row] = v.x; As[(kc + 1) * 68 + row] = v.y;
    As[(kc + 2) * 68 + row] = v.z; As[(kc + 3) * 68 + row] = v.w;
    v = *(const float4*)&A[(long)(m0 + row + 32) * 512 + k0 + kc];
    As[(kc + 0) * 68 + row + 32] = v.x; As[(kc + 1) * 68 + row + 32] = v.y;
    As[(kc + 2) * 68 + row + 32] = v.z; As[(kc + 3) * 68 + row + 32] = v.w;
    v = *(const float4*)&atb[(long)(n0 + row) * 512 + k0 + kc];
    Ws[(kc + 0) * 68 + row] = v.x; Ws[(kc + 1) * 68 + row] = v.y;
    Ws[(kc + 2) * 68 + row] = v.z; Ws[(kc + 3) * 68 + row] = v.w;
    v = *(const float4*)&atb[(long)(n0 + row + 32) * 512 + k0 + kc];
    Ws[(kc + 0) * 68 + row + 32] = v.x; Ws[(kc + 1) * 68 + row + 32] = v.y;
    Ws[(kc + 2) * 68 + row + 32] = v.z; Ws[(kc + 3) * 68 + row + 32] = v.w;
    __syncthreads();
    for (int kk = 0; kk < 32; ++kk) {
      float4 a = *(const float4*)&As[kk * 68 + tm * 4];
      float4 w = *(const float4*)&Ws[kk * 68 + tn * 4];
      acc[0][0] += a.x * w.x; acc[0][1] += a.x * w.y; acc[0][2] += a.x * w.z; acc[0][3] += a.x * w.w;
      acc[1][0] += a.y * w.x; acc[1][1] += a.y * w.y; acc[1][2] += a.y * w.z; acc[1][3] += a.y * w.w;
      acc[2][0] += a.z * w.x; acc[2][1] += a.z * w.y; acc[2][2] += a.z * w.z; acc[2][3] += a.z * w.w;
      acc[3][0] += a.w * w.x; acc[3][1] += a.w * w.y; acc[3][2] += a.w * w.z; acc[3][3] += a.w * w.w;
    }
    __syncthreads();
  }
#pragma unroll
  for (int mi = 0; mi < 4; ++mi) {
    float4 o;
    o.x = acc[mi][0]; o.y = acc[mi][1]; o.z = acc[mi][2]; o.w = acc[mi][3];
    *(float4*)&wafs[(long)(m0 + tm * 4 + mi) * 192 + n0 + tn * 4] = o;
  }
  if (m0 < 512 || m0 >= 1024) {
    float* Ct = smem;
#pragma unroll
    for (int mi = 0; mi < 4; ++mi)
#pragma unroll
      for (int j = 0; j < 4; ++j)
        Ct[(tn * 4 + j) * 65 + tm * 4 + mi] = acc[mi][j];
    __syncthreads();
    float* dst = ((m0 < 512) ? qat : vat) + (long)s * 98304;
    int mr = m0 & 511;
    for (int i = tid; i < 64 * 64; i += 256) {
      int cc = i >> 6, rr = i & 63;
      dst[(long)(n0 + cc) * 512 + mr + rr] = Ct[cc * 65 + rr];
    }
  }
}

// ---------------- stage P5: MT[j][k] = sum_i QA[h128+i][j] * KA[h128+i][k] ----------------
// per (slot,h): 192x192, K=128. grid: 8 * 9 tiles
__global__ __launch_bounds__(256) void mt_gemm(const float* __restrict__ qat,
                                               const float* __restrict__ waf,
                                               float* __restrict__ mt) {
  __shared__ float As[32 * 68];
  __shared__ float Ws[32 * 68];
  int bid = blockIdx.x;
  int s4h = bid / 9, t = bid % 9;
  int s = s4h >> 2, h = s4h & 3;
  int m0 = (t / 3) * 64, n0 = (t % 3) * 64;
  const float* A = qat + (long)s * 98304 + h * 128;          // A[j][i], ld 512
  const float* B = waf + (long)s * 294912 + 98304 + (long)(h * 128) * 192;  // B[i][k], ld 192
  float* C = mt + (long)s4h * 36864;
  int tid = threadIdx.x;
  int tm = tid & 15, tn = tid >> 4;
  float acc[4][4];
#pragma unroll
  for (int i = 0; i < 4; ++i)
#pragma unroll
    for (int j = 0; j < 4; ++j) acc[i][j] = 0.f;
  int row = tid >> 3, kc = (tid & 7) * 4;
  for (int k0 = 0; k0 < 128; k0 += 32) {
    float4 v = *(const float4*)&A[(long)(m0 + row) * 512 + k0 + kc];
    As[(kc + 0) * 68 + row] = v.x; As[(kc + 1) * 68 + row] = v.y;
    As[(kc + 2) * 68 + row] = v.z; As[(kc + 3) * 68 + row] = v.w;
    v = *(const float4*)&A[(long)(m0 + row + 32) * 512 + k0 + kc];
    As[(kc + 0) * 68 + row + 32] = v.x; As[(kc + 1) * 68 + row + 32] = v.y;
    As[(kc + 2) * 68 + row + 32] = v.z; As[(kc + 3) * 68 + row + 32] = v.w;
    for (int l = tid; l < 512; l += 256) {
      int i = l >> 4, kq = (l & 15) * 4;
      float4 b = *(const float4*)&B[(long)(k0 + i) * 192 + n0 + kq];
      Ws[i * 68 + kq + 0] = b.x; Ws[i * 68 + kq + 1] = b.y;
      Ws[i * 68 + kq + 2] = b.z; Ws[i * 68 + kq + 3] = b.w;
    }
    __syncthreads();
    for (int kk = 0; kk < 32; ++kk) {
      float4 a = *(const float4*)&As[kk * 68 + tm * 4];
      float4 w = *(const float4*)&Ws[kk * 68 + tn * 4];
      acc[0][0] += a.x * w.x; acc[0][1] += a.x * w.y; acc[0][2] += a.x * w.z; acc[0][3] += a.x * w.w;
      acc[1][0] += a.y * w.x; acc[1][1] += a.y * w.y; acc[1][2] += a.y * w.z; acc[1][3] += a.y * w.w;
      acc[2][0] += a.z * w.x; acc[2][1] += a.z * w.y; acc[2][2] += a.z * w.z; acc[2][3] += a.z * w.w;
      acc[3][0] += a.w * w.x; acc[3][1] += a.w * w.y; acc[3][2] += a.w * w.z; acc[3][3] += a.w * w.w;
    }
    __syncthreads();
  }
#pragma unroll
  for (int mi = 0; mi < 4; ++mi) {
    float4 o;
    o.x = acc[mi][0]; o.y = acc[mi][1]; o.z = acc[mi][2]; o.w = acc[mi][3];
    *(float4*)&C[(long)(m0 + tm * 4 + mi) * 192 + n0 + tn * 4] = o;
  }
}

// ---------------- stage P6: d/e/f score constants per (slot,h) ----------------
__global__ __launch_bounds__(256) void scoreconsts(const float* __restrict__ qat,
                                                   const float* __restrict__ waf,
                                                   const float* __restrict__ cons,
                                                   float* __restrict__ def) {
  __shared__ float qcl[128];
  __shared__ float kbl[128];
  int bid = blockIdx.x;
  int s = bid >> 2, h = bid & 3;
  int tid = threadIdx.x;
  const float* qc = cons + s * 1536;
  const float* kb = qc + 512;
  if (tid < 128) {
    qcl[tid] = qc[h * 128 + tid];
    kbl[tid] = kb[h * 128 + tid];
  }
  __syncthreads();
  const float* katb = waf + (long)s * 294912 + 98304;  // KA rows, ld 192
  const float* qats = qat + (long)s * 98304;           // QA^T: [j][r], ld 512
  float* dtab = def + (long)(s * 4 + h) * 192;
  float* etab = def + 1536 + (long)(s * 4 + h) * 192;
  float* ftab = def + 3072 + (s * 4 + h);
  if (tid < 192) {
    float acc = 0.f;
    for (int i = 0; i < 128; ++i) acc += katb[(long)(h * 128 + i) * 192 + tid] * qcl[i];
    dtab[tid] = acc;
    float acc2 = 0.f;
    const float* qr = qats + (long)tid * 512 + h * 128;
    for (int i = 0; i < 128; ++i) acc2 += qr[i] * kbl[i];
    etab[tid] = acc2;
  }
  if (tid < 64) {
    float acc = 0.f;
    for (int i = tid; i < 128; i += 64) acc += qcl[i] * kbl[i];
    for (int off = 32; off > 0; off >>= 1) acc += __shfl_down(acc, off, 64);
    if (tid == 0) *ftab = acc;
  }
}

// ---------------- stage P4: OVA^T per (slot,head) ----------------
__global__ __launch_bounds__(256) void ova_gemm2(const float* __restrict__ ow0,
                                                 const float* __restrict__ ow1,
                                                 const float* __restrict__ vat,
                                                 float* __restrict__ ovt) {
  __shared__ float As[32 * 68];
  __shared__ float Ws[32 * 68];
  int bid = blockIdx.x;
  int s = bid / 96, r = bid % 96;
  int h = r / 24, r2 = r % 24;
  int m0 = (r2 / 8) * 64, n0 = (r2 % 8) * 64;
  const float* A = vat + (long)s * 98304 + h * 128;
  const float* W = (s ? ow1 : ow0) + h * 128;
  float* C = ovt + ((long)(s * 4 + h) * 192) * 512;
  int tid = threadIdx.x;
  int tm = tid & 15, tn = tid >> 4;
  float acc[4][4];
#pragma unroll
  for (int i = 0; i < 4; ++i)
#pragma unroll
    for (int j = 0; j < 4; ++j) acc[i][j] = 0.f;
  int row = tid >> 3, kc = (tid & 7) * 4;
  for (int k0 = 0; k0 < 128; k0 += 32) {
    float4 v = *(const float4*)&A[(long)(m0 + row) * 512 + k0 + kc];
    As[(kc + 0) * 68 + row] = v.x; As[(kc + 1) * 68 + row] = v.y;
    As[(kc + 2) * 68 + row] = v.z; As[(kc + 3) * 68 + row] = v.w;
    v = *(const float4*)&A[(long)(m0 + row + 32) * 512 + k0 + kc];
    As[(kc + 0) * 68 + row + 32] = v.x; As[(kc + 1) * 68 + row + 32] = v.y;
    As[(kc + 2) * 68 + row + 32] = v.z; As[(kc + 3) * 68 + row + 32] = v.w;
    v = *(const float4*)&W[(long)(n0 + row) * 512 + k0 + kc];
    Ws[(kc + 0) * 68 + row] = v.x; Ws[(kc + 1) * 68 + row] = v.y;
    Ws[(kc + 2) * 68 + row] = v.z; Ws[(kc + 3) * 68 + row] = v.w;
    v = *(const float4*)&W[(long)(n0 + row + 32) * 512 + k0 + kc];
    Ws[(kc + 0) * 68 + row + 32] = v.x; Ws[(kc + 1) * 68 + row + 32] = v.y;
    Ws[(kc + 2) * 68 + row + 32] = v.z; Ws[(kc + 3) * 68 + row + 32] = v.w;
    __syncthreads();
    for (int kk = 0; kk < 32; ++kk) {
      float4 a = *(const float4*)&As[kk * 68 + tm * 4];
      float4 w = *(const float4*)&Ws[kk * 68 + tn * 4];
      acc[0][0] += a.x * w.x; acc[0][1] += a.x * w.y; acc[0][2] += a.x * w.z; acc[0][3] += a.x * w.w;
      acc[1][0] += a.y * w.x; acc[1][1] += a.y * w.y; acc[1][2] += a.y * w.z; acc[1][3] += a.y * w.w;
      acc[2][0] += a.z * w.x; acc[2][1] += a.z * w.y; acc[2][2] += a.z * w.z; acc[2][3] += a.z * w.w;
      acc[3][0] += a.w * w.x; acc[3][1] += a.w * w.y; acc[3][2] += a.w * w.z; acc[3][3] += a.w * w.w;
    }
    __syncthreads();
  }
#pragma unroll
  for (int mi = 0; mi < 4; ++mi) {
    float4 o;
    o.x = acc[mi][0]; o.y = acc[mi][1]; o.z = acc[mi][2]; o.w = acc[mi][3];
    *(float4*)&C[(long)(m0 + tm * 4 + mi) * 512 + n0 + tn * 4] = o;
  }
}

// ---------------- stage B: fused attention, G=8 batches/block, folded scores ----------------
__global__ __launch_bounds__(256) void attn_kernel(
    const float* __restrict__ xT, const int* __restrict__ per,
    const float* __restrict__ mp, const float* __restrict__ mt,
    const float* __restrict__ def, const float* __restrict__ ovt,
    const float* __restrict__ cons, const float* __restrict__ at_tab,
    const float* __restrict__ sb,
    const float* __restrict__ l1g, const float* __restrict__ l1b,
    const float* __restrict__ l2g, const float* __restrict__ l2b,
    float* __restrict__ comb) {
  __shared__ float xb[8 * 384];     // reused as sc after Ph1
  __shared__ float Z[8 * 1248];
  __shared__ float zl[8 * 96];
  __shared__ float arb[8 * 384];
  __shared__ float qkc[32];
  __shared__ float red[4 * 16];
  __shared__ float stats[16];
  float* scp = xb;

  int tid = threadIdx.x;
  int bid = blockIdx.x;
  int slot = bid & 1;
  int c = (bid >> 1) & 127;
  int b0 = (bid >> 8) * 8;
  int p = per[c * 2 + slot];
  int n = nanch(p);
  int np = Tn / p;
  int n1 = n + 1;
  float s = sqrtf((float)p / (float)n);
  float s2 = s * s;
  const float rscale = 0.08838834764831845f;
  int pre = apre(n);
  const float* mpp = mp + mpoff(p);
  const float* atb = at_tab + (long)pre * 512;
  const float* oc = cons + slot * 1536 + 1024;
  const float* lng = slot ? l2g : l1g;
  const float* lnb = slot ? l2b : l1b;
  const float* dt = def + (long)(slot * 4) * 192;
  const float* et = def + 1536 + (long)(slot * 4) * 192;
  const float* ft = def + 3072 + slot * 4;
  const float* mtb = mt + (long)(slot * 4) * 36864;

  // Ph0: stage x rows
  for (int g = 0; g < 8; ++g)
    for (int t = tid; t < Tn; t += 256)
      xb[g * 384 + t] = xT[((long)c * Bn + b0 + g) * Tn + t];
  __syncthreads();

  // Ph1: Z = patches @ Mpinv (8-way g-fused)
  int znp = np * n;
  for (int idx = tid; idx < znp; idx += 256) {
    int j = idx / n, k = idx - j * n;
    int jb = j * p;
    const float* mk = mpp + k;
    float a[8];
#pragma unroll
    for (int g = 0; g < 8; ++g) a[g] = 0.f;
    for (int t = 0; t < p; ++t) {
      float m = mk[(long)t * n];
#pragma unroll
      for (int g = 0; g < 8; ++g) a[g] += m * xb[g * 384 + jb + t];
    }
    int zi = j * n1 + k;
#pragma unroll
    for (int g = 0; g < 8; ++g) Z[g * 1248 + zi] = a[g];
  }
  __syncthreads();

  // zl: copy z_last (aligned 96-stride)
  for (int idx = tid; idx < 8 * n; idx += 256) {
    int g = idx / n, k = idx - g * n;
    zl[g * 96 + k] = Z[g * 1248 + (np - 1) * n1 + k];
  }
  __syncthreads();

  // qkc[g][h] = s * e_h . z_last + f_h   (32 pairs x 8 lanes)
  {
    int pair = tid >> 3, l = tid & 7;
    int g = pair >> 2, h = pair & 3;
    const float* eh = et + h * 192 + pre;
    float acc = 0.f;
    for (int j = l; j < n; j += 8) acc += eh[j] * zl[g * 96 + j];
    for (int off = 4; off > 0; off >>= 1) acc += __shfl_down(acc, off, 8);
    if (l == 0) qkc[g * 4 + h] = s * acc + ft[h];
  }
  // ar[g][h][k] = s^2 * MT_h z_last + s * d_h[k]
  {
    int tot = 4 * n;
    for (int idx = tid; idx < tot; idx += 256) {
      int h = idx / n, k = idx - h * n;
      const float* mtc = mtb + (long)h * 36864 + (long)pre * 192 + pre + k;
      float a[8];
#pragma unroll
      for (int g = 0; g < 8; ++g) a[g] = 0.f;
      for (int j0 = 0; j0 < n; j0 += 4) {
        float4 zb[8];
#pragma unroll
        for (int g = 0; g < 8; ++g) zb[g] = *(const float4*)&zl[g * 96 + j0];
#pragma unroll
        for (int c4 = 0; c4 < 4; ++c4) {
          float mv = mtc[(long)(j0 + c4) * 192];
#pragma unroll
          for (int g = 0; g < 8; ++g) {
            float zv = (c4 == 0) ? zb[g].x : (c4 == 1) ? zb[g].y : (c4 == 2) ? zb[g].z : zb[g].w;
            a[g] += mv * zv;
          }
        }
      }
      float dv = dt[h * 192 + pre + k];
#pragma unroll
      for (int g = 0; g < 8; ++g) arb[g * 384 + h * 96 + k] = s2 * a[g] + s * dv;
    }
  }
  __syncthreads();

  // Ph4: scores
  {
    int fnp = 4 * np;
    int tot = 8 * fnp;
    for (int idx = tid; idx < tot; idx += 256) {
      int g = idx / fnp;
      int r = idx - g * fnp;
      int h = r / np, j = r - h * np;
      const float* ap = arb + g * 384 + h * 96;
      const float* zp = Z + g * 1248 + j * n1;
      float acc = 0.f;
      for (int k = 0; k < n; ++k) acc += ap[k] * zp[k];
      scp[g * 384 + h * np + j] = (acc + qkc[g * 4 + h]) * rscale;
    }
  }
  __syncthreads();

  // Ph5: softmax (32 pairs x 8 lanes)
  {
    int pair = tid >> 3, l = tid & 7;
    int g = pair >> 2, h = pair & 3;
    float* sp = scp + g * 384 + h * np;
    float m = -1e30f;
    for (int j = l; j < np; j += 8) m = fmaxf(m, sp[j]);
    for (int off = 4; off > 0; off >>= 1) m = fmaxf(m, __shfl_xor(m, off, 8));
    float lsum = 0.f;
    for (int j = l; j < np; j += 8) { float e = expf(sp[j] - m); sp[j] = e; lsum += e; }
    for (int off = 4; off > 0; off >>= 1) lsum += __shfl_xor(lsum, off, 8);
    float il = 1.f / lsum;
    for (int j = l; j < np; j += 8) sp[j] *= il;
  }
  __syncthreads();

  // Ph6: zh into arb
  {
    int fn = 4 * n;
    int tot = 8 * fn;
    for (int idx = tid; idx < tot; idx += 256) {
      int g = idx / fn;
      int r = idx - g * fn;
      int h = r / n, k = r - h * n;
      const float* sp = scp + g * 384 + h * np;
      const float* zp = Z + g * 1248 + k;
      float acc = 0.f;
      for (int j = 0; j < np; ++j) acc += sp[j] * zp[j * n1];
      arb[g * 384 + h * 96 + k] = acc;
    }
  }
  __syncthreads();

  // Ph7: y + layernorm + write
  {
    int d0 = 2 * tid;
    float a0[8], a1[8];
#pragma unroll
    for (int g = 0; g < 8; ++g) { a0[g] = 0.f; a1[g] = 0.f; }
    for (int k0 = 0; k0 < n; k0 += 4) {
      float4 zb[8];
#pragma unroll
      for (int g = 0; g < 8; ++g) zb[g] = *(const float4*)&zl[g * 96 + k0];
#pragma unroll
      for (int c4 = 0; c4 < 4; ++c4) {
        float2 w = *(const float2*)&atb[(long)(k0 + c4) * 512 + d0];
#pragma unroll
        for (int g = 0; g < 8; ++g) {
          float zv = (c4 == 0) ? zb[g].x : (c4 == 1) ? zb[g].y : (c4 == 2) ? zb[g].z : zb[g].w;
          a0[g] += w.x * zv; a1[g] += w.y * zv;
        }
      }
    }
    for (int h = 0; h < 4; ++h) {
      const float* op = ovt + ((long)((slot * 4 + h) * 192 + pre)) * 512;
      const float* zhb = arb + h * 96;
      for (int k0 = 0; k0 < n; k0 += 4) {
        float4 zb[8];
#pragma unroll
        for (int g = 0; g < 8; ++g) zb[g] = *(const float4*)&zhb[g * 384 + k0];
#pragma unroll
        for (int c4 = 0; c4 < 4; ++c4) {
          float2 w = *(const float2*)&op[(long)(k0 + c4) * 512 + d0];
#pragma unroll
          for (int g = 0; g < 8; ++g) {
            float zv = (c4 == 0) ? zb[g].x : (c4 == 1) ? zb[g].y : (c4 == 2) ? zb[g].z : zb[g].w;
            a0[g] += w.x * zv; a1[g] += w.y * zv;
          }
        }
      }
    }
    float2 sbv = *(const float2*)&sb[d0];
    float2 ocv = *(const float2*)&oc[d0];
    float s0 = sbv.x + ocv.x, s1v = sbv.y + ocv.y;
#pragma unroll
    for (int g = 0; g < 8; ++g) { a0[g] = s * a0[g] + s0; a1[g] = s * a1[g] + s1v; }
    // LN reduction: 16 partials per thread
    float ps[16];
#pragma unroll
    for (int g = 0; g < 8; ++g) {
      ps[2 * g] = a0[g] + a1[g];
      ps[2 * g + 1] = a0[g] * a0[g] + a1[g] * a1[g];
    }
    int w = tid >> 6, lane = tid & 63;
    for (int off = 32; off > 0; off >>= 1) {
#pragma unroll
      for (int i = 0; i < 16; ++i) ps[i] += __shfl_down(ps[i], off, 64);
    }
    if (lane == 0) {
#pragma unroll
      for (int i = 0; i < 16; ++i) red[w * 16 + i] = ps[i];
    }
    __syncthreads();
    if (tid < 8) {
      int g = tid;
      float ssum = red[2 * g] + red[16 + 2 * g] + red[32 + 2 * g] + red[48 + 2 * g];
      float qsum = red[2 * g + 1] + red[16 + 2 * g + 1] + red[32 + 2 * g + 1] + red[48 + 2 * g + 1];
      float mu = ssum / 512.f;
      float var = qsum / 512.f - mu * mu;
      stats[g * 2] = mu;
      stats[g * 2 + 1] = rsqrtf(var + 1e-5f);
    }
    __syncthreads();
    float2 gv = *(const float2*)&lng[d0];
    float2 bv = *(const float2*)&lnb[d0];
#pragma unroll
    for (int g = 0; g < 8; ++g) {
      float mu = stats[g * 2], rstd = stats[g * 2 + 1];
      long base = ((long)(b0 + g) * Cn + c) * 1536 + slot * 512;
      float2 o;
      o.x = (a0[g] - mu) * rstd * gv.x + bv.x;
      o.y = (a1[g] - mu) * rstd * gv.y + bv.y;
      *(float2*)&comb[base + d0] = o;
    }
  }
}

// ---------------- stage D: trend ----------------
__global__ __launch_bounds__(256) void trend_kernel(const float* __restrict__ xT,
                                                    const float* __restrict__ mp384,
                                                    const float* __restrict__ at96,
                                                    const float* __restrict__ sb,
                                                    float* __restrict__ comb) {
  __shared__ float xb[Bn * Tn];
  __shared__ float Ztr[Bn * 97];
  int c = blockIdx.x, tid = threadIdx.x;
  for (int i = tid; i < Bn * Tn; i += 256) xb[i] = xT[(long)c * Bn * Tn + i];
  __syncthreads();
  for (int idx = tid; idx < 4 * 96; idx += 256) {
    int bq = idx / 96, k = idx - bq * 96;
    const float* x0 = xb + (bq * 4 + 0) * Tn;
    const float* x1 = xb + (bq * 4 + 1) * Tn;
    const float* x2 = xb + (bq * 4 + 2) * Tn;
    const float* x3 = xb + (bq * 4 + 3) * Tn;
    const float* mk = mp384 + k;
    float a0 = 0.f, a1 = 0.f, a2 = 0.f, a3 = 0.f;
    for (int t = 0; t < Tn; ++t) {
      float m = mk[(long)t * 96];
      a0 += m * x0[t]; a1 += m * x1[t]; a2 += m * x2[t]; a3 += m * x3[t];
    }
    Ztr[(bq * 4 + 0) * 97 + k] = a0;
    Ztr[(bq * 4 + 1) * 97 + k] = a1;
    Ztr[(bq * 4 + 2) * 97 + k] = a2;
    Ztr[(bq * 4 + 3) * 97 + k] = a3;
  }
  __syncthreads();
  float acc0[Bn], acc1[Bn];
#pragma unroll
  for (int b = 0; b < Bn; ++b) { acc0[b] = 0.f; acc1[b] = 0.f; }
  for (int k = 0; k < 96; ++k) {
    float w0 = at96[(long)k * 512 + tid];
    float w1 = at96[(long)k * 512 + 256 + tid];
#pragma unroll
    for (int b = 0; b < Bn; ++b) {
      float z = Ztr[b * 97 + k];
      acc0[b] += w0 * z;
      acc1[b] += w1 * z;
    }
  }
  float s0 = sb[tid], s1 = sb[256 + tid];
#pragma unroll
  for (int b = 0; b < Bn; ++b) {
    long base = ((long)b * Cn + c) * 1536 + 1024;
    comb[base + tid] = 2.f * acc0[b] + s0;
    comb[base + 256 + tid] = 2.f * acc1[b] + s1;
  }
}

// ---------------- stage E: fusion GEMM ----------------
template <bool GELU>
__global__ __launch_bounds__(256) void fused_gemm(const float* __restrict__ A,
                                                  const float* __restrict__ W,
                                                  const float* __restrict__ bias,
                                                  float* __restrict__ C,
                                                  int N, int K) {
  __shared__ float As[32 * 68];
  __shared__ float Ws[32 * 68];
  int nb = N >> 6;
  int m0 = (blockIdx.x / nb) * 64, n0 = (blockIdx.x % nb) * 64;
  int tid = threadIdx.x;
  int tm = tid & 15, tn = tid >> 4;
  float acc[4][4];
#pragma unroll
  for (int i = 0; i < 4; ++i)
#pragma unroll
    for (int j = 0; j < 4; ++j) acc[i][j] = 0.f;
  int row = tid >> 3, kc = (tid & 7) * 4;
  for (int k0 = 0; k0 < K; k0 += 32) {
    {
      float4 v = *(const float4*)&A[(long)(m0 + row) * K + k0 + kc];
      As[(kc + 0) * 68 + row] = v.x; As[(kc + 1) * 68 + row] = v.y;
      As[(kc + 2) * 68 + row] = v.z; As[(kc + 3) * 68 + row] = v.w;
      v = *(const float4*)&A[(long)(m0 + row + 32) * K + k0 + kc];
      As[(kc + 0) * 68 + row + 32] = v.x; As[(kc + 1) * 68 + row + 32] = v.y;
      As[(kc + 2) * 68 + row + 32] = v.z; As[(kc + 3) * 68 + row + 32] = v.w;
      v = *(const float4*)&W[(long)(n0 + row) * K + k0 + kc];
      Ws[(kc + 0) * 68 + row] = v.x; Ws[(kc + 1) * 68 + row] = v.y;
      Ws[(kc + 2) * 68 + row] = v.z; Ws[(kc + 3) * 68 + row] = v.w;
      v = *(const float4*)&W[(long)(n0 + row + 32) * K + k0 + kc];
      Ws[(kc + 0) * 68 + row + 32] = v.x; Ws[(kc + 1) * 68 + row + 32] = v.y;
      Ws[(kc + 2) * 68 + row + 32] = v.z; Ws[(kc + 3) * 68 + row + 32] = v.w;
    }
    __syncthreads();
    for (int kk = 0; kk < 32; ++kk) {
      float4 a = *(const float4*)&As[kk * 68 + tm * 4];
      float4 w = *(const float4*)&Ws[kk * 68 + tn * 4];
      acc[0][0] += a.x * w.x; acc[0][1] += a.x * w.y; acc[0][2] += a.x * w.z; acc[0][3] += a.x * w.w;
      acc[1][0] += a.y * w.x; acc[1][1] += a.y * w.y; acc[1][2] += a.y * w.z; acc[1][3] += a.y * w.w;
      acc[2][0] += a.z * w.x; acc[2][1] += a.z * w.y; acc[2][2] += a.z * w.z; acc[2][3] += a.z * w.w;
      acc[3][0] += a.w * w.x; acc[3][1] += a.w * w.y; acc[3][2] += a.w * w.z; acc[3][3] += a.w * w.w;
    }
    __syncthreads();
  }
  float b0v = bias[n0 + tn * 4 + 0], b1v = bias[n0 + tn * 4 + 1];
  float b2v = bias[n0 + tn * 4 + 2], b3v = bias[n0 + tn * 4 + 3];
#pragma unroll
  for (int mi = 0; mi < 4; ++mi) {
    float4 o;
    o.x = acc[mi][0] + b0v; o.y = acc[mi][1] + b1v;
    o.z = acc[mi][2] + b2v; o.w = acc[mi][3] + b3v;
    if (GELU) {
      o.x = 0.5f * o.x * (1.f + erff(o.x * 0.7071067811865475f));
      o.y = 0.5f * o.y * (1.f + erff(o.y * 0.7071067811865475f));
      o.z = 0.5f * o.z * (1.f + erff(o.z * 0.7071067811865475f));
      o.w = 0.5f * o.w * (1.f + erff(o.w * 0.7071067811865475f));
    }
    *(float4*)&C[(long)(m0 + tm * 4 + mi) * N + n0 + tn * 4] = o;
  }
}

extern "C" void kernel_launch(void* const* d_in, const int* in_sizes, int n_in,
                              void* d_out, int out_size, void* d_ws, size_t ws_size,
                              hipStream_t stream) {
  const float* x    = (const float*)d_in[0];
  const float* a12  = (const float*)d_in[1];
  const float* a24  = (const float*)d_in[2];
  const float* a48  = (const float*)d_in[3];
  const float* a96  = (const float*)d_in[4];
  const float* sb   = (const float*)d_in[5];
  const float* g1iw = (const float*)d_in[6];
  const float* g1ib = (const float*)d_in[7];
  const float* g1ow = (const float*)d_in[8];
  const float* g1ob = (const float*)d_in[9];
  const float* g1lg = (const float*)d_in[10];
  const float* g1lb = (const float*)d_in[11];
  const float* g2iw = (const float*)d_in[12];
  const float* g2ib = (const float*)d_in[13];
  const float* g2ow = (const float*)d_in[14];
  const float* g2ob = (const float*)d_in[15];
  const float* g2lg = (const float*)d_in[16];
  const float* g2lb = (const float*)d_in[17];
  const float* fw1  = (const float*)d_in[18];
  const float* fb1  = (const float*)d_in[19];
  const float* fw2  = (const float*)d_in[20];
  const float* fb2  = (const float*)d_in[21];

  if (ws_size < (size_t)WS_FLOATS * sizeof(float)) return;

  float* ws   = (float*)d_ws;
  float* xT   = ws + OFF_XT;
  float* avgT = ws + OFF_AVG;
  int*   per  = (int*)(ws + OFF_PER);
  float* mp   = ws + OFF_MP;
  float* atb  = ws + OFF_AT;
  float* waf  = ws + OFF_WAF;
  float* qat  = ws + OFF_QAT;
  float* vat  = ws + OFF_VAT;
  float* ovt  = ws + OFF_OVT;
  float* cons = ws + OFF_CON;
  float* vbuf = ws + OFF_VB;
  float* mtab = ws + OFF_MT;
  float* def  = ws + OFF_DEF;
  float* comb = ws + OFF_COMB;
  float* hbuf = ws + OFF_H;
  float* out  = (float*)d_out;

  transpose_kernel<<<192, 256, 0, stream>>>(x, xT);
  acf_kernel<<<Cn * 6, 256, 0, stream>>>(xT, avgT);
  periods_kernel<<<1, 128, 0, stream>>>(avgT, per);
  build_mpinv_kernel<<<190, 256, 0, stream>>>(per, mp);
  at_kernel<<<32, 256, 0, stream>>>(a12, a24, a48, a96, atb);
  constsA<<<192, 256, 0, stream>>>(g1iw, g1ib, g2iw, g2ib, sb, cons, vbuf);
  constsB<<<64, 256, 0, stream>>>(g1ow, g1ob, g2ow, g2ob, vbuf, cons);
  wa_gemm2<<<144, 256, 0, stream>>>(g1iw, g2iw, atb, waf, qat, vat);
  mt_gemm<<<72, 256, 0, stream>>>(qat, waf, mtab);
  scoreconsts<<<8, 256, 0, stream>>>(qat, waf, cons, def);
  ova_gemm2<<<192, 256, 0, stream>>>(g1ow, g2ow, vat, ovt);

  attn_kernel<<<512, 256, 0, stream>>>(xT, per, mp, mtab, def, ovt, cons, atb, sb,
                                       g1lg, g1lb, g2lg, g2lb, comb);
  trend_kernel<<<Cn, 256, 0, stream>>>(xT, mp + 1634436L, atb + 84L * 512, sb, comb);
  fused_gemm<true><<<256, 256, 0, stream>>>(comb, fw1, fb1, hbuf, 512, 1536);
  fused_gemm<false><<<256, 256, 0, stream>>>(hbuf, fw2, fb2, out, 512, 512);
}

// Round 8
// 447.063 us; speedup vs baseline: 17.6337x; 1.2271x over previous
//
#include <hip/hip_runtime.h>
#include <math.h>

#define Bn 16
#define Tn 384
#define Cn 128

// ---------------- workspace layout (floats) ----------------
static constexpr long OFF_XT   = 0;         // 786432
static constexpr long OFF_AVG  = 786432;    // 49152 (channel-major: [c][t])
static constexpr long OFF_PER  = 835584;    // 256 ints
static constexpr long OFF_MP   = 835840;    // 1671300
static constexpr long OFF_AT   = 2507140;   // 98304: anchors^T padded to 192 rows [k*512+d]
static constexpr long OFF_WAF  = 2605444;   // 589824: per slot 1536x192 (in_w @ A_cat)
static constexpr long OFF_QAT  = 3195268;   // 196608: per slot 192x512 (Q-part transposed)
static constexpr long OFF_VAT  = 3391876;   // 196608: per slot 192x512 (V-part transposed)
static constexpr long OFF_OVT  = 3588484;   // 786432: per (slot,h) 192x512 OVA^T
static constexpr long OFF_CON  = 4374916;   // 3072
static constexpr long OFF_VB   = 4377988;   // 1024
static constexpr long OFF_MT   = 4379012;   // 294912: per (slot,h) 192x192 MT[j][k]
static constexpr long OFF_DEF  = 4673924;   // 1536 d + 1536 e + 8 f
static constexpr long OFF_COMB = 4677004;   // 3145728
static constexpr long OFF_H    = 7822732;   // 1048576
static constexpr long WS_FLOATS = 8871308;  // ~35.5 MB

__host__ __device__ inline int nanch(int p) {
  if (p == 384) return 96;
  return (p <= 18) ? 12 : (p <= 36) ? 24 : (p <= 72) ? 48 : 96;
}
__host__ __device__ inline int apre(int n) {
  return (n == 12) ? 0 : (n == 24) ? 12 : (n == 48) ? 36 : 84;
}
__host__ __device__ inline long mpoff(int p) {
  if (p == 384) return 1634436L;
  long T = (long)(p - 1) * p / 2;
  if (p <= 18) return 12 * (T - 6);
  if (p <= 36) return 1980 + 24 * (T - 171);
  if (p <= 72) return 13860 + 48 * (T - 666);
  return 108036 + 96 * (T - 2628);
}

__device__ inline void irow(int j, int newl, int oldl, int& i0, int& i1, float& w) {
  double src = ((double)j + 0.5) * (double)oldl / (double)newl - 0.5;
  if (src < 0.0) src = 0.0;
  double mx = (double)(oldl - 1);
  if (src > mx) src = mx;
  int a = (int)src;
  if (a > oldl - 1) a = oldl - 1;
  i0 = a;
  i1 = (a + 1 < oldl) ? (a + 1) : (oldl - 1);
  w = (float)(src - (double)a);
}

// ---------------- stage 0: transpose x -> xT[c][b][t] ----------------
__global__ __launch_bounds__(256) void transpose_kernel(const float* __restrict__ x,
                                                        float* __restrict__ xT) {
  __shared__ float tile[32 * 129];
  int bid = blockIdx.x;
  int b = bid / 12, t0 = (bid % 12) * 32;
  int tid = threadIdx.x;
  for (int i = tid; i < 32 * 128; i += 256) {
    int tt = i >> 7, cc = i & 127;
    tile[tt * 129 + cc] = x[((long)b * Tn + t0 + tt) * Cn + cc];
  }
  __syncthreads();
  for (int i = tid; i < 32 * 128; i += 256) {
    int cc = i >> 5, tt = i & 31;
    xT[((long)cc * Bn + b) * Tn + t0 + tt] = tile[tt * 129 + cc];
  }
}

// ---------------- stage A1: ACF (writes avg[c][t] channel-major) ----------------
__global__ __launch_bounds__(256) void acf_kernel(const float* __restrict__ xT,
                                                  float* __restrict__ avg) {
  __shared__ float xb[Bn * 397];
  __shared__ float mean[Bn];
  int bid = blockIdx.x;
  int c = bid / 6, tile = bid % 6;
  int tid = threadIdx.x;
  for (int i = tid; i < Bn * Tn; i += 256) {
    int b = i / Tn, t = i - b * Tn;
    xb[b * 397 + t] = xT[(long)c * Bn * Tn + i];
  }
  for (int i = tid; i < Bn * 13; i += 256) {
    int b = i / 13, t = Tn + (i - b * 13);
    xb[b * 397 + t] = 0.f;
  }
  __syncthreads();
  if (tid < Bn) {
    float s = 0.f;
    for (int t = 0; t < Tn; ++t) s += xb[tid * 397 + t];
    mean[tid] = s / (float)Tn;
  }
  __syncthreads();
  for (int i = tid; i < Bn * Tn; i += 256) {
    int b = i / Tn, t = i - b * Tn;
    xb[b * 397 + t] -= mean[b];
  }
  __syncthreads();
  int q = tid >> 4;
  int g = tid & 15;
  int tau0 = tile * 64 + q * 4;
  const float* xr = xb + g * 397;
  float a0 = 0.f, a1 = 0.f, a2 = 0.f, a3 = 0.f;
  float w0 = xr[tau0], w1 = xr[tau0 + 1], w2 = xr[tau0 + 2], w3 = xr[tau0 + 3];
  int tmax = Tn - tau0;
  for (int t = 0; t < tmax; ++t) {
    float a = xr[t];
    float wn = xr[t + tau0 + 4];
    a0 += a * w0; a1 += a * w1; a2 += a * w2; a3 += a * w3;
    w0 = w1; w1 = w2; w2 = w3; w3 = wn;
  }
  for (int off = 8; off > 0; off >>= 1) {
    a0 += __shfl_down(a0, off, 16);
    a1 += __shfl_down(a1, off, 16);
    a2 += __shfl_down(a2, off, 16);
    a3 += __shfl_down(a3, off, 16);
  }
  if (g == 0) {
    float* dst = avg + (long)c * Tn + tau0;
    dst[0] = a0; dst[1] = a1; dst[2] = a2; dst[3] = a3;
  }
}

// ---------------- stage A2: peaks — one wave per channel, shuffle top-2 ----------------
__global__ __launch_bounds__(256) void periods_kernel(const float* __restrict__ avg,
                                                      int* __restrict__ per) {
  int wv = threadIdx.x >> 6;
  int lane = threadIdx.x & 63;
  int c = blockIdx.x * 4 + wv;        // grid 32
  const float* a = avg + (long)c * Tn;
  const float NEG = -1e30f;
  float b1v = NEG, b2v = NEG;
  int b1i = 0, b2i = 0;
  int t0 = 4 + lane * 6;
#pragma unroll
  for (int i = 0; i < 6; ++i) {
    int t = t0 + i;
    if (t > Tn - 1) break;
    float v = a[t];
    float pv = (t == 4) ? NEG : a[t - 1];
    float nv = (t == Tn - 1) ? NEG : a[t + 1];
    bool peak = (v > pv) && (v > nv) && (v > 0.f);
    float m = peak ? v : NEG;
    if (m > b1v || (m == b1v && t < b1i)) {
      b2v = b1v; b2i = b1i; b1v = m; b1i = t;
    } else if (m > b2v || (m == b2v && t < b2i)) {
      b2v = m; b2i = t;
    }
  }
  for (int off = 32; off > 0; off >>= 1) {
    float c1v = __shfl_down(b1v, off, 64); int c1i = __shfl_down(b1i, off, 64);
    float c2v = __shfl_down(b2v, off, 64); int c2i = __shfl_down(b2i, off, 64);
    if (c1v > b1v || (c1v == b1v && c1i < b1i)) {
      b2v = b1v; b2i = b1i; b1v = c1v; b1i = c1i;
    } else if (c1v > b2v || (c1v == b2v && c1i < b2i)) {
      b2v = c1v; b2i = c1i;
    }
    if (c2v > b1v || (c2v == b1v && c2i < b1i)) {
      b2v = b1v; b2i = b1i; b1v = c2v; b1i = c2i;
    } else if (c2v > b2v || (c2v == b2v && c2i < b2i)) {
      b2v = c2v; b2i = c2i;
    }
  }
  if (lane == 0) {
    per[c * 2 + 0] = min(max(b1i, 4), 192);
    per[c * 2 + 1] = min(max(b2i, 4), 192);
  }
}

// ---------------- stage C: Mpinv via tridiagonal Thomas ----------------
__global__ __launch_bounds__(256) void build_mpinv_kernel(const int* __restrict__ per,
                                                          float* __restrict__ mp) {
  __shared__ int ii[384];
  __shared__ float ww[384];
  __shared__ float dd_[96], ee[96], cp[96], idt[96];
  __shared__ float ginv[96 * 97];
  __shared__ float outp[96 * 97];
  __shared__ int flag;
  int tid = threadIdx.x;
  int p = (blockIdx.x < 189) ? (4 + (int)blockIdx.x) : 384;
  if (tid == 0) flag = (p == 384) ? 1 : 0;
  __syncthreads();
  if (p != 384) {
    for (int i = tid; i < Cn * 2; i += 256)
      if (per[i] == p) flag = 1;
  }
  __syncthreads();
  if (!flag) return;

  int n = nanch(p);
  int m = (p >= n) ? n : p;
  float* dst = mp + mpoff(p);

  for (int j = tid; j < p; j += 256) {
    int i0, i1; float w;
    irow(j, p, n, i0, i1, w);
    ii[j] = i0; ww[j] = w;
  }
  for (int i = tid; i < m; i += 256) { dd_[i] = 0.f; ee[i] = 0.f; }
  __syncthreads();

  if (p >= n) {
    for (int j = tid; j < p; j += 256) {
      int i0 = ii[j]; float w = ww[j];
      int i1 = min(i0 + 1, n - 1);
      if (i1 == i0) {
        atomicAdd(&dd_[i0], 1.0f);
      } else {
        float a = 1.f - w, b = w;
        atomicAdd(&dd_[i0], a * a);
        atomicAdd(&dd_[i1], b * b);
        atomicAdd(&ee[i0], a * b);
      }
    }
  } else {
    for (int r = tid; r < p; r += 256) {
      int i0 = ii[r]; float w = ww[r];
      int i1 = min(i0 + 1, n - 1);
      float a, b; int c0 = i0, c1 = i1;
      if (i1 == i0) { a = 1.f; b = 0.f; c1 = -1; }
      else { a = 1.f - w; b = w; }
      dd_[r] = a * a + b * b;
      if (r < p - 1) {
        int j0 = ii[r + 1]; float w2 = ww[r + 1];
        int j1 = min(j0 + 1, n - 1);
        float a2, b2; int d0 = j0, d1 = j1;
        if (j1 == j0) { a2 = 1.f; b2 = 0.f; d1 = -2; }
        else { a2 = 1.f - w2; b2 = w2; }
        float s = 0.f;
        if (c0 == d0) s += a * a2;
        if (c0 == d1) s += a * b2;
        if (c1 == d0) s += b * a2;
        if (c1 == d1) s += b * b2;
        ee[r] = s;
      }
    }
  }
  __syncthreads();
  if (tid == 0) {
    float dt = dd_[0];
    idt[0] = 1.f / dt;
    for (int i = 1; i < m; ++i) {
      float c = ee[i - 1] * idt[i - 1];
      cp[i - 1] = c;
      dt = dd_[i] - ee[i - 1] * c;
      idt[i] = 1.f / dt;
    }
  }
  __syncthreads();
  if (tid < m) {
    int j = tid;
    float z = 1.f;
    ginv[j * 97 + j] = 1.f;
    for (int i = j + 1; i < m; ++i) {
      z = -cp[i - 1] * z;
      ginv[i * 97 + j] = z;
    }
    float xn = ginv[(m - 1) * 97 + j] * idt[m - 1];
    ginv[(m - 1) * 97 + j] = xn;
    for (int i = m - 2; i >= 0; --i) {
      float zi = (i >= j) ? ginv[i * 97 + j] : 0.f;
      xn = zi * idt[i] - cp[i] * xn;
      ginv[i * 97 + j] = xn;
    }
  }
  __syncthreads();
  if (p >= n) {
    for (int idx = tid; idx < p * n; idx += 256) {
      int t = idx / n, k = idx - t * n;
      int i0 = ii[t]; float w = ww[t];
      int i1 = min(i0 + 1, n - 1);
      dst[idx] = (1.f - w) * ginv[i0 * 97 + k] + w * ginv[i1 * 97 + k];
    }
  } else {
    for (int t = tid; t < p; t += 256) {
      for (int k = 0; k < n; ++k) outp[t * 97 + k] = 0.f;
      for (int j = 0; j < p; ++j) {
        float hv = ginv[t * 97 + j];
        int i0 = ii[j]; float w = ww[j];
        int i1 = min(i0 + 1, n - 1);
        outp[t * 97 + i0] += hv * (1.f - w);
        outp[t * 97 + i1] += hv * w;
      }
    }
    __syncthreads();
    for (int idx = tid; idx < p * n; idx += 256) {
      int t = idx / n, k = idx - t * n;
      dst[idx] = outp[t * 97 + k];
    }
  }
}

// ---------------- stage P1: anchors^T -> at_tab (192x512, pad zeroed) ----------------
__global__ __launch_bounds__(256) void at_kernel(const float* __restrict__ a12,
                                                 const float* __restrict__ a24,
                                                 const float* __restrict__ a48,
                                                 const float* __restrict__ a96,
                                                 float* __restrict__ at_tab) {
  __shared__ float tile[64 * 97];
  int bid = blockIdx.x;
  int a = bid >> 3, d0 = (bid & 7) * 64;
  int n = (a == 0) ? 12 : (a == 1) ? 24 : (a == 2) ? 48 : 96;
  const float* src = (a == 0) ? a12 : (a == 1) ? a24 : (a == 2) ? a48 : a96;
  float* dst = at_tab + (long)apre(n) * 512;
  int tid = threadIdx.x;
  for (int i = tid; i < 64 * n; i += 256) {
    int dd = i / n, k = i - dd * n;
    tile[dd * 97 + k] = src[(long)(d0 + dd) * n + (long)k];
  }
  __syncthreads();
  for (int i = tid; i < n * 64; i += 256) {
    int k = i >> 6, dd = i & 63;
    dst[(long)k * 512 + d0 + dd] = tile[dd * 97 + k];
  }
  if (bid == 0) {
    for (int i = tid; i < 12 * 512; i += 256) at_tab[180L * 512 + i] = 0.f;
  }
}

// ---------------- stage P3a: qc/kb folds + vb scratch ----------------
__global__ __launch_bounds__(256) void constsA(const float* __restrict__ i1w,
                                               const float* __restrict__ i1b,
                                               const float* __restrict__ i2w,
                                               const float* __restrict__ i2b,
                                               const float* __restrict__ sb,
                                               float* __restrict__ cons,
                                               float* __restrict__ vbuf) {
  __shared__ float sv[512];
  int bid = blockIdx.x;
  int s = bid / 96, r0 = (bid % 96) * 16;
  const float* inw = s ? i2w : i1w;
  const float* inb = s ? i2b : i1b;
  int tid = threadIdx.x;
  for (int i = tid; i < 512; i += 256) sv[i] = sb[i];
  __syncthreads();
  int lane = tid & 63, w = tid >> 6;
  for (int rr = 0; rr < 4; ++rr) {
    int r = r0 + w * 4 + rr;
    const float* row = inw + (long)r * 512;
    float part = 0.f;
    for (int kk = 0; kk < 8; ++kk) part += row[lane + 64 * kk] * sv[lane + 64 * kk];
    for (int off = 32; off > 0; off >>= 1) part += __shfl_down(part, off, 64);
    if (lane == 0) {
      float v = part + inb[r];
      if (r < 1024) cons[s * 1536 + r] = v;
      else vbuf[s * 512 + (r - 1024)] = v;
    }
  }
}

// ---------------- stage P3b: oc = out_w @ vb + outb ----------------
__global__ __launch_bounds__(256) void constsB(const float* __restrict__ o1w,
                                               const float* __restrict__ o1b,
                                               const float* __restrict__ o2w,
                                               const float* __restrict__ o2b,
                                               const float* __restrict__ vbuf,
                                               float* __restrict__ cons) {
  __shared__ float vv[512];
  int bid = blockIdx.x;
  int s = bid / 32, r0 = (bid % 32) * 16;
  const float* outw = s ? o2w : o1w;
  const float* outb = s ? o2b : o1b;
  int tid = threadIdx.x;
  for (int i = tid; i < 512; i += 256) vv[i] = vbuf[s * 512 + i];
  __syncthreads();
  int lane = tid & 63, w = tid >> 6;
  for (int rr = 0; rr < 4; ++rr) {
    int r = r0 + w * 4 + rr;
    const float* row = outw + (long)r * 512;
    float part = 0.f;
    for (int kk = 0; kk < 8; ++kk) part += row[lane + 64 * kk] * vv[lane + 64 * kk];
    for (int off = 32; off > 0; off >>= 1) part += __shfl_down(part, off, 64);
    if (lane == 0) cons[s * 1536 + 1024 + r] = part + outb[r];
  }
}

// ---------------- stage P2: WAfull = in_w @ A_cat (1536x192 per slot) ----------------
__global__ __launch_bounds__(256) void wa_gemm2(const float* __restrict__ iw0,
                                                const float* __restrict__ iw1,
                                                const float* __restrict__ atb,
                                                float* __restrict__ waf,
                                                float* __restrict__ qat,
                                                float* __restrict__ vat) {
  __shared__ float smem[2 * 32 * 68];
  float* As = smem;
  float* Ws = smem + 32 * 68;
  int bid = blockIdx.x;
  int s = bid / 72, r = bid % 72;
  int m0 = (r / 3) * 64, n0 = (r % 3) * 64;
  const float* A = s ? iw1 : iw0;
  float* wafs = waf + (long)s * 294912;
  int tid = threadIdx.x;
  int tm = tid & 15, tn = tid >> 4;
  float acc[4][4];
#pragma unroll
  for (int i = 0; i < 4; ++i)
#pragma unroll
    for (int j = 0; j < 4; ++j) acc[i][j] = 0.f;
  int row = tid >> 3, kc = (tid & 7) * 4;
  for (int k0 = 0; k0 < 512; k0 += 32) {
    float4 v = *(const float4*)&A[(long)(m0 + row) * 512 + k0 + kc];
    As[(kc + 0) * 68 + row] = v.x; As[(kc + 1) * 68 + row] = v.y;
    As[(kc + 2) * 68 + row] = v.z; As[(kc + 3) * 68 + row] = v.w;
    v = *(const float4*)&A[(long)(m0 + row + 32) * 512 + k0 + kc];
    As[(kc + 0) * 68 + row + 32] = v.x; As[(kc + 1) * 68 + row + 32] = v.y;
    As[(kc + 2) * 68 + row + 32] = v.z; As[(kc + 3) * 68 + row + 32] = v.w;
    v = *(const float4*)&atb[(long)(n0 + row) * 512 + k0 + kc];
    Ws[(kc + 0) * 68 + row] = v.x; Ws[(kc + 1) * 68 + row] = v.y;
    Ws[(kc + 2) * 68 + row] = v.z; Ws[(kc + 3) * 68 + row] = v.w;
    v = *(const float4*)&atb[(long)(n0 + row + 32) * 512 + k0 + kc];
    Ws[(kc + 0) * 68 + row + 32] = v.x; Ws[(kc + 1) * 68 + row + 32] = v.y;
    Ws[(kc + 2) * 68 + row + 32] = v.z; Ws[(kc + 3) * 68 + row + 32] = v.w;
    __syncthreads();
    for (int kk = 0; kk < 32; ++kk) {
      float4 a = *(const float4*)&As[kk * 68 + tm * 4];
      float4 w = *(const float4*)&Ws[kk * 68 + tn * 4];
      acc[0][0] += a.x * w.x; acc[0][1] += a.x * w.y; acc[0][2] += a.x * w.z; acc[0][3] += a.x * w.w;
      acc[1][0] += a.y * w.x; acc[1][1] += a.y * w.y; acc[1][2] += a.y * w.z; acc[1][3] += a.y * w.w;
      acc[2][0] += a.z * w.x; acc[2][1] += a.z * w.y; acc[2][2] += a.z * w.z; acc[2][3] += a.z * w.w;
      acc[3][0] += a.w * w.x; acc[3][1] += a.w * w.y; acc[3][2] += a.w * w.z; acc[3][3] += a.w * w.w;
    }
    __syncthreads();
  }
#pragma unroll
  for (int mi = 0; mi < 4; ++mi) {
    float4 o;
    o.x = acc[mi][0]; o.y = acc[mi][1]; o.z = acc[mi][2]; o.w = acc[mi][3];
    *(float4*)&wafs[(long)(m0 + tm * 4 + mi) * 192 + n0 + tn * 4] = o;
  }
  if (m0 < 512 || m0 >= 1024) {
    float* Ct = smem;
#pragma unroll
    for (int mi = 0; mi < 4; ++mi)
#pragma unroll
      for (int j = 0; j < 4; ++j)
        Ct[(tn * 4 + j) * 65 + tm * 4 + mi] = acc[mi][j];
    __syncthreads();
    float* dst = ((m0 < 512) ? qat : vat) + (long)s * 98304;
    int mr = m0 & 511;
    for (int i = tid; i < 64 * 64; i += 256) {
      int cc = i >> 6, rr = i & 63;
      dst[(long)(n0 + cc) * 512 + mr + rr] = Ct[cc * 65 + rr];
    }
  }
}

// ---------------- stage P5: MT per (slot,h): 192x192, K=128 ----------------
__global__ __launch_bounds__(256) void mt_gemm(const float* __restrict__ qat,
                                               const float* __restrict__ waf,
                                               float* __restrict__ mt) {
  __shared__ float As[32 * 68];
  __shared__ float Ws[32 * 68];
  int bid = blockIdx.x;
  int s4h = bid / 9, t = bid % 9;
  int s = s4h >> 2, h = s4h & 3;
  int m0 = (t / 3) * 64, n0 = (t % 3) * 64;
  const float* A = qat + (long)s * 98304 + h * 128;
  const float* B = waf + (long)s * 294912 + 98304 + (long)(h * 128) * 192;
  float* C = mt + (long)s4h * 36864;
  int tid = threadIdx.x;
  int tm = tid & 15, tn = tid >> 4;
  float acc[4][4];
#pragma unroll
  for (int i = 0; i < 4; ++i)
#pragma unroll
    for (int j = 0; j < 4; ++j) acc[i][j] = 0.f;
  int row = tid >> 3, kc = (tid & 7) * 4;
  for (int k0 = 0; k0 < 128; k0 += 32) {
    float4 v = *(const float4*)&A[(long)(m0 + row) * 512 + k0 + kc];
    As[(kc + 0) * 68 + row] = v.x; As[(kc + 1) * 68 + row] = v.y;
    As[(kc + 2) * 68 + row] = v.z; As[(kc + 3) * 68 + row] = v.w;
    v = *(const float4*)&A[(long)(m0 + row + 32) * 512 + k0 + kc];
    As[(kc + 0) * 68 + row + 32] = v.x; As[(kc + 1) * 68 + row + 32] = v.y;
    As[(kc + 2) * 68 + row + 32] = v.z; As[(kc + 3) * 68 + row + 32] = v.w;
    for (int l = tid; l < 512; l += 256) {
      int i = l >> 4, kq = (l & 15) * 4;
      float4 b = *(const float4*)&B[(long)(k0 + i) * 192 + n0 + kq];
      Ws[i * 68 + kq + 0] = b.x; Ws[i * 68 + kq + 1] = b.y;
      Ws[i * 68 + kq + 2] = b.z; Ws[i * 68 + kq + 3] = b.w;
    }
    __syncthreads();
    for (int kk = 0; kk < 32; ++kk) {
      float4 a = *(const float4*)&As[kk * 68 + tm * 4];
      float4 w = *(const float4*)&Ws[kk * 68 + tn * 4];
      acc[0][0] += a.x * w.x; acc[0][1] += a.x * w.y; acc[0][2] += a.x * w.z; acc[0][3] += a.x * w.w;
      acc[1][0] += a.y * w.x; acc[1][1] += a.y * w.y; acc[1][2] += a.y * w.z; acc[1][3] += a.y * w.w;
      acc[2][0] += a.z * w.x; acc[2][1] += a.z * w.y; acc[2][2] += a.z * w.z; acc[2][3] += a.z * w.w;
      acc[3][0] += a.w * w.x; acc[3][1] += a.w * w.y; acc[3][2] += a.w * w.z; acc[3][3] += a.w * w.w;
    }
    __syncthreads();
  }
#pragma unroll
  for (int mi = 0; mi < 4; ++mi) {
    float4 o;
    o.x = acc[mi][0]; o.y = acc[mi][1]; o.z = acc[mi][2]; o.w = acc[mi][3];
    *(float4*)&C[(long)(m0 + tm * 4 + mi) * 192 + n0 + tn * 4] = o;
  }
}

// ---------------- stage P6: d/e/f score constants per (slot,h) ----------------
__global__ __launch_bounds__(256) void scoreconsts(const float* __restrict__ qat,
                                                   const float* __restrict__ waf,
                                                   const float* __restrict__ cons,
                                                   float* __restrict__ def) {
  __shared__ float qcl[128];
  __shared__ float kbl[128];
  int bid = blockIdx.x;
  int s = bid >> 2, h = bid & 3;
  int tid = threadIdx.x;
  const float* qc = cons + s * 1536;
  const float* kb = qc + 512;
  if (tid < 128) {
    qcl[tid] = qc[h * 128 + tid];
    kbl[tid] = kb[h * 128 + tid];
  }
  __syncthreads();
  const float* katb = waf + (long)s * 294912 + 98304;
  const float* qats = qat + (long)s * 98304;
  float* dtab = def + (long)(s * 4 + h) * 192;
  float* etab = def + 1536 + (long)(s * 4 + h) * 192;
  float* ftab = def + 3072 + (s * 4 + h);
  if (tid < 192) {
    float acc = 0.f;
    for (int i = 0; i < 128; ++i) acc += katb[(long)(h * 128 + i) * 192 + tid] * qcl[i];
    dtab[tid] = acc;
    float acc2 = 0.f;
    const float* qr = qats + (long)tid * 512 + h * 128;
    for (int i = 0; i < 128; ++i) acc2 += qr[i] * kbl[i];
    etab[tid] = acc2;
  }
  if (tid < 64) {
    float acc = 0.f;
    for (int i = tid; i < 128; i += 64) acc += qcl[i] * kbl[i];
    for (int off = 32; off > 0; off >>= 1) acc += __shfl_down(acc, off, 64);
    if (tid == 0) *ftab = acc;
  }
}

// ---------------- stage P4: OVA^T per (slot,head) ----------------
__global__ __launch_bounds__(256) void ova_gemm2(const float* __restrict__ ow0,
                                                 const float* __restrict__ ow1,
                                                 const float* __restrict__ vat,
                                                 float* __restrict__ ovt) {
  __shared__ float As[32 * 68];
  __shared__ float Ws[32 * 68];
  int bid = blockIdx.x;
  int s = bid / 96, r = bid % 96;
  int h = r / 24, r2 = r % 24;
  int m0 = (r2 / 8) * 64, n0 = (r2 % 8) * 64;
  const float* A = vat + (long)s * 98304 + h * 128;
  const float* W = (s ? ow1 : ow0) + h * 128;
  float* C = ovt + ((long)(s * 4 + h) * 192) * 512;
  int tid = threadIdx.x;
  int tm = tid & 15, tn = tid >> 4;
  float acc[4][4];
#pragma unroll
  for (int i = 0; i < 4; ++i)
#pragma unroll
    for (int j = 0; j < 4; ++j) acc[i][j] = 0.f;
  int row = tid >> 3, kc = (tid & 7) * 4;
  for (int k0 = 0; k0 < 128; k0 += 32) {
    float4 v = *(const float4*)&A[(long)(m0 + row) * 512 + k0 + kc];
    As[(kc + 0) * 68 + row] = v.x; As[(kc + 1) * 68 + row] = v.y;
    As[(kc + 2) * 68 + row] = v.z; As[(kc + 3) * 68 + row] = v.w;
    v = *(const float4*)&A[(long)(m0 + row + 32) * 512 + k0 + kc];
    As[(kc + 0) * 68 + row + 32] = v.x; As[(kc + 1) * 68 + row + 32] = v.y;
    As[(kc + 2) * 68 + row + 32] = v.z; As[(kc + 3) * 68 + row + 32] = v.w;
    v = *(const float4*)&W[(long)(n0 + row) * 512 + k0 + kc];
    Ws[(kc + 0) * 68 + row] = v.x; Ws[(kc + 1) * 68 + row] = v.y;
    Ws[(kc + 2) * 68 + row] = v.z; Ws[(kc + 3) * 68 + row] = v.w;
    v = *(const float4*)&W[(long)(n0 + row + 32) * 512 + k0 + kc];
    Ws[(kc + 0) * 68 + row + 32] = v.x; Ws[(kc + 1) * 68 + row + 32] = v.y;
    Ws[(kc + 2) * 68 + row + 32] = v.z; Ws[(kc + 3) * 68 + row + 32] = v.w;
    __syncthreads();
    for (int kk = 0; kk < 32; ++kk) {
      float4 a = *(const float4*)&As[kk * 68 + tm * 4];
      float4 w = *(const float4*)&Ws[kk * 68 + tn * 4];
      acc[0][0] += a.x * w.x; acc[0][1] += a.x * w.y; acc[0][2] += a.x * w.z; acc[0][3] += a.x * w.w;
      acc[1][0] += a.y * w.x; acc[1][1] += a.y * w.y; acc[1][2] += a.y * w.z; acc[1][3] += a.y * w.w;
      acc[2][0] += a.z * w.x; acc[2][1] += a.z * w.y; acc[2][2] += a.z * w.z; acc[2][3] += a.z * w.w;
      acc[3][0] += a.w * w.x; acc[3][1] += a.w * w.y; acc[3][2] += a.w * w.z; acc[3][3] += a.w * w.w;
    }
    __syncthreads();
  }
#pragma unroll
  for (int mi = 0; mi < 4; ++mi) {
    float4 o;
    o.x = acc[mi][0]; o.y = acc[mi][1]; o.z = acc[mi][2]; o.w = acc[mi][3];
    *(float4*)&C[(long)(m0 + tm * 4 + mi) * 512 + n0 + tn * 4] = o;
  }
}

// ---------------- stage B: fused attention, G=8 batches/block, folded scores ----------------
__global__ __launch_bounds__(256) void attn_kernel(
    const float* __restrict__ xT, const int* __restrict__ per,
    const float* __restrict__ mp, const float* __restrict__ mt,
    const float* __restrict__ def, const float* __restrict__ ovt,
    const float* __restrict__ cons, const float* __restrict__ at_tab,
    const float* __restrict__ sb,
    const float* __restrict__ l1g, const float* __restrict__ l1b,
    const float* __restrict__ l2g, const float* __restrict__ l2b,
    float* __restrict__ comb) {
  __shared__ float xb[8 * 384];
  __shared__ float Z[8 * 1248];
  __shared__ float zl[8 * 96];
  __shared__ float arb[8 * 384];
  __shared__ float qkc[32];
  __shared__ float red[4 * 16];
  __shared__ float stats[16];
  float* scp = xb;

  int tid = threadIdx.x;
  int bid = blockIdx.x;
  int slot = bid & 1;
  int c = (bid >> 1) & 127;
  int b0 = (bid >> 8) * 8;
  int p = per[c * 2 + slot];
  int n = nanch(p);
  int np = Tn / p;
  int n1 = n + 1;
  float s = sqrtf((float)p / (float)n);
  float s2 = s * s;
  const float rscale = 0.08838834764831845f;
  int pre = apre(n);
  const float* mpp = mp + mpoff(p);
  const float* atb = at_tab + (long)pre * 512;
  const float* oc = cons + slot * 1536 + 1024;
  const float* lng = slot ? l2g : l1g;
  const float* lnb = slot ? l2b : l1b;
  const float* dt = def + (long)(slot * 4) * 192;
  const float* et = def + 1536 + (long)(slot * 4) * 192;
  const float* ft = def + 3072 + slot * 4;
  const float* mtb = mt + (long)(slot * 4) * 36864;

  for (int g = 0; g < 8; ++g)
    for (int t = tid; t < Tn; t += 256)
      xb[g * 384 + t] = xT[((long)c * Bn + b0 + g) * Tn + t];
  __syncthreads();

  int znp = np * n;
  for (int idx = tid; idx < znp; idx += 256) {
    int j = idx / n, k = idx - j * n;
    int jb = j * p;
    const float* mk = mpp + k;
    float a[8];
#pragma unroll
    for (int g = 0; g < 8; ++g) a[g] = 0.f;
    for (int t = 0; t < p; ++t) {
      float m = mk[(long)t * n];
#pragma unroll
      for (int g = 0; g < 8; ++g) a[g] += m * xb[g * 384 + jb + t];
    }
    int zi = j * n1 + k;
#pragma unroll
    for (int g = 0; g < 8; ++g) Z[g * 1248 + zi] = a[g];
  }
  __syncthreads();

  for (int idx = tid; idx < 8 * n; idx += 256) {
    int g = idx / n, k = idx - g * n;
    zl[g * 96 + k] = Z[g * 1248 + (np - 1) * n1 + k];
  }
  __syncthreads();

  {
    int pair = tid >> 3, l = tid & 7;
    int g = pair >> 2, h = pair & 3;
    const float* eh = et + h * 192 + pre;
    float acc = 0.f;
    for (int j = l; j < n; j += 8) acc += eh[j] * zl[g * 96 + j];
    for (int off = 4; off > 0; off >>= 1) acc += __shfl_down(acc, off, 8);
    if (l == 0) qkc[g * 4 + h] = s * acc + ft[h];
  }
  {
    int tot = 4 * n;
    for (int idx = tid; idx < tot; idx += 256) {
      int h = idx / n, k = idx - h * n;
      const float* mtc = mtb + (long)h * 36864 + (long)pre * 192 + pre + k;
      float a[8];
#pragma unroll
      for (int g = 0; g < 8; ++g) a[g] = 0.f;
      for (int j0 = 0; j0 < n; j0 += 4) {
        float4 zb[8];
#pragma unroll
        for (int g = 0; g < 8; ++g) zb[g] = *(const float4*)&zl[g * 96 + j0];
#pragma unroll
        for (int c4 = 0; c4 < 4; ++c4) {
          float mv = mtc[(long)(j0 + c4) * 192];
#pragma unroll
          for (int g = 0; g < 8; ++g) {
            float zv = (c4 == 0) ? zb[g].x : (c4 == 1) ? zb[g].y : (c4 == 2) ? zb[g].z : zb[g].w;
            a[g] += mv * zv;
          }
        }
      }
      float dv = dt[h * 192 + pre + k];
#pragma unroll
      for (int g = 0; g < 8; ++g) arb[g * 384 + h * 96 + k] = s2 * a[g] + s * dv;
    }
  }
  __syncthreads();

  {
    int fnp = 4 * np;
    int tot = 8 * fnp;
    for (int idx = tid; idx < tot; idx += 256) {
      int g = idx / fnp;
      int r = idx - g * fnp;
      int h = r / np, j = r - h * np;
      const float* ap = arb + g * 384 + h * 96;
      const float* zp = Z + g * 1248 + j * n1;
      float acc = 0.f;
      for (int k = 0; k < n; ++k) acc += ap[k] * zp[k];
      scp[g * 384 + h * np + j] = (acc + qkc[g * 4 + h]) * rscale;
    }
  }
  __syncthreads();

  {
    int pair = tid >> 3, l = tid & 7;
    int g = pair >> 2, h = pair & 3;
    float* sp = scp + g * 384 + h * np;
    float m = -1e30f;
    for (int j = l; j < np; j += 8) m = fmaxf(m, sp[j]);
    for (int off = 4; off > 0; off >>= 1) m = fmaxf(m, __shfl_xor(m, off, 8));
    float lsum = 0.f;
    for (int j = l; j < np; j += 8) { float e = expf(sp[j] - m); sp[j] = e; lsum += e; }
    for (int off = 4; off > 0; off >>= 1) lsum += __shfl_xor(lsum, off, 8);
    float il = 1.f / lsum;
    for (int j = l; j < np; j += 8) sp[j] *= il;
  }
  __syncthreads();

  {
    int fn = 4 * n;
    int tot = 8 * fn;
    for (int idx = tid; idx < tot; idx += 256) {
      int g = idx / fn;
      int r = idx - g * fn;
      int h = r / n, k = r - h * n;
      const float* sp = scp + g * 384 + h * np;
      const float* zp = Z + g * 1248 + k;
      float acc = 0.f;
      for (int j = 0; j < np; ++j) acc += sp[j] * zp[j * n1];
      arb[g * 384 + h * 96 + k] = acc;
    }
  }
  __syncthreads();

  {
    int d0 = 2 * tid;
    float a0[8], a1[8];
#pragma unroll
    for (int g = 0; g < 8; ++g) { a0[g] = 0.f; a1[g] = 0.f; }
    for (int k0 = 0; k0 < n; k0 += 4) {
      float4 zb[8];
#pragma unroll
      for (int g = 0; g < 8; ++g) zb[g] = *(const float4*)&zl[g * 96 + k0];
#pragma unroll
      for (int c4 = 0; c4 < 4; ++c4) {
        float2 w = *(const float2*)&atb[(long)(k0 + c4) * 512 + d0];
#pragma unroll
        for (int g = 0; g < 8; ++g) {
          float zv = (c4 == 0) ? zb[g].x : (c4 == 1) ? zb[g].y : (c4 == 2) ? zb[g].z : zb[g].w;
          a0[g] += w.x * zv; a1[g] += w.y * zv;
        }
      }
    }
    for (int h = 0; h < 4; ++h) {
      const float* op = ovt + ((long)((slot * 4 + h) * 192 + pre)) * 512;
      const float* zhb = arb + h * 96;
      for (int k0 = 0; k0 < n; k0 += 4) {
        float4 zb[8];
#pragma unroll
        for (int g = 0; g < 8; ++g) zb[g] = *(const float4*)&zhb[g * 384 + k0];
#pragma unroll
        for (int c4 = 0; c4 < 4; ++c4) {
          float2 w = *(const float2*)&op[(long)(k0 + c4) * 512 + d0];
#pragma unroll
          for (int g = 0; g < 8; ++g) {
            float zv = (c4 == 0) ? zb[g].x : (c4 == 1) ? zb[g].y : (c4 == 2) ? zb[g].z : zb[g].w;
            a0[g] += w.x * zv; a1[g] += w.y * zv;
          }
        }
      }
    }
    float2 sbv = *(const float2*)&sb[d0];
    float2 ocv = *(const float2*)&oc[d0];
    float s0 = sbv.x + ocv.x, s1v = sbv.y + ocv.y;
#pragma unroll
    for (int g = 0; g < 8; ++g) { a0[g] = s * a0[g] + s0; a1[g] = s * a1[g] + s1v; }
    float ps[16];
#pragma unroll
    for (int g = 0; g < 8; ++g) {
      ps[2 * g] = a0[g] + a1[g];
      ps[2 * g + 1] = a0[g] * a0[g] + a1[g] * a1[g];
    }
    int w = tid >> 6, lane = tid & 63;
    for (int off = 32; off > 0; off >>= 1) {
#pragma unroll
      for (int i = 0; i < 16; ++i) ps[i] += __shfl_down(ps[i], off, 64);
    }
    if (lane == 0) {
#pragma unroll
      for (int i = 0; i < 16; ++i) red[w * 16 + i] = ps[i];
    }
    __syncthreads();
    if (tid < 8) {
      int g = tid;
      float ssum = red[2 * g] + red[16 + 2 * g] + red[32 + 2 * g] + red[48 + 2 * g];
      float qsum = red[2 * g + 1] + red[16 + 2 * g + 1] + red[32 + 2 * g + 1] + red[48 + 2 * g + 1];
      float mu = ssum / 512.f;
      float var = qsum / 512.f - mu * mu;
      stats[g * 2] = mu;
      stats[g * 2 + 1] = rsqrtf(var + 1e-5f);
    }
    __syncthreads();
    float2 gv = *(const float2*)&lng[d0];
    float2 bv = *(const float2*)&lnb[d0];
#pragma unroll
    for (int g = 0; g < 8; ++g) {
      float mu = stats[g * 2], rstd = stats[g * 2 + 1];
      long base = ((long)(b0 + g) * Cn + c) * 1536 + slot * 512;
      float2 o;
      o.x = (a0[g] - mu) * rstd * gv.x + bv.x;
      o.y = (a1[g] - mu) * rstd * gv.y + bv.y;
      *(float2*)&comb[base + d0] = o;
    }
  }
}

// ---------------- stage D: trend ----------------
__global__ __launch_bounds__(256) void trend_kernel(const float* __restrict__ xT,
                                                    const float* __restrict__ mp384,
                                                    const float* __restrict__ at96,
                                                    const float* __restrict__ sb,
                                                    float* __restrict__ comb) {
  __shared__ float xb[Bn * Tn];
  __shared__ float Ztr[Bn * 97];
  int c = blockIdx.x, tid = threadIdx.x;
  for (int i = tid; i < Bn * Tn; i += 256) xb[i] = xT[(long)c * Bn * Tn + i];
  __syncthreads();
  for (int idx = tid; idx < 4 * 96; idx += 256) {
    int bq = idx / 96, k = idx - bq * 96;
    const float* x0 = xb + (bq * 4 + 0) * Tn;
    const float* x1 = xb + (bq * 4 + 1) * Tn;
    const float* x2 = xb + (bq * 4 + 2) * Tn;
    const float* x3 = xb + (bq * 4 + 3) * Tn;
    const float* mk = mp384 + k;
    float a0 = 0.f, a1 = 0.f, a2 = 0.f, a3 = 0.f;
    for (int t = 0; t < Tn; ++t) {
      float m = mk[(long)t * 96];
      a0 += m * x0[t]; a1 += m * x1[t]; a2 += m * x2[t]; a3 += m * x3[t];
    }
    Ztr[(bq * 4 + 0) * 97 + k] = a0;
    Ztr[(bq * 4 + 1) * 97 + k] = a1;
    Ztr[(bq * 4 + 2) * 97 + k] = a2;
    Ztr[(bq * 4 + 3) * 97 + k] = a3;
  }
  __syncthreads();
  float acc0[Bn], acc1[Bn];
#pragma unroll
  for (int b = 0; b < Bn; ++b) { acc0[b] = 0.f; acc1[b] = 0.f; }
  for (int k = 0; k < 96; ++k) {
    float w0 = at96[(long)k * 512 + tid];
    float w1 = at96[(long)k * 512 + 256 + tid];
#pragma unroll
    for (int b = 0; b < Bn; ++b) {
      float z = Ztr[b * 97 + k];
      acc0[b] += w0 * z;
      acc1[b] += w1 * z;
    }
  }
  float s0 = sb[tid], s1 = sb[256 + tid];
#pragma unroll
  for (int b = 0; b < Bn; ++b) {
    long base = ((long)b * Cn + c) * 1536 + 1024;
    comb[base + tid] = 2.f * acc0[b] + s0;
    comb[base + 256 + tid] = 2.f * acc1[b] + s1;
  }
}

// ---------------- stage E: fusion GEMM ----------------
template <bool GELU>
__global__ __launch_bounds__(256) void fused_gemm(const float* __restrict__ A,
                                                  const float* __restrict__ W,
                                                  const float* __restrict__ bias,
                                                  float* __restrict__ C,
                                                  int N, int K) {
  __shared__ float As[32 * 68];
  __shared__ float Ws[32 * 68];
  int nb = N >> 6;
  int m0 = (blockIdx.x / nb) * 64, n0 = (blockIdx.x % nb) * 64;
  int tid = threadIdx.x;
  int tm = tid & 15, tn = tid >> 4;
  float acc[4][4];
#pragma unroll
  for (int i = 0; i < 4; ++i)
#pragma unroll
    for (int j = 0; j < 4; ++j) acc[i][j] = 0.f;
  int row = tid >> 3, kc = (tid & 7) * 4;
  for (int k0 = 0; k0 < K; k0 += 32) {
    {
      float4 v = *(const float4*)&A[(long)(m0 + row) * K + k0 + kc];
      As[(kc + 0) * 68 + row] = v.x; As[(kc + 1) * 68 + row] = v.y;
      As[(kc + 2) * 68 + row] = v.z; As[(kc + 3) * 68 + row] = v.w;
      v = *(const float4*)&A[(long)(m0 + row + 32) * K + k0 + kc];
      As[(kc + 0) * 68 + row + 32] = v.x; As[(kc + 1) * 68 + row + 32] = v.y;
      As[(kc + 2) * 68 + row + 32] = v.z; As[(kc + 3) * 68 + row + 32] = v.w;
      v = *(const float4*)&W[(long)(n0 + row) * K + k0 + kc];
      Ws[(kc + 0) * 68 + row] = v.x; Ws[(kc + 1) * 68 + row] = v.y;
      Ws[(kc + 2) * 68 + row] = v.z; Ws[(kc + 3) * 68 + row] = v.w;
      v = *(const float4*)&W[(long)(n0 + row + 32) * K + k0 + kc];
      Ws[(kc + 0) * 68 + row + 32] = v.x; Ws[(kc + 1) * 68 + row + 32] = v.y;
      Ws[(kc + 2) * 68 + row + 32] = v.z; Ws[(kc + 3) * 68 + row + 32] = v.w;
    }
    __syncthreads();
    for (int kk = 0; kk < 32; ++kk) {
      float4 a = *(const float4*)&As[kk * 68 + tm * 4];
      float4 w = *(const float4*)&Ws[kk * 68 + tn * 4];
      acc[0][0] += a.x * w.x; acc[0][1] += a.x * w.y; acc[0][2] += a.x * w.z; acc[0][3] += a.x * w.w;
      acc[1][0] += a.y * w.x; acc[1][1] += a.y * w.y; acc[1][2] += a.y * w.z; acc[1][3] += a.y * w.w;
      acc[2][0] += a.z * w.x; acc[2][1] += a.z * w.y; acc[2][2] += a.z * w.z; acc[2][3] += a.z * w.w;
      acc[3][0] += a.w * w.x; acc[3][1] += a.w * w.y; acc[3][2] += a.w * w.z; acc[3][3] += a.w * w.w;
    }
    __syncthreads();
  }
  float b0v = bias[n0 + tn * 4 + 0], b1v = bias[n0 + tn * 4 + 1];
  float b2v = bias[n0 + tn * 4 + 2], b3v = bias[n0 + tn * 4 + 3];
#pragma unroll
  for (int mi = 0; mi < 4; ++mi) {
    float4 o;
    o.x = acc[mi][0] + b0v; o.y = acc[mi][1] + b1v;
    o.z = acc[mi][2] + b2v; o.w = acc[mi][3] + b3v;
    if (GELU) {
      o.x = 0.5f * o.x * (1.f + erff(o.x * 0.7071067811865475f));
      o.y = 0.5f * o.y * (1.f + erff(o.y * 0.7071067811865475f));
      o.z = 0.5f * o.z * (1.f + erff(o.z * 0.7071067811865475f));
      o.w = 0.5f * o.w * (1.f + erff(o.w * 0.7071067811865475f));
    }
    *(float4*)&C[(long)(m0 + tm * 4 + mi) * N + n0 + tn * 4] = o;
  }
}

extern "C" void kernel_launch(void* const* d_in, const int* in_sizes, int n_in,
                              void* d_out, int out_size, void* d_ws, size_t ws_size,
                              hipStream_t stream) {
  const float* x    = (const float*)d_in[0];
  const float* a12  = (const float*)d_in[1];
  const float* a24  = (const float*)d_in[2];
  const float* a48  = (const float*)d_in[3];
  const float* a96  = (const float*)d_in[4];
  const float* sb   = (const float*)d_in[5];
  const float* g1iw = (const float*)d_in[6];
  const float* g1ib = (const float*)d_in[7];
  const float* g1ow = (const float*)d_in[8];
  const float* g1ob = (const float*)d_in[9];
  const float* g1lg = (const float*)d_in[10];
  const float* g1lb = (const float*)d_in[11];
  const float* g2iw = (const float*)d_in[12];
  const float* g2ib = (const float*)d_in[13];
  const float* g2ow = (const float*)d_in[14];
  const float* g2ob = (const float*)d_in[15];
  const float* g2lg = (const float*)d_in[16];
  const float* g2lb = (const float*)d_in[17];
  const float* fw1  = (const float*)d_in[18];
  const float* fb1  = (const float*)d_in[19];
  const float* fw2  = (const float*)d_in[20];
  const float* fb2  = (const float*)d_in[21];

  if (ws_size < (size_t)WS_FLOATS * sizeof(float)) return;

  float* ws   = (float*)d_ws;
  float* xT   = ws + OFF_XT;
  float* avg  = ws + OFF_AVG;
  int*   per  = (int*)(ws + OFF_PER);
  float* mp   = ws + OFF_MP;
  float* atb  = ws + OFF_AT;
  float* waf  = ws + OFF_WAF;
  float* qat  = ws + OFF_QAT;
  float* vat  = ws + OFF_VAT;
  float* ovt  = ws + OFF_OVT;
  float* cons = ws + OFF_CON;
  float* vbuf = ws + OFF_VB;
  float* mtab = ws + OFF_MT;
  float* def  = ws + OFF_DEF;
  float* comb = ws + OFF_COMB;
  float* hbuf = ws + OFF_H;
  float* out  = (float*)d_out;

  transpose_kernel<<<192, 256, 0, stream>>>(x, xT);
  acf_kernel<<<Cn * 6, 256, 0, stream>>>(xT, avg);
  periods_kernel<<<32, 256, 0, stream>>>(avg, per);
  build_mpinv_kernel<<<190, 256, 0, stream>>>(per, mp);
  at_kernel<<<32, 256, 0, stream>>>(a12, a24, a48, a96, atb);
  constsA<<<192, 256, 0, stream>>>(g1iw, g1ib, g2iw, g2ib, sb, cons, vbuf);
  constsB<<<64, 256, 0, stream>>>(g1ow, g1ob, g2ow, g2ob, vbuf, cons);
  wa_gemm2<<<144, 256, 0, stream>>>(g1iw, g2iw, atb, waf, qat, vat);
  mt_gemm<<<72, 256, 0, stream>>>(qat, waf, mtab);
  scoreconsts<<<8, 256, 0, stream>>>(qat, waf, cons, def);
  ova_gemm2<<<192, 256, 0, stream>>>(g1ow, g2ow, vat, ovt);

  attn_kernel<<<512, 256, 0, stream>>>(xT, per, mp, mtab, def, ovt, cons, atb, sb,
                                       g1lg, g1lb, g2lg, g2lb, comb);
  trend_kernel<<<Cn, 256, 0, stream>>>(xT, mp + 1634436L, atb + 84L * 512, sb, comb);
  fused_gemm<true><<<256, 256, 0, stream>>>(comb, fw1, fb1, hbuf, 512, 1536);
  fused_gemm<false><<<256, 256, 0, stream>>>(hbuf, fw2, fb2, out, 512, 512);
}

// Round 9
// 440.706 us; speedup vs baseline: 17.8881x; 1.0144x over previous
//
#include <hip/hip_runtime.h>
#include <math.h>

#define Bn 16
#define Tn 384
#define Cn 128

// ---------------- workspace layout (floats) ----------------
static constexpr long OFF_XT   = 0;         // 786432
static constexpr long OFF_AVG  = 786432;    // 49152 (channel-major: [c][t])
static constexpr long OFF_PER  = 835584;    // 256 ints
static constexpr long OFF_MP   = 835840;    // 1671300
static constexpr long OFF_AT   = 2507140;   // 98304
static constexpr long OFF_WAF  = 2605444;   // 589824
static constexpr long OFF_QAT  = 3195268;   // 196608
static constexpr long OFF_VAT  = 3391876;   // 196608
static constexpr long OFF_OVT  = 3588484;   // 786432
static constexpr long OFF_CON  = 4374916;   // 3072
static constexpr long OFF_VB   = 4377988;   // 1024
static constexpr long OFF_MT   = 4379012;   // 294912
static constexpr long OFF_DEF  = 4673924;   // 3080
static constexpr long OFF_ZC   = 4677004;   // 4096*480 = 1966080
static constexpr long OFF_COMB = 6643084;   // 3145728
static constexpr long OFF_H    = 9788812;   // 1048576
static constexpr long OFF_H2   = 10837388;  // 1048576
static constexpr long WS_FLOATS = 11885964; // ~47.5 MB

__host__ __device__ inline int nanch(int p) {
  if (p == 384) return 96;
  return (p <= 18) ? 12 : (p <= 36) ? 24 : (p <= 72) ? 48 : 96;
}
__host__ __device__ inline int apre(int n) {
  return (n == 12) ? 0 : (n == 24) ? 12 : (n == 48) ? 36 : 84;
}
__host__ __device__ inline long mpoff(int p) {
  if (p == 384) return 1634436L;
  long T = (long)(p - 1) * p / 2;
  if (p <= 18) return 12 * (T - 6);
  if (p <= 36) return 1980 + 24 * (T - 171);
  if (p <= 72) return 13860 + 48 * (T - 666);
  return 108036 + 96 * (T - 2628);
}

__device__ inline void irow(int j, int newl, int oldl, int& i0, int& i1, float& w) {
  double src = ((double)j + 0.5) * (double)oldl / (double)newl - 0.5;
  if (src < 0.0) src = 0.0;
  double mx = (double)(oldl - 1);
  if (src > mx) src = mx;
  int a = (int)src;
  if (a > oldl - 1) a = oldl - 1;
  i0 = a;
  i1 = (a + 1 < oldl) ? (a + 1) : (oldl - 1);
  w = (float)(src - (double)a);
}

// ---------------- stage 0: transpose x -> xT[c][b][t] ----------------
__global__ __launch_bounds__(256) void transpose_kernel(const float* __restrict__ x,
                                                        float* __restrict__ xT) {
  __shared__ float tile[32 * 129];
  int bid = blockIdx.x;
  int b = bid / 12, t0 = (bid % 12) * 32;
  int tid = threadIdx.x;
  for (int i = tid; i < 32 * 128; i += 256) {
    int tt = i >> 7, cc = i & 127;
    tile[tt * 129 + cc] = x[((long)b * Tn + t0 + tt) * Cn + cc];
  }
  __syncthreads();
  for (int i = tid; i < 32 * 128; i += 256) {
    int cc = i >> 5, tt = i & 31;
    xT[((long)cc * Bn + b) * Tn + t0 + tt] = tile[tt * 129 + cc];
  }
}

// ---------------- stage A1: ACF (writes avg[c][t]) ----------------
__global__ __launch_bounds__(256) void acf_kernel(const float* __restrict__ xT,
                                                  float* __restrict__ avg) {
  __shared__ float xb[Bn * 397];
  __shared__ float mean[Bn];
  int bid = blockIdx.x;
  int c = bid / 6, tile = bid % 6;
  int tid = threadIdx.x;
  for (int i = tid; i < Bn * Tn; i += 256) {
    int b = i / Tn, t = i - b * Tn;
    xb[b * 397 + t] = xT[(long)c * Bn * Tn + i];
  }
  for (int i = tid; i < Bn * 13; i += 256) {
    int b = i / 13, t = Tn + (i - b * 13);
    xb[b * 397 + t] = 0.f;
  }
  __syncthreads();
  if (tid < Bn) {
    float s = 0.f;
    for (int t = 0; t < Tn; ++t) s += xb[tid * 397 + t];
    mean[tid] = s / (float)Tn;
  }
  __syncthreads();
  for (int i = tid; i < Bn * Tn; i += 256) {
    int b = i / Tn, t = i - b * Tn;
    xb[b * 397 + t] -= mean[b];
  }
  __syncthreads();
  int q = tid >> 4;
  int g = tid & 15;
  int tau0 = tile * 64 + q * 4;
  const float* xr = xb + g * 397;
  float a0 = 0.f, a1 = 0.f, a2 = 0.f, a3 = 0.f;
  float w0 = xr[tau0], w1 = xr[tau0 + 1], w2 = xr[tau0 + 2], w3 = xr[tau0 + 3];
  int tmax = Tn - tau0;
  for (int t = 0; t < tmax; ++t) {
    float a = xr[t];
    float wn = xr[t + tau0 + 4];
    a0 += a * w0; a1 += a * w1; a2 += a * w2; a3 += a * w3;
    w0 = w1; w1 = w2; w2 = w3; w3 = wn;
  }
  for (int off = 8; off > 0; off >>= 1) {
    a0 += __shfl_down(a0, off, 16);
    a1 += __shfl_down(a1, off, 16);
    a2 += __shfl_down(a2, off, 16);
    a3 += __shfl_down(a3, off, 16);
  }
  if (g == 0) {
    float* dst = avg + (long)c * Tn + tau0;
    dst[0] = a0; dst[1] = a1; dst[2] = a2; dst[3] = a3;
  }
}

// ---------------- stage A2: peaks ----------------
__global__ __launch_bounds__(256) void periods_kernel(const float* __restrict__ avg,
                                                      int* __restrict__ per) {
  int wv = threadIdx.x >> 6;
  int lane = threadIdx.x & 63;
  int c = blockIdx.x * 4 + wv;
  const float* a = avg + (long)c * Tn;
  const float NEG = -1e30f;
  float b1v = NEG, b2v = NEG;
  int b1i = 0, b2i = 0;
  int t0 = 4 + lane * 6;
#pragma unroll
  for (int i = 0; i < 6; ++i) {
    int t = t0 + i;
    if (t > Tn - 1) break;
    float v = a[t];
    float pv = (t == 4) ? NEG : a[t - 1];
    float nv = (t == Tn - 1) ? NEG : a[t + 1];
    bool peak = (v > pv) && (v > nv) && (v > 0.f);
    float m = peak ? v : NEG;
    if (m > b1v || (m == b1v && t < b1i)) {
      b2v = b1v; b2i = b1i; b1v = m; b1i = t;
    } else if (m > b2v || (m == b2v && t < b2i)) {
      b2v = m; b2i = t;
    }
  }
  for (int off = 32; off > 0; off >>= 1) {
    float c1v = __shfl_down(b1v, off, 64); int c1i = __shfl_down(b1i, off, 64);
    float c2v = __shfl_down(b2v, off, 64); int c2i = __shfl_down(b2i, off, 64);
    if (c1v > b1v || (c1v == b1v && c1i < b1i)) {
      b2v = b1v; b2i = b1i; b1v = c1v; b1i = c1i;
    } else if (c1v > b2v || (c1v == b2v && c1i < b2i)) {
      b2v = c1v; b2i = c1i;
    }
    if (c2v > b1v || (c2v == b1v && c2i < b1i)) {
      b2v = b1v; b2i = b1i; b1v = c2v; b1i = c2i;
    } else if (c2v > b2v || (c2v == b2v && c2i < b2i)) {
      b2v = c2v; b2i = c2i;
    }
  }
  if (lane == 0) {
    per[c * 2 + 0] = min(max(b1i, 4), 192);
    per[c * 2 + 1] = min(max(b2i, 4), 192);
  }
}

// ---------------- stage C: Mpinv via tridiagonal Thomas ----------------
__global__ __launch_bounds__(256) void build_mpinv_kernel(const int* __restrict__ per,
                                                          float* __restrict__ mp) {
  __shared__ int ii[384];
  __shared__ float ww[384];
  __shared__ float dd_[96], ee[96], cp[96], idt[96];
  __shared__ float ginv[96 * 97];
  __shared__ float outp[96 * 97];
  __shared__ int flag;
  int tid = threadIdx.x;
  int p = (blockIdx.x < 189) ? (4 + (int)blockIdx.x) : 384;
  if (tid == 0) flag = (p == 384) ? 1 : 0;
  __syncthreads();
  if (p != 384) {
    for (int i = tid; i < Cn * 2; i += 256)
      if (per[i] == p) flag = 1;
  }
  __syncthreads();
  if (!flag) return;

  int n = nanch(p);
  int m = (p >= n) ? n : p;
  float* dst = mp + mpoff(p);

  for (int j = tid; j < p; j += 256) {
    int i0, i1; float w;
    irow(j, p, n, i0, i1, w);
    ii[j] = i0; ww[j] = w;
  }
  for (int i = tid; i < m; i += 256) { dd_[i] = 0.f; ee[i] = 0.f; }
  __syncthreads();

  if (p >= n) {
    for (int j = tid; j < p; j += 256) {
      int i0 = ii[j]; float w = ww[j];
      int i1 = min(i0 + 1, n - 1);
      if (i1 == i0) {
        atomicAdd(&dd_[i0], 1.0f);
      } else {
        float a = 1.f - w, b = w;
        atomicAdd(&dd_[i0], a * a);
        atomicAdd(&dd_[i1], b * b);
        atomicAdd(&ee[i0], a * b);
      }
    }
  } else {
    for (int r = tid; r < p; r += 256) {
      int i0 = ii[r]; float w = ww[r];
      int i1 = min(i0 + 1, n - 1);
      float a, b; int c0 = i0, c1 = i1;
      if (i1 == i0) { a = 1.f; b = 0.f; c1 = -1; }
      else { a = 1.f - w; b = w; }
      dd_[r] = a * a + b * b;
      if (r < p - 1) {
        int j0 = ii[r + 1]; float w2 = ww[r + 1];
        int j1 = min(j0 + 1, n - 1);
        float a2, b2; int d0 = j0, d1 = j1;
        if (j1 == j0) { a2 = 1.f; b2 = 0.f; d1 = -2; }
        else { a2 = 1.f - w2; b2 = w2; }
        float s = 0.f;
        if (c0 == d0) s += a * a2;
        if (c0 == d1) s += a * b2;
        if (c1 == d0) s += b * a2;
        if (c1 == d1) s += b * b2;
        ee[r] = s;
      }
    }
  }
  __syncthreads();
  if (tid == 0) {
    float dt = dd_[0];
    idt[0] = 1.f / dt;
    for (int i = 1; i < m; ++i) {
      float c = ee[i - 1] * idt[i - 1];
      cp[i - 1] = c;
      dt = dd_[i] - ee[i - 1] * c;
      idt[i] = 1.f / dt;
    }
  }
  __syncthreads();
  if (tid < m) {
    int j = tid;
    float z = 1.f;
    ginv[j * 97 + j] = 1.f;
    for (int i = j + 1; i < m; ++i) {
      z = -cp[i - 1] * z;
      ginv[i * 97 + j] = z;
    }
    float xn = ginv[(m - 1) * 97 + j] * idt[m - 1];
    ginv[(m - 1) * 97 + j] = xn;
    for (int i = m - 2; i >= 0; --i) {
      float zi = (i >= j) ? ginv[i * 97 + j] : 0.f;
      xn = zi * idt[i] - cp[i] * xn;
      ginv[i * 97 + j] = xn;
    }
  }
  __syncthreads();
  if (p >= n) {
    for (int idx = tid; idx < p * n; idx += 256) {
      int t = idx / n, k = idx - t * n;
      int i0 = ii[t]; float w = ww[t];
      int i1 = min(i0 + 1, n - 1);
      dst[idx] = (1.f - w) * ginv[i0 * 97 + k] + w * ginv[i1 * 97 + k];
    }
  } else {
    for (int t = tid; t < p; t += 256) {
      for (int k = 0; k < n; ++k) outp[t * 97 + k] = 0.f;
      for (int j = 0; j < p; ++j) {
        float hv = ginv[t * 97 + j];
        int i0 = ii[j]; float w = ww[j];
        int i1 = min(i0 + 1, n - 1);
        outp[t * 97 + i0] += hv * (1.f - w);
        outp[t * 97 + i1] += hv * w;
      }
    }
    __syncthreads();
    for (int idx = tid; idx < p * n; idx += 256) {
      int t = idx / n, k = idx - t * n;
      dst[idx] = outp[t * 97 + k];
    }
  }
}

// ---------------- prep1: anchors^T + constsA merged ----------------
__device__ void at_body(int bid, const float* __restrict__ a12,
                        const float* __restrict__ a24, const float* __restrict__ a48,
                        const float* __restrict__ a96, float* __restrict__ at_tab,
                        float* tile) {
  int a = bid >> 3, d0 = (bid & 7) * 64;
  int n = (a == 0) ? 12 : (a == 1) ? 24 : (a == 2) ? 48 : 96;
  const float* src = (a == 0) ? a12 : (a == 1) ? a24 : (a == 2) ? a48 : a96;
  float* dst = at_tab + (long)apre(n) * 512;
  int tid = threadIdx.x;
  for (int i = tid; i < 64 * n; i += 256) {
    int dd = i / n, k = i - dd * n;
    tile[dd * 97 + k] = src[(long)(d0 + dd) * n + (long)k];
  }
  __syncthreads();
  for (int i = tid; i < n * 64; i += 256) {
    int k = i >> 6, dd = i & 63;
    dst[(long)k * 512 + d0 + dd] = tile[dd * 97 + k];
  }
  if (bid == 0) {
    for (int i = tid; i < 12 * 512; i += 256) at_tab[180L * 512 + i] = 0.f;
  }
}

__device__ void constsA_body(int bid, const float* __restrict__ i1w,
                             const float* __restrict__ i1b, const float* __restrict__ i2w,
                             const float* __restrict__ i2b, const float* __restrict__ sb,
                             float* __restrict__ cons, float* __restrict__ vbuf,
                             float* sv) {
  int s = bid / 96, r0 = (bid % 96) * 16;
  const float* inw = s ? i2w : i1w;
  const float* inb = s ? i2b : i1b;
  int tid = threadIdx.x;
  for (int i = tid; i < 512; i += 256) sv[i] = sb[i];
  __syncthreads();
  int lane = tid & 63, w = tid >> 6;
  for (int rr = 0; rr < 4; ++rr) {
    int r = r0 + w * 4 + rr;
    const float* row = inw + (long)r * 512;
    float part = 0.f;
    for (int kk = 0; kk < 8; ++kk) part += row[lane + 64 * kk] * sv[lane + 64 * kk];
    for (int off = 32; off > 0; off >>= 1) part += __shfl_down(part, off, 64);
    if (lane == 0) {
      float v = part + inb[r];
      if (r < 1024) cons[s * 1536 + r] = v;
      else vbuf[s * 512 + (r - 1024)] = v;
    }
  }
}

__global__ __launch_bounds__(256) void prep1(const float* __restrict__ a12,
                                             const float* __restrict__ a24,
                                             const float* __restrict__ a48,
                                             const float* __restrict__ a96,
                                             const float* __restrict__ i1w,
                                             const float* __restrict__ i1b,
                                             const float* __restrict__ i2w,
                                             const float* __restrict__ i2b,
                                             const float* __restrict__ sb,
                                             float* __restrict__ at_tab,
                                             float* __restrict__ cons,
                                             float* __restrict__ vbuf) {
  __shared__ float sm[64 * 97];
  int bid = blockIdx.x;
  if (bid < 32) at_body(bid, a12, a24, a48, a96, at_tab, sm);
  else constsA_body(bid - 32, i1w, i1b, i2w, i2b, sb, cons, vbuf, sm);
}

// ---------------- stage P2: WAfull = in_w @ A_cat ----------------
__global__ __launch_bounds__(256) void wa_gemm2(const float* __restrict__ iw0,
                                                const float* __restrict__ iw1,
                                                const float* __restrict__ atb,
                                                float* __restrict__ waf,
                                                float* __restrict__ qat,
                                                float* __restrict__ vat) {
  __shared__ float smem[2 * 32 * 68];
  float* As = smem;
  float* Ws = smem + 32 * 68;
  int bid = blockIdx.x;
  int s = bid / 72, r = bid % 72;
  int m0 = (r / 3) * 64, n0 = (r % 3) * 64;
  const float* A = s ? iw1 : iw0;
  float* wafs = waf + (long)s * 294912;
  int tid = threadIdx.x;
  int tm = tid & 15, tn = tid >> 4;
  float acc[4][4];
#pragma unroll
  for (int i = 0; i < 4; ++i)
#pragma unroll
    for (int j = 0; j < 4; ++j) acc[i][j] = 0.f;
  int row = tid >> 3, kc = (tid & 7) * 4;
  for (int k0 = 0; k0 < 512; k0 += 32) {
    float4 v = *(const float4*)&A[(long)(m0 + row) * 512 + k0 + kc];
    As[(kc + 0) * 68 + row] = v.x; As[(kc + 1) * 68 + row] = v.y;
    As[(kc + 2) * 68 + row] = v.z; As[(kc + 3) * 68 + row] = v.w;
    v = *(const float4*)&A[(long)(m0 + row + 32) * 512 + k0 + kc];
    As[(kc + 0) * 68 + row + 32] = v.x; As[(kc + 1) * 68 + row + 32] = v.y;
    As[(kc + 2) * 68 + row + 32] = v.z; As[(kc + 3) * 68 + row + 32] = v.w;
    v = *(const float4*)&atb[(long)(n0 + row) * 512 + k0 + kc];
    Ws[(kc + 0) * 68 + row] = v.x; Ws[(kc + 1) * 68 + row] = v.y;
    Ws[(kc + 2) * 68 + row] = v.z; Ws[(kc + 3) * 68 + row] = v.w;
    v = *(const float4*)&atb[(long)(n0 + row + 32) * 512 + k0 + kc];
    Ws[(kc + 0) * 68 + row + 32] = v.x; Ws[(kc + 1) * 68 + row + 32] = v.y;
    Ws[(kc + 2) * 68 + row + 32] = v.z; Ws[(kc + 3) * 68 + row + 32] = v.w;
    __syncthreads();
    for (int kk = 0; kk < 32; ++kk) {
      float4 a = *(const float4*)&As[kk * 68 + tm * 4];
      float4 w = *(const float4*)&Ws[kk * 68 + tn * 4];
      acc[0][0] += a.x * w.x; acc[0][1] += a.x * w.y; acc[0][2] += a.x * w.z; acc[0][3] += a.x * w.w;
      acc[1][0] += a.y * w.x; acc[1][1] += a.y * w.y; acc[1][2] += a.y * w.z; acc[1][3] += a.y * w.w;
      acc[2][0] += a.z * w.x; acc[2][1] += a.z * w.y; acc[2][2] += a.z * w.z; acc[2][3] += a.z * w.w;
      acc[3][0] += a.w * w.x; acc[3][1] += a.w * w.y; acc[3][2] += a.w * w.z; acc[3][3] += a.w * w.w;
    }
    __syncthreads();
  }
#pragma unroll
  for (int mi = 0; mi < 4; ++mi) {
    float4 o;
    o.x = acc[mi][0]; o.y = acc[mi][1]; o.z = acc[mi][2]; o.w = acc[mi][3];
    *(float4*)&wafs[(long)(m0 + tm * 4 + mi) * 192 + n0 + tn * 4] = o;
  }
  if (m0 < 512 || m0 >= 1024) {
    float* Ct = smem;
#pragma unroll
    for (int mi = 0; mi < 4; ++mi)
#pragma unroll
      for (int j = 0; j < 4; ++j)
        Ct[(tn * 4 + j) * 65 + tm * 4 + mi] = acc[mi][j];
    __syncthreads();
    float* dst = ((m0 < 512) ? qat : vat) + (long)s * 98304;
    int mr = m0 & 511;
    for (int i = tid; i < 64 * 64; i += 256) {
      int cc = i >> 6, rr = i & 63;
      dst[(long)(n0 + cc) * 512 + mr + rr] = Ct[cc * 65 + rr];
    }
  }
}

// ---------------- prep2 bodies ----------------
__device__ void constsB_body(int bid, const float* __restrict__ o1w,
                             const float* __restrict__ o1b, const float* __restrict__ o2w,
                             const float* __restrict__ o2b, const float* __restrict__ vbuf,
                             float* __restrict__ cons, float* vv) {
  int s = bid / 32, r0 = (bid % 32) * 16;
  const float* outw = s ? o2w : o1w;
  const float* outb = s ? o2b : o1b;
  int tid = threadIdx.x;
  for (int i = tid; i < 512; i += 256) vv[i] = vbuf[s * 512 + i];
  __syncthreads();
  int lane = tid & 63, w = tid >> 6;
  for (int rr = 0; rr < 4; ++rr) {
    int r = r0 + w * 4 + rr;
    const float* row = outw + (long)r * 512;
    float part = 0.f;
    for (int kk = 0; kk < 8; ++kk) part += row[lane + 64 * kk] * vv[lane + 64 * kk];
    for (int off = 32; off > 0; off >>= 1) part += __shfl_down(part, off, 64);
    if (lane == 0) cons[s * 1536 + 1024 + r] = part + outb[r];
  }
}

__device__ void mt_body(int bid, const float* __restrict__ qat,
                        const float* __restrict__ waf, float* __restrict__ mt,
                        float* As, float* Ws) {
  int s4h = bid / 9, t = bid % 9;
  int s = s4h >> 2, h = s4h & 3;
  int m0 = (t / 3) * 64, n0 = (t % 3) * 64;
  const float* A = qat + (long)s * 98304 + h * 128;
  const float* B = waf + (long)s * 294912 + 98304 + (long)(h * 128) * 192;
  float* C = mt + (long)s4h * 36864;
  int tid = threadIdx.x;
  int tm = tid & 15, tn = tid >> 4;
  float acc[4][4];
#pragma unroll
  for (int i = 0; i < 4; ++i)
#pragma unroll
    for (int j = 0; j < 4; ++j) acc[i][j] = 0.f;
  int row = tid >> 3, kc = (tid & 7) * 4;
  for (int k0 = 0; k0 < 128; k0 += 32) {
    float4 v = *(const float4*)&A[(long)(m0 + row) * 512 + k0 + kc];
    As[(kc + 0) * 68 + row] = v.x; As[(kc + 1) * 68 + row] = v.y;
    As[(kc + 2) * 68 + row] = v.z; As[(kc + 3) * 68 + row] = v.w;
    v = *(const float4*)&A[(long)(m0 + row + 32) * 512 + k0 + kc];
    As[(kc + 0) * 68 + row + 32] = v.x; As[(kc + 1) * 68 + row + 32] = v.y;
    As[(kc + 2) * 68 + row + 32] = v.z; As[(kc + 3) * 68 + row + 32] = v.w;
    for (int l = tid; l < 512; l += 256) {
      int i = l >> 4, kq = (l & 15) * 4;
      float4 b = *(const float4*)&B[(long)(k0 + i) * 192 + n0 + kq];
      Ws[i * 68 + kq + 0] = b.x; Ws[i * 68 + kq + 1] = b.y;
      Ws[i * 68 + kq + 2] = b.z; Ws[i * 68 + kq + 3] = b.w;
    }
    __syncthreads();
    for (int kk = 0; kk < 32; ++kk) {
      float4 a = *(const float4*)&As[kk * 68 + tm * 4];
      float4 w = *(const float4*)&Ws[kk * 68 + tn * 4];
      acc[0][0] += a.x * w.x; acc[0][1] += a.x * w.y; acc[0][2] += a.x * w.z; acc[0][3] += a.x * w.w;
      acc[1][0] += a.y * w.x; acc[1][1] += a.y * w.y; acc[1][2] += a.y * w.z; acc[1][3] += a.y * w.w;
      acc[2][0] += a.z * w.x; acc[2][1] += a.z * w.y; acc[2][2] += a.z * w.z; acc[2][3] += a.z * w.w;
      acc[3][0] += a.w * w.x; acc[3][1] += a.w * w.y; acc[3][2] += a.w * w.z; acc[3][3] += a.w * w.w;
    }
    __syncthreads();
  }
#pragma unroll
  for (int mi = 0; mi < 4; ++mi) {
    float4 o;
    o.x = acc[mi][0]; o.y = acc[mi][1]; o.z = acc[mi][2]; o.w = acc[mi][3];
    *(float4*)&C[(long)(m0 + tm * 4 + mi) * 192 + n0 + tn * 4] = o;
  }
}

__device__ void sc_body(int bid, const float* __restrict__ qat,
                        const float* __restrict__ waf, const float* __restrict__ cons,
                        float* __restrict__ def, float* qcl, float* kbl) {
  int s = bid >> 2, h = bid & 3;
  int tid = threadIdx.x;
  const float* qc = cons + s * 1536;
  const float* kb = qc + 512;
  if (tid < 128) {
    qcl[tid] = qc[h * 128 + tid];
    kbl[tid] = kb[h * 128 + tid];
  }
  __syncthreads();
  const float* katb = waf + (long)s * 294912 + 98304;
  const float* qats = qat + (long)s * 98304;
  float* dtab = def + (long)(s * 4 + h) * 192;
  float* etab = def + 1536 + (long)(s * 4 + h) * 192;
  float* ftab = def + 3072 + (s * 4 + h);
  if (tid < 192) {
    float acc = 0.f;
    for (int i = 0; i < 128; ++i) acc += katb[(long)(h * 128 + i) * 192 + tid] * qcl[i];
    dtab[tid] = acc;
    float acc2 = 0.f;
    const float* qr = qats + (long)tid * 512 + h * 128;
    for (int i = 0; i < 128; ++i) acc2 += qr[i] * kbl[i];
    etab[tid] = acc2;
  }
  if (tid < 64) {
    float acc = 0.f;
    for (int i = tid; i < 128; i += 64) acc += qcl[i] * kbl[i];
    for (int off = 32; off > 0; off >>= 1) acc += __shfl_down(acc, off, 64);
    if (tid == 0) *ftab = acc;
  }
}

__device__ void ova_body(int bid, const float* __restrict__ ow0,
                         const float* __restrict__ ow1, const float* __restrict__ vat,
                         float* __restrict__ ovt, float* As, float* Ws) {
  int s = bid / 96, r = bid % 96;
  int h = r / 24, r2 = r % 24;
  int m0 = (r2 / 8) * 64, n0 = (r2 % 8) * 64;
  const float* A = vat + (long)s * 98304 + h * 128;
  const float* W = (s ? ow1 : ow0) + h * 128;
  float* C = ovt + ((long)(s * 4 + h) * 192) * 512;
  int tid = threadIdx.x;
  int tm = tid & 15, tn = tid >> 4;
  float acc[4][4];
#pragma unroll
  for (int i = 0; i < 4; ++i)
#pragma unroll
    for (int j = 0; j < 4; ++j) acc[i][j] = 0.f;
  int row = tid >> 3, kc = (tid & 7) * 4;
  for (int k0 = 0; k0 < 128; k0 += 32) {
    float4 v = *(const float4*)&A[(long)(m0 + row) * 512 + k0 + kc];
    As[(kc + 0) * 68 + row] = v.x; As[(kc + 1) * 68 + row] = v.y;
    As[(kc + 2) * 68 + row] = v.z; As[(kc + 3) * 68 + row] = v.w;
    v = *(const float4*)&A[(long)(m0 + row + 32) * 512 + k0 + kc];
    As[(kc + 0) * 68 + row + 32] = v.x; As[(kc + 1) * 68 + row + 32] = v.y;
    As[(kc + 2) * 68 + row + 32] = v.z; As[(kc + 3) * 68 + row + 32] = v.w;
    v = *(const float4*)&W[(long)(n0 + row) * 512 + k0 + kc];
    Ws[(kc + 0) * 68 + row] = v.x; Ws[(kc + 1) * 68 + row] = v.y;
    Ws[(kc + 2) * 68 + row] = v.z; Ws[(kc + 3) * 68 + row] = v.w;
    v = *(const float4*)&W[(long)(n0 + row + 32) * 512 + k0 + kc];
    Ws[(kc + 0) * 68 + row + 32] = v.x; Ws[(kc + 1) * 68 + row + 32] = v.y;
    Ws[(kc + 2) * 68 + row + 32] = v.z; Ws[(kc + 3) * 68 + row + 32] = v.w;
    __syncthreads();
    for (int kk = 0; kk < 32; ++kk) {
      float4 a = *(const float4*)&As[kk * 68 + tm * 4];
      float4 w = *(const float4*)&Ws[kk * 68 + tn * 4];
      acc[0][0] += a.x * w.x; acc[0][1] += a.x * w.y; acc[0][2] += a.x * w.z; acc[0][3] += a.x * w.w;
      acc[1][0] += a.y * w.x; acc[1][1] += a.y * w.y; acc[1][2] += a.y * w.z; acc[1][3] += a.y * w.w;
      acc[2][0] += a.z * w.x; acc[2][1] += a.z * w.y; acc[2][2] += a.z * w.z; acc[2][3] += a.z * w.w;
      acc[3][0] += a.w * w.x; acc[3][1] += a.w * w.y; acc[3][2] += a.w * w.z; acc[3][3] += a.w * w.w;
    }
    __syncthreads();
  }
#pragma unroll
  for (int mi = 0; mi < 4; ++mi) {
    float4 o;
    o.x = acc[mi][0]; o.y = acc[mi][1]; o.z = acc[mi][2]; o.w = acc[mi][3];
    *(float4*)&C[(long)(m0 + tm * 4 + mi) * 512 + n0 + tn * 4] = o;
  }
}

__global__ __launch_bounds__(256) void prep2(const float* __restrict__ o1w,
                                             const float* __restrict__ o1b,
                                             const float* __restrict__ o2w,
                                             const float* __restrict__ o2b,
                                             const float* __restrict__ vbuf,
                                             float* __restrict__ cons,
                                             const float* __restrict__ qat,
                                             const float* __restrict__ waf,
                                             float* __restrict__ mtab,
                                             float* __restrict__ def,
                                             const float* __restrict__ vat,
                                             float* __restrict__ ovt) {
  __shared__ float sm[2 * 32 * 68];
  int bid = blockIdx.x;
  if (bid < 64) constsB_body(bid, o1w, o1b, o2w, o2b, vbuf, cons, sm);
  else if (bid < 136) mt_body(bid - 64, qat, waf, mtab, sm, sm + 32 * 68);
  else if (bid < 144) sc_body(bid - 136, qat, waf, cons, def, sm, sm + 128);
  else ova_body(bid - 144, o1w, o2w, vat, ovt, sm, sm + 32 * 68);
}

// ---------------- stage B1: attn_a — Z, scores, softmax, zh -> zcat ----------------
__global__ __launch_bounds__(256) void attn_a(
    const float* __restrict__ xT, const int* __restrict__ per,
    const float* __restrict__ mp, const float* __restrict__ mt,
    const float* __restrict__ def, float* __restrict__ zc) {
  __shared__ float xb[8 * 384];
  __shared__ float Z[8 * 1248];
  __shared__ float zl[8 * 96];
  __shared__ float arb[8 * 384];
  __shared__ float qkc[32];
  float* scp = xb;

  int tid = threadIdx.x;
  int bid = blockIdx.x;
  int slot = bid & 1;
  int c = (bid >> 1) & 127;
  int b0 = (bid >> 8) * 8;
  int p = per[c * 2 + slot];
  int n = nanch(p);
  int np = Tn / p;
  int n1 = n + 1;
  float s = sqrtf((float)p / (float)n);
  float s2 = s * s;
  const float rscale = 0.08838834764831845f;
  int pre = apre(n);
  const float* mpp = mp + mpoff(p);
  const float* dt = def + (long)(slot * 4) * 192;
  const float* et = def + 1536 + (long)(slot * 4) * 192;
  const float* ft = def + 3072 + slot * 4;
  const float* mtb = mt + (long)(slot * 4) * 36864;

  for (int g = 0; g < 8; ++g)
    for (int t = tid; t < Tn; t += 256)
      xb[g * 384 + t] = xT[((long)c * Bn + b0 + g) * Tn + t];
  __syncthreads();

  // Ph1: Z = patches @ Mpinv (8-way g-fused, k-pairs, float2 Mpinv loads)
  {
    int half = n >> 1;
    int tot1 = np * half;
    for (int idx = tid; idx < tot1; idx += 256) {
      int j = idx / half, k2 = idx - j * half;
      int k = k2 * 2;
      int jb = j * p;
      const float* mk = mpp + k;
      float a0[8], a1[8];
#pragma unroll
      for (int g = 0; g < 8; ++g) { a0[g] = 0.f; a1[g] = 0.f; }
      for (int t = 0; t < p; ++t) {
        float2 m = *(const float2*)&mk[(long)t * n];
#pragma unroll
        for (int g = 0; g < 8; ++g) {
          float xv = xb[g * 384 + jb + t];
          a0[g] += m.x * xv;
          a1[g] += m.y * xv;
        }
      }
      int zi = j * n1 + k;
#pragma unroll
      for (int g = 0; g < 8; ++g) {
        Z[g * 1248 + zi] = a0[g];
        Z[g * 1248 + zi + 1] = a1[g];
      }
    }
  }
  __syncthreads();

  for (int idx = tid; idx < 8 * n; idx += 256) {
    int g = idx / n, k = idx - g * n;
    zl[g * 96 + k] = Z[g * 1248 + (np - 1) * n1 + k];
  }
  __syncthreads();

  {
    int pair = tid >> 3, l = tid & 7;
    int g = pair >> 2, h = pair & 3;
    const float* eh = et + h * 192 + pre;
    float acc = 0.f;
    for (int j = l; j < n; j += 8) acc += eh[j] * zl[g * 96 + j];
    for (int off = 4; off > 0; off >>= 1) acc += __shfl_down(acc, off, 8);
    if (l == 0) qkc[g * 4 + h] = s * acc + ft[h];
  }
  {
    int tot = 4 * n;
    for (int idx = tid; idx < tot; idx += 256) {
      int h = idx / n, k = idx - h * n;
      const float* mtc = mtb + (long)h * 36864 + (long)pre * 192 + pre + k;
      float a[8];
#pragma unroll
      for (int g = 0; g < 8; ++g) a[g] = 0.f;
      for (int j0 = 0; j0 < n; j0 += 4) {
        float4 zb[8];
#pragma unroll
        for (int g = 0; g < 8; ++g) zb[g] = *(const float4*)&zl[g * 96 + j0];
#pragma unroll
        for (int c4 = 0; c4 < 4; ++c4) {
          float mv = mtc[(long)(j0 + c4) * 192];
#pragma unroll
          for (int g = 0; g < 8; ++g) {
            float zv = (c4 == 0) ? zb[g].x : (c4 == 1) ? zb[g].y : (c4 == 2) ? zb[g].z : zb[g].w;
            a[g] += mv * zv;
          }
        }
      }
      float dv = dt[h * 192 + pre + k];
#pragma unroll
      for (int g = 0; g < 8; ++g) arb[g * 384 + h * 96 + k] = s2 * a[g] + s * dv;
    }
  }
  __syncthreads();

  // scores
  {
    int fnp = 4 * np;
    int tot = 8 * fnp;
    for (int idx = tid; idx < tot; idx += 256) {
      int g = idx / fnp;
      int r = idx - g * fnp;
      int h = r / np, j = r - h * np;
      const float* ap = arb + g * 384 + h * 96;
      const float* zp = Z + g * 1248 + j * n1;
      float acc = 0.f;
      for (int k = 0; k < n; ++k) acc += ap[k] * zp[k];
      scp[g * 384 + h * np + j] = (acc + qkc[g * 4 + h]) * rscale;
    }
  }
  __syncthreads();

  // softmax
  {
    int pair = tid >> 3, l = tid & 7;
    int g = pair >> 2, h = pair & 3;
    float* sp = scp + g * 384 + h * np;
    float m = -1e30f;
    for (int j = l; j < np; j += 8) m = fmaxf(m, sp[j]);
    for (int off = 4; off > 0; off >>= 1) m = fmaxf(m, __shfl_xor(m, off, 8));
    float lsum = 0.f;
    for (int j = l; j < np; j += 8) { float e = expf(sp[j] - m); sp[j] = e; lsum += e; }
    for (int off = 4; off > 0; off >>= 1) lsum += __shfl_xor(lsum, off, 8);
    float il = 1.f / lsum;
    for (int j = l; j < np; j += 8) sp[j] *= il;
  }
  __syncthreads();

  // zh
  {
    int fn = 4 * n;
    int tot = 8 * fn;
    for (int idx = tid; idx < tot; idx += 256) {
      int g = idx / fn;
      int r = idx - g * fn;
      int h = r / n, k = r - h * n;
      const float* sp = scp + g * 384 + h * np;
      const float* zp = Z + g * 1248 + k;
      float acc = 0.f;
      for (int j = 0; j < np; ++j) acc += sp[j] * zp[j * n1];
      arb[g * 384 + h * 96 + k] = acc;
    }
  }
  __syncthreads();

  // write zcat (s-scaled): row = (slot*128+c)*16 + b; cols seg*96+k, k<n
  {
    long rowb = ((long)slot * 128 + c) * 16 + b0;
    int fn5 = 5 * n;
    int tot = 8 * fn5;
    for (int idx = tid; idx < tot; idx += 256) {
      int g = idx / fn5, r = idx - g * fn5;
      int seg = r / n, k = r - seg * n;
      float v = (seg == 0) ? zl[g * 96 + k] : arb[g * 384 + (seg - 1) * 96 + k];
      zc[(rowb + g) * 480 + seg * 96 + k] = s * v;
    }
  }
}

// ---------------- stage B2: attn_y — y = Wcat^T zcat + const, LN, write comb ----------------
__global__ __launch_bounds__(256) void attn_y(
    const int* __restrict__ per, const float* __restrict__ zc,
    const float* __restrict__ at_tab, const float* __restrict__ ovt,
    const float* __restrict__ cons, const float* __restrict__ sb,
    const float* __restrict__ l1g, const float* __restrict__ l1b,
    const float* __restrict__ l2g, const float* __restrict__ l2b,
    float* __restrict__ comb) {
  __shared__ float zbuf[16 * 480];
  __shared__ float red[128];
  __shared__ float stats[32];
  int tid = threadIdx.x;
  int bid = blockIdx.x;
  int slot = bid & 1, c = bid >> 1;
  int p = per[c * 2 + slot];
  int n = nanch(p);
  int pre = apre(n);
  const float* atb = at_tab + (long)pre * 512;
  const float* oc = cons + slot * 1536 + 1024;
  const float* lng = slot ? l2g : l1g;
  const float* lnb = slot ? l2b : l1b;
  long rowb = ((long)slot * 128 + c) * 16;
  int fn5 = 5 * n;
  for (int idx = tid; idx < 16 * fn5; idx += 256) {
    int g = idx / fn5, r = idx - g * fn5;
    int seg = r / n, k = r - seg * n;
    zbuf[g * 480 + seg * 96 + k] = zc[(rowb + g) * 480 + seg * 96 + k];
  }
  __syncthreads();
  int d0 = 2 * tid;
  float acc0[16], acc1[16];
#pragma unroll
  for (int r = 0; r < 16; ++r) { acc0[r] = 0.f; acc1[r] = 0.f; }
  for (int seg = 0; seg < 5; ++seg) {
    const float* wt = (seg == 0) ? atb
                                 : (ovt + ((long)(slot * 4 + seg - 1) * 192 + pre) * 512);
    int zoff = seg * 96;
    for (int k0 = 0; k0 < n; k0 += 4) {
      float4 zv[16];
#pragma unroll
      for (int r = 0; r < 16; ++r) zv[r] = *(const float4*)&zbuf[r * 480 + zoff + k0];
#pragma unroll
      for (int c4 = 0; c4 < 4; ++c4) {
        float2 w = *(const float2*)&wt[(long)(k0 + c4) * 512 + d0];
#pragma unroll
        for (int r = 0; r < 16; ++r) {
          float z = (c4 == 0) ? zv[r].x : (c4 == 1) ? zv[r].y : (c4 == 2) ? zv[r].z : zv[r].w;
          acc0[r] += w.x * z;
          acc1[r] += w.y * z;
        }
      }
    }
  }
  float2 sbv = *(const float2*)&sb[d0];
  float2 ocv = *(const float2*)&oc[d0];
  float s0 = sbv.x + ocv.x, s1 = sbv.y + ocv.y;
#pragma unroll
  for (int r = 0; r < 16; ++r) { acc0[r] += s0; acc1[r] += s1; }
  // LN over 512 per row
  float ps[32];
#pragma unroll
  for (int r = 0; r < 16; ++r) {
    ps[2 * r] = acc0[r] + acc1[r];
    ps[2 * r + 1] = acc0[r] * acc0[r] + acc1[r] * acc1[r];
  }
  int w = tid >> 6, lane = tid & 63;
  for (int off = 32; off > 0; off >>= 1) {
#pragma unroll
    for (int i = 0; i < 32; ++i) ps[i] += __shfl_down(ps[i], off, 64);
  }
  if (lane == 0) {
#pragma unroll
    for (int i = 0; i < 32; ++i) red[w * 32 + i] = ps[i];
  }
  __syncthreads();
  if (tid < 16) {
    int r = tid;
    float ssum = red[2 * r] + red[32 + 2 * r] + red[64 + 2 * r] + red[96 + 2 * r];
    float qsum = red[2 * r + 1] + red[32 + 2 * r + 1] + red[64 + 2 * r + 1] + red[96 + 2 * r + 1];
    float mu = ssum / 512.f;
    float var = qsum / 512.f - mu * mu;
    stats[2 * r] = mu;
    stats[2 * r + 1] = rsqrtf(var + 1e-5f);
  }
  __syncthreads();
  float2 gv = *(const float2*)&lng[d0];
  float2 bv = *(const float2*)&lnb[d0];
#pragma unroll
  for (int r = 0; r < 16; ++r) {
    float mu = stats[2 * r], rstd = stats[2 * r + 1];
    long base = ((long)r * Cn + c) * 1536 + slot * 512;
    float2 o;
    o.x = (acc0[r] - mu) * rstd * gv.x + bv.x;
    o.y = (acc1[r] - mu) * rstd * gv.y + bv.y;
    *(float2*)&comb[base + d0] = o;
  }
}

// ---------------- stage D: trend ----------------
__global__ __launch_bounds__(256) void trend_kernel(const float* __restrict__ xT,
                                                    const float* __restrict__ mp384,
                                                    const float* __restrict__ at96,
                                                    const float* __restrict__ sb,
                                                    float* __restrict__ comb) {
  __shared__ float xb[Bn * Tn];
  __shared__ float Ztr[Bn * 97];
  int c = blockIdx.x, tid = threadIdx.x;
  for (int i = tid; i < Bn * Tn; i += 256) xb[i] = xT[(long)c * Bn * Tn + i];
  __syncthreads();
  for (int idx = tid; idx < 4 * 96; idx += 256) {
    int bq = idx / 96, k = idx - bq * 96;
    const float* x0 = xb + (bq * 4 + 0) * Tn;
    const float* x1 = xb + (bq * 4 + 1) * Tn;
    const float* x2 = xb + (bq * 4 + 2) * Tn;
    const float* x3 = xb + (bq * 4 + 3) * Tn;
    const float* mk = mp384 + k;
    float a0 = 0.f, a1 = 0.f, a2 = 0.f, a3 = 0.f;
    for (int t = 0; t < Tn; ++t) {
      float m = mk[(long)t * 96];
      a0 += m * x0[t]; a1 += m * x1[t]; a2 += m * x2[t]; a3 += m * x3[t];
    }
    Ztr[(bq * 4 + 0) * 97 + k] = a0;
    Ztr[(bq * 4 + 1) * 97 + k] = a1;
    Ztr[(bq * 4 + 2) * 97 + k] = a2;
    Ztr[(bq * 4 + 3) * 97 + k] = a3;
  }
  __syncthreads();
  float acc0[Bn], acc1[Bn];
#pragma unroll
  for (int b = 0; b < Bn; ++b) { acc0[b] = 0.f; acc1[b] = 0.f; }
  for (int k = 0; k < 96; ++k) {
    float w0 = at96[(long)k * 512 + tid];
    float w1 = at96[(long)k * 512 + 256 + tid];
#pragma unroll
    for (int b = 0; b < Bn; ++b) {
      float z = Ztr[b * 97 + k];
      acc0[b] += w0 * z;
      acc1[b] += w1 * z;
    }
  }
  float s0 = sb[tid], s1 = sb[256 + tid];
#pragma unroll
  for (int b = 0; b < Bn; ++b) {
    long base = ((long)b * Cn + c) * 1536 + 1024;
    comb[base + tid] = 2.f * acc0[b] + s0;
    comb[base + 256 + tid] = 2.f * acc1[b] + s1;
  }
}

// ---------------- stage E1: fusion GEMM-1, split-K halves (no bias) ----------------
__global__ __launch_bounds__(256) void gemm1_part(const float* __restrict__ A,
                                                  const float* __restrict__ W,
                                                  float* __restrict__ C0,
                                                  float* __restrict__ C1) {
  __shared__ float As[32 * 68];
  __shared__ float Ws[32 * 68];
  int bid = blockIdx.x;
  int kh = bid >> 8;
  int r = bid & 255;
  int m0 = (r >> 3) * 64, n0 = (r & 7) * 64;
  float* C = kh ? C1 : C0;
  const float* Ab = A + kh * 768;
  const float* Wb = W + kh * 768;
  int tid = threadIdx.x;
  int tm = tid & 15, tn = tid >> 4;
  float acc[4][4];
#pragma unroll
  for (int i = 0; i < 4; ++i)
#pragma unroll
    for (int j = 0; j < 4; ++j) acc[i][j] = 0.f;
  int row = tid >> 3, kc = (tid & 7) * 4;
  for (int k0 = 0; k0 < 768; k0 += 32) {
    float4 v = *(const float4*)&Ab[(long)(m0 + row) * 1536 + k0 + kc];
    As[(kc + 0) * 68 + row] = v.x; As[(kc + 1) * 68 + row] = v.y;
    As[(kc + 2) * 68 + row] = v.z; As[(kc + 3) * 68 + row] = v.w;
    v = *(const float4*)&Ab[(long)(m0 + row + 32) * 1536 + k0 + kc];
    As[(kc + 0) * 68 + row + 32] = v.x; As[(kc + 1) * 68 + row + 32] = v.y;
    As[(kc + 2) * 68 + row + 32] = v.z; As[(kc + 3) * 68 + row + 32] = v.w;
    v = *(const float4*)&Wb[(long)(n0 + row) * 1536 + k0 + kc];
    Ws[(kc + 0) * 68 + row] = v.x; Ws[(kc + 1) * 68 + row] = v.y;
    Ws[(kc + 2) * 68 + row] = v.z; Ws[(kc + 3) * 68 + row] = v.w;
    v = *(const float4*)&Wb[(long)(n0 + row + 32) * 1536 + k0 + kc];
    Ws[(kc + 0) * 68 + row + 32] = v.x; Ws[(kc + 1) * 68 + row + 32] = v.y;
    Ws[(kc + 2) * 68 + row + 32] = v.z; Ws[(kc + 3) * 68 + row + 32] = v.w;
    __syncthreads();
    for (int kk = 0; kk < 32; ++kk) {
      float4 a = *(const float4*)&As[kk * 68 + tm * 4];
      float4 w = *(const float4*)&Ws[kk * 68 + tn * 4];
      acc[0][0] += a.x * w.x; acc[0][1] += a.x * w.y; acc[0][2] += a.x * w.z; acc[0][3] += a.x * w.w;
      acc[1][0] += a.y * w.x; acc[1][1] += a.y * w.y; acc[1][2] += a.y * w.z; acc[1][3] += a.y * w.w;
      acc[2][0] += a.z * w.x; acc[2][1] += a.z * w.y; acc[2][2] += a.z * w.z; acc[2][3] += a.z * w.w;
      acc[3][0] += a.w * w.x; acc[3][1] += a.w * w.y; acc[3][2] += a.w * w.z; acc[3][3] += a.w * w.w;
    }
    __syncthreads();
  }
#pragma unroll
  for (int mi = 0; mi < 4; ++mi) {
    float4 o;
    o.x = acc[mi][0]; o.y = acc[mi][1]; o.z = acc[mi][2]; o.w = acc[mi][3];
    *(float4*)&C[(long)(m0 + tm * 4 + mi) * 512 + n0 + tn * 4] = o;
  }
}

// ---------------- stage E1b: combine split-K halves + bias + exact gelu ----------------
__global__ __launch_bounds__(256) void gelu_red(float* __restrict__ H,
                                                const float* __restrict__ H2,
                                                const float* __restrict__ fb1) {
  int i = blockIdx.x * 256 + threadIdx.x;     // float4 index, 262144 total
  float4 a = ((const float4*)H)[i];
  float4 b = ((const float4*)H2)[i];
  int col4 = (i & 127) << 2;
  float4 bs = *(const float4*)&fb1[col4];
  float4 v;
  v.x = a.x + b.x + bs.x;
  v.y = a.y + b.y + bs.y;
  v.z = a.z + b.z + bs.z;
  v.w = a.w + b.w + bs.w;
  v.x = 0.5f * v.x * (1.f + erff(v.x * 0.7071067811865475f));
  v.y = 0.5f * v.y * (1.f + erff(v.y * 0.7071067811865475f));
  v.z = 0.5f * v.z * (1.f + erff(v.z * 0.7071067811865475f));
  v.w = 0.5f * v.w * (1.f + erff(v.w * 0.7071067811865475f));
  ((float4*)H)[i] = v;
}

// ---------------- stage E2: GEMM-2 with bias ----------------
template <bool GELU>
__global__ __launch_bounds__(256) void fused_gemm(const float* __restrict__ A,
                                                  const float* __restrict__ W,
                                                  const float* __restrict__ bias,
                                                  float* __restrict__ C,
                                                  int N, int K) {
  __shared__ float As[32 * 68];
  __shared__ float Ws[32 * 68];
  int nb = N >> 6;
  int m0 = (blockIdx.x / nb) * 64, n0 = (blockIdx.x % nb) * 64;
  int tid = threadIdx.x;
  int tm = tid & 15, tn = tid >> 4;
  float acc[4][4];
#pragma unroll
  for (int i = 0; i < 4; ++i)
#pragma unroll
    for (int j = 0; j < 4; ++j) acc[i][j] = 0.f;
  int row = tid >> 3, kc = (tid & 7) * 4;
  for (int k0 = 0; k0 < K; k0 += 32) {
    {
      float4 v = *(const float4*)&A[(long)(m0 + row) * K + k0 + kc];
      As[(kc + 0) * 68 + row] = v.x; As[(kc + 1) * 68 + row] = v.y;
      As[(kc + 2) * 68 + row] = v.z; As[(kc + 3) * 68 + row] = v.w;
      v = *(const float4*)&A[(long)(m0 + row + 32) * K + k0 + kc];
      As[(kc + 0) * 68 + row + 32] = v.x; As[(kc + 1) * 68 + row + 32] = v.y;
      As[(kc + 2) * 68 + row + 32] = v.z; As[(kc + 3) * 68 + row + 32] = v.w;
      v = *(const float4*)&W[(long)(n0 + row) * K + k0 + kc];
      Ws[(kc + 0) * 68 + row] = v.x; Ws[(kc + 1) * 68 + row] = v.y;
      Ws[(kc + 2) * 68 + row] = v.z; Ws[(kc + 3) * 68 + row] = v.w;
      v = *(const float4*)&W[(long)(n0 + row + 32) * K + k0 + kc];
      Ws[(kc + 0) * 68 + row + 32] = v.x; Ws[(kc + 1) * 68 + row + 32] = v.y;
      Ws[(kc + 2) * 68 + row + 32] = v.z; Ws[(kc + 3) * 68 + row + 32] = v.w;
    }
    __syncthreads();
    for (int kk = 0; kk < 32; ++kk) {
      float4 a = *(const float4*)&As[kk * 68 + tm * 4];
      float4 w = *(const float4*)&Ws[kk * 68 + tn * 4];
      acc[0][0] += a.x * w.x; acc[0][1] += a.x * w.y; acc[0][2] += a.x * w.z; acc[0][3] += a.x * w.w;
      acc[1][0] += a.y * w.x; acc[1][1] += a.y * w.y; acc[1][2] += a.y * w.z; acc[1][3] += a.y * w.w;
      acc[2][0] += a.z * w.x; acc[2][1] += a.z * w.y; acc[2][2] += a.z * w.z; acc[2][3] += a.z * w.w;
      acc[3][0] += a.w * w.x; acc[3][1] += a.w * w.y; acc[3][2] += a.w * w.z; acc[3][3] += a.w * w.w;
    }
    __syncthreads();
  }
  float b0v = bias[n0 + tn * 4 + 0], b1v = bias[n0 + tn * 4 + 1];
  float b2v = bias[n0 + tn * 4 + 2], b3v = bias[n0 + tn * 4 + 3];
#pragma unroll
  for (int mi = 0; mi < 4; ++mi) {
    float4 o;
    o.x = acc[mi][0] + b0v; o.y = acc[mi][1] + b1v;
    o.z = acc[mi][2] + b2v; o.w = acc[mi][3] + b3v;
    if (GELU) {
      o.x = 0.5f * o.x * (1.f + erff(o.x * 0.7071067811865475f));
      o.y = 0.5f * o.y * (1.f + erff(o.y * 0.7071067811865475f));
      o.z = 0.5f * o.z * (1.f + erff(o.z * 0.7071067811865475f));
      o.w = 0.5f * o.w * (1.f + erff(o.w * 0.7071067811865475f));
    }
    *(float4*)&C[(long)(m0 + tm * 4 + mi) * N + n0 + tn * 4] = o;
  }
}

extern "C" void kernel_launch(void* const* d_in, const int* in_sizes, int n_in,
                              void* d_out, int out_size, void* d_ws, size_t ws_size,
                              hipStream_t stream) {
  const float* x    = (const float*)d_in[0];
  const float* a12  = (const float*)d_in[1];
  const float* a24  = (const float*)d_in[2];
  const float* a48  = (const float*)d_in[3];
  const float* a96  = (const float*)d_in[4];
  const float* sb   = (const float*)d_in[5];
  const float* g1iw = (const float*)d_in[6];
  const float* g1ib = (const float*)d_in[7];
  const float* g1ow = (const float*)d_in[8];
  const float* g1ob = (const float*)d_in[9];
  const float* g1lg = (const float*)d_in[10];
  const float* g1lb = (const float*)d_in[11];
  const float* g2iw = (const float*)d_in[12];
  const float* g2ib = (const float*)d_in[13];
  const float* g2ow = (const float*)d_in[14];
  const float* g2ob = (const float*)d_in[15];
  const float* g2lg = (const float*)d_in[16];
  const float* g2lb = (const float*)d_in[17];
  const float* fw1  = (const float*)d_in[18];
  const float* fb1  = (const float*)d_in[19];
  const float* fw2  = (const float*)d_in[20];
  const float* fb2  = (const float*)d_in[21];

  if (ws_size < (size_t)WS_FLOATS * sizeof(float)) return;

  float* ws   = (float*)d_ws;
  float* xT   = ws + OFF_XT;
  float* avg  = ws + OFF_AVG;
  int*   per  = (int*)(ws + OFF_PER);
  float* mp   = ws + OFF_MP;
  float* atb  = ws + OFF_AT;
  float* waf  = ws + OFF_WAF;
  float* qat  = ws + OFF_QAT;
  float* vat  = ws + OFF_VAT;
  float* ovt  = ws + OFF_OVT;
  float* cons = ws + OFF_CON;
  float* vbuf = ws + OFF_VB;
  float* mtab = ws + OFF_MT;
  float* def  = ws + OFF_DEF;
  float* zc   = ws + OFF_ZC;
  float* comb = ws + OFF_COMB;
  float* hbuf = ws + OFF_H;
  float* hbu2 = ws + OFF_H2;
  float* out  = (float*)d_out;

  transpose_kernel<<<192, 256, 0, stream>>>(x, xT);
  acf_kernel<<<Cn * 6, 256, 0, stream>>>(xT, avg);
  periods_kernel<<<32, 256, 0, stream>>>(avg, per);
  build_mpinv_kernel<<<190, 256, 0, stream>>>(per, mp);
  prep1<<<224, 256, 0, stream>>>(a12, a24, a48, a96, g1iw, g1ib, g2iw, g2ib, sb,
                                 atb, cons, vbuf);
  wa_gemm2<<<144, 256, 0, stream>>>(g1iw, g2iw, atb, waf, qat, vat);
  prep2<<<336, 256, 0, stream>>>(g1ow, g1ob, g2ow, g2ob, vbuf, cons,
                                 qat, waf, mtab, def, vat, ovt);
  attn_a<<<512, 256, 0, stream>>>(xT, per, mp, mtab, def, zc);
  attn_y<<<256, 256, 0, stream>>>(per, zc, atb, ovt, cons, sb,
                                  g1lg, g1lb, g2lg, g2lb, comb);
  trend_kernel<<<Cn, 256, 0, stream>>>(xT, mp + 1634436L, atb + 84L * 512, sb, comb);
  gemm1_part<<<512, 256, 0, stream>>>(comb, fw1, hbuf, hbu2);
  gelu_red<<<1024, 256, 0, stream>>>(hbuf, hbu2, fb1);
  fused_gemm<false><<<256, 256, 0, stream>>>(hbuf, fw2, fb2, out, 512, 512);
}